// Round 1
// baseline (17842.415 us; speedup 1.0000x reference)
//
#include <hip/hip_runtime.h>
#include <math.h>

#define TPB 256
#define PTS 64
#define ACT_LD 260
#define WT_LD 33
#define NVOX 32768
#define BN_EPS 1e-5f

// ws layout (float offsets)
#define OFF_SUM0 0
#define OFF_SSQ0 9
#define OFF_SUM1 18
#define OFF_SSQ1 82
#define OFF_SUM2 146
#define OFF_SSQ2 274
#define OFF_SUM3 402
#define OFF_SSQ3 658
#define OFF_A0  914
#define OFF_C0  923
#define OFF_A1  932
#define OFF_C1  996
#define OFF_A2  1060
#define OFF_C2  1188
#define OFF_A3  1316
#define OFF_C3  1572
#define WS_FLOATS 1828

__device__ __forceinline__ void atomicMaxFloat(float* addr, float val) {
    if (val >= 0.f) {
        atomicMax((int*)addr, __float_as_int(val));
    } else {
        atomicMin((unsigned int*)addr, (unsigned int)__float_as_int(val));
    }
}

// ---- stats of raw feats (9 channels) ----
__global__ void k_stats0(const float* __restrict__ feats, int N, float* __restrict__ ws) {
    __shared__ float s[9], q[9];
    if (threadIdx.x < 9) { s[threadIdx.x] = 0.f; q[threadIdx.x] = 0.f; }
    __syncthreads();
    float ls0=0,ls1=0,ls2=0,ls3=0,ls4=0,ls5=0,ls6=0,ls7=0,ls8=0;
    float lq0=0,lq1=0,lq2=0,lq3=0,lq4=0,lq5=0,lq6=0,lq7=0,lq8=0;
    for (size_t i = (size_t)blockIdx.x * blockDim.x + threadIdx.x; i < (size_t)N;
         i += (size_t)gridDim.x * blockDim.x) {
        const float* r = feats + i * 9;
        float v;
        v = r[0]; ls0 += v; lq0 += v*v;
        v = r[1]; ls1 += v; lq1 += v*v;
        v = r[2]; ls2 += v; lq2 += v*v;
        v = r[3]; ls3 += v; lq3 += v*v;
        v = r[4]; ls4 += v; lq4 += v*v;
        v = r[5]; ls5 += v; lq5 += v*v;
        v = r[6]; ls6 += v; lq6 += v*v;
        v = r[7]; ls7 += v; lq7 += v*v;
        v = r[8]; ls8 += v; lq8 += v*v;
    }
    atomicAdd(&s[0], ls0); atomicAdd(&q[0], lq0);
    atomicAdd(&s[1], ls1); atomicAdd(&q[1], lq1);
    atomicAdd(&s[2], ls2); atomicAdd(&q[2], lq2);
    atomicAdd(&s[3], ls3); atomicAdd(&q[3], lq3);
    atomicAdd(&s[4], ls4); atomicAdd(&q[4], lq4);
    atomicAdd(&s[5], ls5); atomicAdd(&q[5], lq5);
    atomicAdd(&s[6], ls6); atomicAdd(&q[6], lq6);
    atomicAdd(&s[7], ls7); atomicAdd(&q[7], lq7);
    atomicAdd(&s[8], ls8); atomicAdd(&q[8], lq8);
    __syncthreads();
    if (threadIdx.x < 9) {
        atomicAdd(&ws[OFF_SUM0 + threadIdx.x], s[threadIdx.x]);
        atomicAdd(&ws[OFF_SSQ0 + threadIdx.x], q[threadIdx.x]);
    }
}

// ---- finalize BN params: a = g*rsqrt(var+eps), c = be - m*a ----
__global__ void k_fin(float* __restrict__ ws, int sum_off, int ssq_off, int a_off, int c_off,
                      int C, const float* __restrict__ g, const float* __restrict__ be, float n) {
    int c = threadIdx.x;
    if (c < C) {
        float m = ws[sum_off + c] / n;
        float v = ws[ssq_off + c] / n - m * m;
        float a = g[c] * rsqrtf(v + BN_EPS);
        ws[a_off + c] = a;
        ws[c_off + c] = be[c] - m * a;
    }
}

__global__ void k_initout(float* __restrict__ out) {
    size_t total = (size_t)NVOX * 256;
    for (size_t i = (size_t)blockIdx.x * blockDim.x + threadIdx.x; i < total;
         i += (size_t)gridDim.x * blockDim.x) {
        out[i] = -INFINITY;
    }
}

__global__ void k_coords(float* __restrict__ outc) {
    int v = blockIdx.x * blockDim.x + threadIdx.x;
    if (v < NVOX) {
        outc[3 * v + 0] = (float)(v >> 10);
        outc[3 * v + 1] = (float)((v >> 5) & 31);
        outc[3 * v + 2] = (float)(v & 31);
    }
}

// MODE: 0 = hidden layer (bias, BN, ReLU, write back to Act)
//       1 = stats layer  (bias, accumulate sum/sumsq of h, done)
//       2 = final layer  (bias, atomicMax scatter to out)
template<int C, int K, int MODE>
__device__ __forceinline__ void dense_layer(
    const float* __restrict__ W, const float* __restrict__ bias,
    const float* __restrict__ bn_a, const float* __restrict__ bn_c,
    float* __restrict__ gsum, float* __restrict__ gssq,
    float* __restrict__ Act, float* __restrict__ Wt,
    float* __restrict__ red, const int* __restrict__ vox,
    float* __restrict__ out, int tid, int nv)
{
    constexpr int G = TPB / C;    // thread groups over points
    constexpr int P = PTS / G;    // points per thread
    const int col = tid % C;
    const int g = tid / C;
    const int pbase = g * P;

    float acc[P];
#pragma unroll
    for (int p = 0; p < P; ++p) acc[p] = 0.f;

    constexpr int KC  = (K < 32) ? K : 32;
    constexpr int NCH = K / KC;

    for (int ch = 0; ch < NCH; ++ch) {
        const int k0 = ch * KC;
        // stage transposed weight chunk: Wt[c][kk] = W[k0+kk][c]
        for (int idx = tid; idx < KC * C; idx += TPB) {
            const int kk = idx / C;
            const int c = idx - kk * C;
            Wt[c * WT_LD + kk] = W[(k0 + kk) * C + c];
        }
        __syncthreads();
        constexpr int K4 = KC / 4;
        for (int kk4 = 0; kk4 < K4; ++kk4) {
            const float w0 = Wt[col * WT_LD + kk4 * 4 + 0];
            const float w1 = Wt[col * WT_LD + kk4 * 4 + 1];
            const float w2 = Wt[col * WT_LD + kk4 * 4 + 2];
            const float w3 = Wt[col * WT_LD + kk4 * 4 + 3];
#pragma unroll
            for (int p = 0; p < P; ++p) {
                const float4 av = *reinterpret_cast<const float4*>(
                    &Act[(pbase + p) * ACT_LD + k0 + kk4 * 4]);
                acc[p] = fmaf(av.x, w0, acc[p]);
                acc[p] = fmaf(av.y, w1, acc[p]);
                acc[p] = fmaf(av.z, w2, acc[p]);
                acc[p] = fmaf(av.w, w3, acc[p]);
            }
        }
        if constexpr ((KC % 4) != 0) {
            for (int kk = K4 * 4; kk < KC; ++kk) {
                const float w = Wt[col * WT_LD + kk];
#pragma unroll
                for (int p = 0; p < P; ++p)
                    acc[p] = fmaf(Act[(pbase + p) * ACT_LD + k0 + kk], w, acc[p]);
            }
        }
        __syncthreads();
    }

    const float bv = bias[col];
    if constexpr (MODE == 0) {
        const float a = bn_a[col];
        const float c = bn_c[col];
#pragma unroll
        for (int p = 0; p < P; ++p) {
            const float h = acc[p] + bv;
            Act[(pbase + p) * ACT_LD + col] = fmaxf(fmaf(h, a, c), 0.f);
        }
        __syncthreads();
    } else if constexpr (MODE == 1) {
        float ps = 0.f, pq = 0.f;
#pragma unroll
        for (int p = 0; p < P; ++p) {
            if (pbase + p < nv) {
                const float h = acc[p] + bv;
                ps += h;
                pq += h * h;
            }
        }
        red[tid] = ps;
        red[TPB + tid] = pq;
        __syncthreads();
        if (g == 0) {
            float ts = ps, tq = pq;
            for (int gg = 1; gg < G; ++gg) {
                ts += red[gg * C + col];
                tq += red[TPB + gg * C + col];
            }
            atomicAdd(&gsum[col], ts);
            atomicAdd(&gssq[col], tq);
        }
    } else {
#pragma unroll
        for (int p = 0; p < P; ++p) {
            if (pbase + p < nv) {
                const float h = acc[p] + bv;
                atomicMaxFloat(&out[(size_t)vox[pbase + p] * 256 + col], h);
            }
        }
    }
}

template<int STAGE>
__global__ __launch_bounds__(TPB, 1)
void mlp_pass(const float* __restrict__ feats, const int* __restrict__ coords, int N,
              const float* __restrict__ W1, const float* __restrict__ b1,
              const float* __restrict__ W2, const float* __restrict__ b2,
              const float* __restrict__ W3, const float* __restrict__ b3,
              const float* __restrict__ W4, const float* __restrict__ b4,
              float* __restrict__ ws, float* __restrict__ out)
{
    __shared__ __align__(16) float Act[PTS * ACT_LD];
    __shared__ __align__(16) float Wt[256 * WT_LD];
    __shared__ float red[2 * TPB];
    __shared__ int vox[PTS];

    const int tid = threadIdx.x;
    const int p0 = blockIdx.x * PTS;
    const int nv = min(PTS, N - p0);

    {
        const float* a0 = ws + OFF_A0;
        const float* c0 = ws + OFF_C0;
        for (int idx = tid; idx < PTS * 9; idx += TPB) {
            const int p = idx / 9;
            const int chn = idx - p * 9;
            float v = 0.f;
            if (p < nv) v = fmaf(feats[(size_t)(p0 + p) * 9 + chn], a0[chn], c0[chn]);
            Act[p * ACT_LD + chn] = v;
        }
    }
    if constexpr (STAGE == 4) {
        for (int p = tid; p < PTS; p += TPB) {
            int vv = 0;
            if (p < nv) {
                const int cx = coords[(size_t)(p0 + p) * 3 + 0];
                const int cy = coords[(size_t)(p0 + p) * 3 + 1];
                const int cz = coords[(size_t)(p0 + p) * 3 + 2];
                vv = (cx << 10) | (cy << 5) | cz;
            }
            vox[p] = vv;
        }
    }
    __syncthreads();

    if constexpr (STAGE == 1) {
        dense_layer<64, 9, 1>(W1, b1, nullptr, nullptr, ws + OFF_SUM1, ws + OFF_SSQ1,
                              Act, Wt, red, vox, out, tid, nv);
        return;
    }
    dense_layer<64, 9, 0>(W1, b1, ws + OFF_A1, ws + OFF_C1, nullptr, nullptr,
                          Act, Wt, red, vox, out, tid, nv);
    if constexpr (STAGE == 2) {
        dense_layer<128, 64, 1>(W2, b2, nullptr, nullptr, ws + OFF_SUM2, ws + OFF_SSQ2,
                                Act, Wt, red, vox, out, tid, nv);
        return;
    }
    if constexpr (STAGE >= 3) {
        dense_layer<128, 64, 0>(W2, b2, ws + OFF_A2, ws + OFF_C2, nullptr, nullptr,
                                Act, Wt, red, vox, out, tid, nv);
        if constexpr (STAGE == 3) {
            dense_layer<256, 128, 1>(W3, b3, nullptr, nullptr, ws + OFF_SUM3, ws + OFF_SSQ3,
                                     Act, Wt, red, vox, out, tid, nv);
            return;
        }
        if constexpr (STAGE == 4) {
            dense_layer<256, 128, 0>(W3, b3, ws + OFF_A3, ws + OFF_C3, nullptr, nullptr,
                                     Act, Wt, red, vox, out, tid, nv);
            dense_layer<256, 256, 2>(W4, b4, nullptr, nullptr, nullptr, nullptr,
                                     Act, Wt, red, vox, out, tid, nv);
        }
    }
}

extern "C" void kernel_launch(void* const* d_in, const int* in_sizes, int n_in,
                              void* d_out, int out_size, void* d_ws, size_t ws_size,
                              hipStream_t stream) {
    const float* feats = (const float*)d_in[0];
    const int*   coords = (const int*)d_in[1];
    const float* g0  = (const float*)d_in[3];
    const float* be0 = (const float*)d_in[4];
    const float* W1  = (const float*)d_in[5];
    const float* b1  = (const float*)d_in[6];
    const float* g1  = (const float*)d_in[7];
    const float* be1 = (const float*)d_in[8];
    const float* W2  = (const float*)d_in[9];
    const float* b2  = (const float*)d_in[10];
    const float* g2  = (const float*)d_in[11];
    const float* be2 = (const float*)d_in[12];
    const float* W3  = (const float*)d_in[13];
    const float* b3  = (const float*)d_in[14];
    const float* g3  = (const float*)d_in[15];
    const float* be3 = (const float*)d_in[16];
    const float* W4  = (const float*)d_in[17];
    const float* b4  = (const float*)d_in[18];
    float* out = (float*)d_out;
    float* ws  = (float*)d_ws;

    const int N = in_sizes[0] / 9;
    const int nblk = (N + PTS - 1) / PTS;
    const float fN = (float)N;

    // zero the stats accumulators (ws is poisoned, not re-poisoned between replays)
    hipMemsetAsync(ws, 0, WS_FLOATS * sizeof(float), stream);

    // BN0 stats from raw feats
    k_stats0<<<1024, TPB, 0, stream>>>(feats, N, ws);
    k_fin<<<1, TPB, 0, stream>>>(ws, OFF_SUM0, OFF_SSQ0, OFF_A0, OFF_C0, 9, g0, be0, fN);

    // h1 stats
    mlp_pass<1><<<nblk, TPB, 0, stream>>>(feats, coords, N, W1, b1, W2, b2, W3, b3, W4, b4, ws, out);
    k_fin<<<1, TPB, 0, stream>>>(ws, OFF_SUM1, OFF_SSQ1, OFF_A1, OFF_C1, 64, g1, be1, fN);

    // h2 stats
    mlp_pass<2><<<nblk, TPB, 0, stream>>>(feats, coords, N, W1, b1, W2, b2, W3, b3, W4, b4, ws, out);
    k_fin<<<1, TPB, 0, stream>>>(ws, OFF_SUM2, OFF_SSQ2, OFF_A2, OFF_C2, 128, g2, be2, fN);

    // h3 stats
    mlp_pass<3><<<nblk, TPB, 0, stream>>>(feats, coords, N, W1, b1, W2, b2, W3, b3, W4, b4, ws, out);
    k_fin<<<1, TPB, 0, stream>>>(ws, OFF_SUM3, OFF_SSQ3, OFF_A3, OFF_C3, 256, g3, be3, fN);

    // init outputs, final pass with segment-max scatter
    k_initout<<<2048, TPB, 0, stream>>>(out);
    k_coords<<<(NVOX + TPB - 1) / TPB, TPB, 0, stream>>>(out + (size_t)NVOX * 256);
    mlp_pass<4><<<nblk, TPB, 0, stream>>>(feats, coords, N, W1, b1, W2, b2, W3, b3, W4, b4, ws, out);
}

// Round 2
// 1428.436 us; speedup vs baseline: 12.4909x; 12.4909x over previous
//
#include <hip/hip_runtime.h>
#include <math.h>

#define TPB 256
#define PT 64            // points per tile
#define NVOX 32768
#define VB 8             // voxels per stage-4 block
#define BN_EPS 1e-5f

typedef short s16x8 __attribute__((ext_vector_type(8)));
typedef short s16x4 __attribute__((ext_vector_type(4)));
typedef float f32x4 __attribute__((ext_vector_type(4)));

// ---------------- ws byte offsets ----------------
#define P0_OFF     0u                      // 18 f32 (sum9|ssq9)
#define P1_OFF     256u                    // 64 banks x (64 sum | 64 ssq)
#define P2_OFF     (P1_OFF + 64u*128u*4u)        // 33024
#define P3_OFF     (P2_OFF + 64u*256u*4u)        // 98560
#define PAR_END    (P3_OFF + 64u*512u*4u)        // 229632
#define A0_OFF     229632u
#define C0_OFF     229888u
#define A1_OFF     230144u
#define C1_OFF     230400u
#define A2_OFF     230656u
#define C2_OFF     231680u
#define A3_OFF     232704u
#define C3_OFF     233728u
#define HIST_OFF   234752u                 // 32768 u32
#define BASE_OFF   (HIST_OFF + 131072u)    // 32769 i32 (padded)
#define CURS_OFF   (BASE_OFF + 131328u)    // 32768 u32
#define PERM_OFF   (CURS_OFF + 131072u)    // N u32 (N<=1e6)
#define WT1_OFF    (PERM_OFF + 4000000u)   // 64x32 bf16
#define WT2_OFF    (WT1_OFF + 4096u)       // 128x64
#define WT3_OFF    (WT2_OFF + 16384u)      // 256x128
#define WT4_OFF    (WT3_OFF + 65536u)      // 256x256

// ---------------- LDS byte offsets (dynamic smem) ----------------
#define ACT0_OFF 0        // [64][32]  bf16 = 4096
#define ACT1_OFF 4096     // [64][64]  bf16 = 8192
#define ACT2_OFF 12288    // [64][128] bf16 = 16384
#define ACT3_OFF 32768    // [64][256] bf16 = 32768
#define H4_OFF   0        // [64][256] bf16 = 32768 (reuses act0..act2 region)
#define SMEM_S1  4096
#define SMEM_S2  12288
#define SMEM_S3  28672
#define SMEM_S4  65536

__device__ __forceinline__ unsigned short f2bf(float f) {
    unsigned u = __float_as_uint(f);
    u += 0x7FFFu + ((u >> 16) & 1u);
    return (unsigned short)(u >> 16);
}
__device__ __forceinline__ float bf2f(unsigned short h) {
    return __uint_as_float(((unsigned)h) << 16);
}

template<int ROWB>
__device__ __forceinline__ int swz(int row, int b) {
    constexpr int M = (ROWB >= 128) ? 7 : 3;
    return row * ROWB + (b ^ ((row & M) << 4));
}

// ---------------- small prep kernels ----------------
__global__ void k_prepw(const float* __restrict__ W1, const float* __restrict__ W2,
                        const float* __restrict__ W3, const float* __restrict__ W4,
                        unsigned short* __restrict__ wt1, unsigned short* __restrict__ wt2,
                        unsigned short* __restrict__ wt3, unsigned short* __restrict__ wt4) {
    for (int i = blockIdx.x * blockDim.x + threadIdx.x; i < 108544;
         i += gridDim.x * blockDim.x) {
        if (i < 2048) {
            int n = i >> 5, k = i & 31;
            wt1[i] = (k < 9) ? f2bf(W1[k * 64 + n]) : (unsigned short)0;
        } else if (i < 10240) {
            int j = i - 2048; int n = j >> 6, k = j & 63;
            wt2[j] = f2bf(W2[k * 128 + n]);
        } else if (i < 43008) {
            int j = i - 10240; int n = j >> 7, k = j & 127;
            wt3[j] = f2bf(W3[k * 256 + n]);
        } else {
            int j = i - 43008; int n = j >> 8, k = j & 255;
            wt4[j] = f2bf(W4[k * 256 + n]);
        }
    }
}

__global__ void k_hist(const int* __restrict__ coords, int N, unsigned* __restrict__ hist) {
    for (int i = blockIdx.x * blockDim.x + threadIdx.x; i < N;
         i += gridDim.x * blockDim.x) {
        int v = (coords[3 * i] << 10) | (coords[3 * i + 1] << 5) | coords[3 * i + 2];
        atomicAdd(&hist[v], 1u);
    }
}

__global__ void k_scan(const unsigned* __restrict__ hist, int* __restrict__ base,
                       unsigned* __restrict__ cursor, int N) {
    __shared__ unsigned part[1024];
    const int t = threadIdx.x;
    unsigned sum = 0;
    for (int j = 0; j < 32; ++j) sum += hist[t * 32 + j];
    part[t] = sum;
    __syncthreads();
    for (int d = 1; d < 1024; d <<= 1) {
        unsigned v = (t >= d) ? part[t - d] : 0u;
        __syncthreads();
        part[t] += v;
        __syncthreads();
    }
    unsigned run = part[t] - sum;   // exclusive
    for (int j = 0; j < 32; ++j) {
        unsigned h = hist[t * 32 + j];
        base[t * 32 + j] = (int)run;
        cursor[t * 32 + j] = run;
        run += h;
    }
    if (t == 1023) base[32768] = (int)run;
}

__global__ void k_scatter(const int* __restrict__ coords, int N,
                          unsigned* __restrict__ cursor, int* __restrict__ perm) {
    for (int i = blockIdx.x * blockDim.x + threadIdx.x; i < N;
         i += gridDim.x * blockDim.x) {
        int v = (coords[3 * i] << 10) | (coords[3 * i + 1] << 5) | coords[3 * i + 2];
        unsigned pos = atomicAdd(&cursor[v], 1u);
        perm[pos] = i;
    }
}

__global__ void k_stats0(const float* __restrict__ feats, int N, float* __restrict__ p0) {
    __shared__ float s[9], q[9];
    if (threadIdx.x < 9) { s[threadIdx.x] = 0.f; q[threadIdx.x] = 0.f; }
    __syncthreads();
    float ls[9] = {0}, lq[9] = {0};
    for (size_t i = (size_t)blockIdx.x * blockDim.x + threadIdx.x; i < (size_t)N;
         i += (size_t)gridDim.x * blockDim.x) {
        const float* r = feats + i * 9;
#pragma unroll
        for (int c = 0; c < 9; ++c) { float v = r[c]; ls[c] += v; lq[c] += v * v; }
    }
#pragma unroll
    for (int c = 0; c < 9; ++c) { atomicAdd(&s[c], ls[c]); atomicAdd(&q[c], lq[c]); }
    __syncthreads();
    if (threadIdx.x < 9) {
        atomicAdd(&p0[threadIdx.x], s[threadIdx.x]);
        atomicAdd(&p0[9 + threadIdx.x], q[threadIdx.x]);
    }
}

// A = g*rsqrt(var+eps); C = be - m*A (+ A*bias folded when bias given)
__global__ void k_fin(const float* __restrict__ part, int nparts, int C,
                      const float* __restrict__ g, const float* __restrict__ be,
                      const float* __restrict__ bias,
                      float* __restrict__ A, float* __restrict__ Cc, float n) {
    int c = threadIdx.x;
    if (c >= C) return;
    float s = 0.f, q = 0.f;
    for (int r = 0; r < nparts; ++r) { s += part[r * 2 * C + c]; q += part[r * 2 * C + C + c]; }
    float m = s / n;
    float v = q / n - m * m;
    float a = g[c] * rsqrtf(v + BN_EPS);
    float cc = be[c] - m * a;
    A[c] = a;
    Cc[c] = bias ? fmaf(a, bias[c], cc) : cc;
}

__global__ void k_coords(float* __restrict__ outc) {
    int v = blockIdx.x * blockDim.x + threadIdx.x;
    if (v < NVOX) {
        outc[3 * v + 0] = (float)(v >> 10);
        outc[3 * v + 1] = (float)((v >> 5) & 31);
        outc[3 * v + 2] = (float)(v & 31);
    }
}

// ---------------- fused MLP stage ----------------
// swapped GEMM: H^T = Wt * X^T.  A-frag = weights (global, row-major [out][in] bf16),
// B-frag = activations from LDS [pt][ch] bf16 (XOR-swizzled), C: col=pt(lane&15),
// row=ch((lane>>4)*4+reg).  Waves split the out-channel dim.
// MODE: 0 = hidden (BN+ReLU -> lds_out), 1 = stats (sum/ssq -> part), 2 = final (-> lds_out raw)
template<int NOUT, int K, int MODE>
__device__ __forceinline__ void layer(
    const unsigned short* __restrict__ wt,
    const char* __restrict__ lds_in, char* __restrict__ lds_out,
    const float* __restrict__ Af, const float* __restrict__ Cf,
    const float* __restrict__ bias, float* __restrict__ part,
    int p0, int N, int tid) {
    constexpr int ROWB_IN = K * 2;
    constexpr int ROWB_OUT = NOUT * 2;
    constexpr int MT = NOUT / 64;
    constexpr int KC = K / 32;
    const int w = tid >> 6, lane = tid & 63, g = lane >> 4, lq = lane & 15;
    const int chbase = w * (NOUT / 4);

    f32x4 acc[MT][4];
#pragma unroll
    for (int mt = 0; mt < MT; ++mt)
#pragma unroll
        for (int ct = 0; ct < 4; ++ct) acc[mt][ct] = (f32x4){0.f, 0.f, 0.f, 0.f};

#pragma unroll
    for (int kc = 0; kc < KC; ++kc) {
        s16x8 a[MT];
#pragma unroll
        for (int mt = 0; mt < MT; ++mt)
            a[mt] = *(const s16x8*)(wt + (size_t)(chbase + mt * 16 + lq) * K + kc * 32 + g * 8);
#pragma unroll
        for (int ct = 0; ct < 4; ++ct) {
            const int row = ct * 16 + lq;
            s16x8 b = *(const s16x8*)(lds_in + swz<ROWB_IN>(row, kc * 64 + g * 16));
#pragma unroll
            for (int mt = 0; mt < MT; ++mt)
                acc[mt][ct] = __builtin_amdgcn_mfma_f32_16x16x32_bf16(a[mt], b, acc[mt][ct], 0, 0, 0);
        }
    }

    if constexpr (MODE == 0) {
#pragma unroll
        for (int mt = 0; mt < MT; ++mt) {
            const int ch = chbase + mt * 16 + g * 4;
            const f32x4 av = *(const f32x4*)(Af + ch);
            const f32x4 cv = *(const f32x4*)(Cf + ch);
#pragma unroll
            for (int ct = 0; ct < 4; ++ct) {
                const int row = ct * 16 + lq;
                s16x4 pk;
#pragma unroll
                for (int r = 0; r < 4; ++r)
                    pk[r] = (short)f2bf(fmaxf(fmaf(acc[mt][ct][r], av[r], cv[r]), 0.f));
                *(s16x4*)(lds_out + swz<ROWB_OUT>(row, ch * 2)) = pk;
            }
        }
    } else if constexpr (MODE == 1) {
#pragma unroll
        for (int mt = 0; mt < MT; ++mt) {
            const int ch = chbase + mt * 16 + g * 4;
            const f32x4 bv = *(const f32x4*)(bias + ch);
            f32x4 ps = (f32x4){0.f, 0.f, 0.f, 0.f}, pq = (f32x4){0.f, 0.f, 0.f, 0.f};
#pragma unroll
            for (int ct = 0; ct < 4; ++ct) {
                const bool valid = (p0 + ct * 16 + lq) < N;
#pragma unroll
                for (int r = 0; r < 4; ++r) {
                    float h = valid ? (acc[mt][ct][r] + bv[r]) : 0.f;
                    ps[r] += h; pq[r] += h * h;
                }
            }
#pragma unroll
            for (int m = 1; m <= 8; m <<= 1) {
#pragma unroll
                for (int r = 0; r < 4; ++r) {
                    ps[r] += __shfl_xor(ps[r], m);
                    pq[r] += __shfl_xor(pq[r], m);
                }
            }
            if (lq == 0) {
#pragma unroll
                for (int r = 0; r < 4; ++r) {
                    atomicAdd(&part[ch + r], ps[r]);
                    atomicAdd(&part[NOUT + ch + r], pq[r]);
                }
            }
        }
    } else {
#pragma unroll
        for (int mt = 0; mt < MT; ++mt) {
            const int ch = chbase + mt * 16 + g * 4;
            const f32x4 bv = *(const f32x4*)(bias + ch);
#pragma unroll
            for (int ct = 0; ct < 4; ++ct) {
                const int row = ct * 16 + lq;
                s16x4 pk;
#pragma unroll
                for (int r = 0; r < 4; ++r)
                    pk[r] = (short)f2bf(acc[mt][ct][r] + bv[r]);
                *(s16x4*)(lds_out + swz<ROWB_OUT>(row, ch * 2)) = pk;
            }
        }
    }
}

__device__ __forceinline__ void stage_act0(const float* __restrict__ feats,
                                           const float* __restrict__ A0,
                                           const float* __restrict__ C0,
                                           const int* __restrict__ perm,
                                           int t0, int pend, char* act0, int tid) {
    *(f32x4*)(act0 + tid * 16) = (f32x4){0.f, 0.f, 0.f, 0.f};  // zero [64][32] bf16
    __syncthreads();
    for (int idx = tid; idx < PT * 9; idx += TPB) {
        const int p = idx / 9, ch = idx - p * 9;
        const int gp = t0 + p;
        if (gp < pend) {
            const int src = perm ? perm[gp] : gp;
            float v = fmaf(feats[(size_t)src * 9 + ch], A0[ch], C0[ch]);
            *(unsigned short*)(act0 + swz<64>(p, ch * 2)) = f2bf(v);
        }
    }
}

template<int STAGE>
__global__ __launch_bounds__(TPB, 2) void k_stage(
    const float* __restrict__ feats, char* __restrict__ ws,
    const float* __restrict__ b1, const float* __restrict__ b2,
    const float* __restrict__ b3, const float* __restrict__ b4,
    float* __restrict__ out, int N) {
    extern __shared__ char smem[];
    char* act0 = smem + ACT0_OFF;
    char* act1 = smem + ACT1_OFF;
    char* act2 = smem + ACT2_OFF;
    char* act3 = smem + ACT3_OFF;
    char* h4   = smem + H4_OFF;

    const int tid = threadIdx.x;
    const float* A0 = (const float*)(ws + A0_OFF);
    const float* C0 = (const float*)(ws + C0_OFF);
    const float* A1 = (const float*)(ws + A1_OFF);
    const float* C1 = (const float*)(ws + C1_OFF);
    const float* A2 = (const float*)(ws + A2_OFF);
    const float* C2 = (const float*)(ws + C2_OFF);
    const float* A3 = (const float*)(ws + A3_OFF);
    const float* C3 = (const float*)(ws + C3_OFF);
    const unsigned short* Wt1 = (const unsigned short*)(ws + WT1_OFF);
    const unsigned short* Wt2 = (const unsigned short*)(ws + WT2_OFF);
    const unsigned short* Wt3 = (const unsigned short*)(ws + WT3_OFF);
    const unsigned short* Wt4 = (const unsigned short*)(ws + WT4_OFF);

    if constexpr (STAGE < 4) {
        const int t0 = blockIdx.x * PT;
        stage_act0(feats, A0, C0, nullptr, t0, N, act0, tid);
        __syncthreads();
        if constexpr (STAGE == 1) {
            float* prow = (float*)(ws + P1_OFF) + (blockIdx.x & 63) * 128;
            layer<64, 32, 1>(Wt1, act0, nullptr, nullptr, nullptr, b1, prow, t0, N, tid);
            return;
        }
        layer<64, 32, 0>(Wt1, act0, act1, A1, C1, nullptr, nullptr, t0, N, tid);
        __syncthreads();
        if constexpr (STAGE == 2) {
            float* prow = (float*)(ws + P2_OFF) + (blockIdx.x & 63) * 256;
            layer<128, 64, 1>(Wt2, act1, nullptr, nullptr, nullptr, b2, prow, t0, N, tid);
            return;
        }
        layer<128, 64, 0>(Wt2, act1, act2, A2, C2, nullptr, nullptr, t0, N, tid);
        __syncthreads();
        float* prow = (float*)(ws + P3_OFF) + (blockIdx.x & 63) * 512;
        layer<256, 128, 1>(Wt3, act2, nullptr, nullptr, nullptr, b3, prow, t0, N, tid);
    } else {
        const int* base = (const int*)(ws + BASE_OFF);
        const int* perm = (const int*)(ws + PERM_OFF);
        const int vb = blockIdx.x * VB;
        const int pstart = base[vb], pend = base[vb + VB];
        const int chgrp = tid & 31, slot = tid >> 5;
        const int vlo = base[vb + slot], vhi = base[vb + slot + 1];
        float rmax[8];
#pragma unroll
        for (int j = 0; j < 8; ++j) rmax[j] = -INFINITY;

        for (int t0 = pstart; t0 < pend; t0 += PT) {
            stage_act0(feats, A0, C0, perm, t0, pend, act0, tid);
            __syncthreads();
            layer<64, 32, 0>(Wt1, act0, act1, A1, C1, nullptr, nullptr, t0, N, tid);
            __syncthreads();
            layer<128, 64, 0>(Wt2, act1, act2, A2, C2, nullptr, nullptr, t0, N, tid);
            __syncthreads();
            layer<256, 128, 0>(Wt3, act2, act3, A3, C3, nullptr, nullptr, t0, N, tid);
            __syncthreads();
            layer<256, 256, 2>(Wt4, act3, h4, nullptr, nullptr, b4, nullptr, t0, N, tid);
            __syncthreads();
            const int lo = max(vlo, t0), hi = min(vhi, t0 + PT);
            for (int p = lo; p < hi; ++p) {
                const int row = p - t0;
                s16x8 hv = *(const s16x8*)(h4 + swz<512>(row, chgrp * 16));
#pragma unroll
                for (int j = 0; j < 8; ++j)
                    rmax[j] = fmaxf(rmax[j], bf2f((unsigned short)hv[j]));
            }
            __syncthreads();
        }
        float* orow = out + (size_t)(vb + slot) * 256 + chgrp * 8;
        f32x4 o0, o1;
#pragma unroll
        for (int j = 0; j < 4; ++j) { o0[j] = rmax[j]; o1[j] = rmax[4 + j]; }
        *(f32x4*)orow = o0;
        *(f32x4*)(orow + 4) = o1;
    }
}

extern "C" void kernel_launch(void* const* d_in, const int* in_sizes, int n_in,
                              void* d_out, int out_size, void* d_ws, size_t ws_size,
                              hipStream_t stream) {
    const float* feats = (const float*)d_in[0];
    const int* coords = (const int*)d_in[1];
    const float* g0 = (const float*)d_in[3];
    const float* be0 = (const float*)d_in[4];
    const float* W1 = (const float*)d_in[5];
    const float* b1 = (const float*)d_in[6];
    const float* g1 = (const float*)d_in[7];
    const float* be1 = (const float*)d_in[8];
    const float* W2 = (const float*)d_in[9];
    const float* b2 = (const float*)d_in[10];
    const float* g2 = (const float*)d_in[11];
    const float* be2 = (const float*)d_in[12];
    const float* W3 = (const float*)d_in[13];
    const float* b3 = (const float*)d_in[14];
    const float* g3 = (const float*)d_in[15];
    const float* be3 = (const float*)d_in[16];
    const float* W4 = (const float*)d_in[17];
    const float* b4 = (const float*)d_in[18];
    float* out = (float*)d_out;
    char* ws = (char*)d_ws;

    const int N = in_sizes[0] / 9;
    const float fN = (float)N;
    const int nblk = (N + PT - 1) / PT;

    hipMemsetAsync(ws, 0, PAR_END, stream);                  // stats partials
    hipMemsetAsync(ws + HIST_OFF, 0, 131072, stream);        // histogram

    k_prepw<<<128, TPB, 0, stream>>>(W1, W2, W3, W4,
        (unsigned short*)(ws + WT1_OFF), (unsigned short*)(ws + WT2_OFF),
        (unsigned short*)(ws + WT3_OFF), (unsigned short*)(ws + WT4_OFF));
    k_hist<<<1024, TPB, 0, stream>>>(coords, N, (unsigned*)(ws + HIST_OFF));
    k_scan<<<1, 1024, 0, stream>>>((const unsigned*)(ws + HIST_OFF),
                                   (int*)(ws + BASE_OFF), (unsigned*)(ws + CURS_OFF), N);
    k_scatter<<<1024, TPB, 0, stream>>>(coords, N, (unsigned*)(ws + CURS_OFF),
                                        (int*)(ws + PERM_OFF));

    k_stats0<<<256, TPB, 0, stream>>>(feats, N, (float*)(ws + P0_OFF));
    k_fin<<<1, TPB, 0, stream>>>((const float*)(ws + P0_OFF), 1, 9, g0, be0, nullptr,
                                 (float*)(ws + A0_OFF), (float*)(ws + C0_OFF), fN);

    k_stage<1><<<nblk, TPB, SMEM_S1, stream>>>(feats, ws, b1, b2, b3, b4, out, N);
    k_fin<<<1, TPB, 0, stream>>>((const float*)(ws + P1_OFF), 64, 64, g1, be1, b1,
                                 (float*)(ws + A1_OFF), (float*)(ws + C1_OFF), fN);

    k_stage<2><<<nblk, TPB, SMEM_S2, stream>>>(feats, ws, b1, b2, b3, b4, out, N);
    k_fin<<<1, TPB, 0, stream>>>((const float*)(ws + P2_OFF), 64, 128, g2, be2, b2,
                                 (float*)(ws + A2_OFF), (float*)(ws + C2_OFF), fN);

    k_stage<3><<<nblk, TPB, SMEM_S3, stream>>>(feats, ws, b1, b2, b3, b4, out, N);
    k_fin<<<1, TPB, 0, stream>>>((const float*)(ws + P3_OFF), 64, 256, g3, be3, b3,
                                 (float*)(ws + A3_OFF), (float*)(ws + C3_OFF), fN);

    k_coords<<<(NVOX + TPB - 1) / TPB, TPB, 0, stream>>>(out + (size_t)NVOX * 256);
    k_stage<4><<<NVOX / VB, TPB, SMEM_S4, stream>>>(feats, ws, b1, b2, b3, b4, out, N);
}

// Round 3
// 1426.236 us; speedup vs baseline: 12.5101x; 1.0015x over previous
//
#include <hip/hip_runtime.h>
#include <math.h>

#define TPB 256
#define PT 64            // points per tile (legacy path)
#define NVOX 32768
#define VB 8             // voxels per stage-4 block (legacy path)
#define BN_EPS 1e-5f

typedef short s16x8 __attribute__((ext_vector_type(8)));
typedef short s16x4 __attribute__((ext_vector_type(4)));
typedef float f32x4 __attribute__((ext_vector_type(4)));

// ---------------- ws byte offsets ----------------
#define P0_OFF     0u                      // 18 f32 (sum9|ssq9)
#define P1_OFF     256u                    // 64 banks x (64 sum | 64 ssq)
#define P2_OFF     (P1_OFF + 64u*128u*4u)        // 33024
#define P3_OFF     (P2_OFF + 64u*256u*4u)        // 98560
#define PAR_END    (P3_OFF + 64u*512u*4u)        // 229632
#define A0_OFF     229632u
#define C0_OFF     229888u
#define A1_OFF     230144u
#define C1_OFF     230400u
#define A2_OFF     230656u
#define C2_OFF     231680u
#define A3_OFF     232704u
#define C3_OFF     233728u
#define HIST_OFF   234752u                 // 32768 u32
#define BASE_OFF   (HIST_OFF + 131072u)    // 32769 i32 (padded)
#define CURS_OFF   (BASE_OFF + 131328u)    // 32768 u32
#define PERM_OFF   (CURS_OFF + 131072u)    // N u32 (N<=1e6)
#define WT1_OFF    (PERM_OFF + 4000000u)   // 64x32 bf16
#define WT2_OFF    (WT1_OFF + 4096u)       // 128x64
#define WT3_OFF    (WT2_OFF + 16384u)      // 256x128
#define WT4_OFF    (WT3_OFF + 65536u)      // 256x256
#define H1_OFF     4845568u                // streaming path: h1 bf16 [N][64]

// ---------------- LDS byte offsets (legacy path) ----------------
#define ACT0_OFF 0        // [64][32]  bf16 = 4096
#define ACT1_OFF 4096     // [64][64]  bf16 = 8192
#define ACT2_OFF 12288    // [64][128] bf16 = 16384
#define ACT3_OFF 32768    // [64][256] bf16 = 32768
#define H4_OFF   0        // [64][256] bf16 = 32768
#define SMEM_S1  4096
#define SMEM_S2  12288
#define SMEM_S3  28672
#define SMEM_S4  65536

__device__ __forceinline__ unsigned short f2bf(float f) {
    unsigned u = __float_as_uint(f);
    u += 0x7FFFu + ((u >> 16) & 1u);
    return (unsigned short)(u >> 16);
}
__device__ __forceinline__ float bf2f(unsigned short h) {
    return __uint_as_float(((unsigned)h) << 16);
}

template<int ROWB>
__device__ __forceinline__ int swz(int row, int b) {
    constexpr int M = (ROWB >= 128) ? 7 : 3;
    return row * ROWB + (b ^ ((row & M) << 4));
}

// ---------------- small prep kernels ----------------
__global__ void k_prepw(const float* __restrict__ W1, const float* __restrict__ W2,
                        const float* __restrict__ W3, const float* __restrict__ W4,
                        unsigned short* __restrict__ wt1, unsigned short* __restrict__ wt2,
                        unsigned short* __restrict__ wt3, unsigned short* __restrict__ wt4) {
    for (int i = blockIdx.x * blockDim.x + threadIdx.x; i < 108544;
         i += gridDim.x * blockDim.x) {
        if (i < 2048) {
            int n = i >> 5, k = i & 31;
            wt1[i] = (k < 9) ? f2bf(W1[k * 64 + n]) : (unsigned short)0;
        } else if (i < 10240) {
            int j = i - 2048; int n = j >> 6, k = j & 63;
            wt2[j] = f2bf(W2[k * 128 + n]);
        } else if (i < 43008) {
            int j = i - 10240; int n = j >> 7, k = j & 127;
            wt3[j] = f2bf(W3[k * 256 + n]);
        } else {
            int j = i - 43008; int n = j >> 8, k = j & 255;
            wt4[j] = f2bf(W4[k * 256 + n]);
        }
    }
}

__global__ void k_hist(const int* __restrict__ coords, int N, unsigned* __restrict__ hist) {
    for (int i = blockIdx.x * blockDim.x + threadIdx.x; i < N;
         i += gridDim.x * blockDim.x) {
        int v = (coords[3 * i] << 10) | (coords[3 * i + 1] << 5) | coords[3 * i + 2];
        atomicAdd(&hist[v], 1u);
    }
}

__global__ void k_scan(const unsigned* __restrict__ hist, int* __restrict__ base,
                       unsigned* __restrict__ cursor, int N) {
    __shared__ unsigned part[1024];
    const int t = threadIdx.x;
    unsigned sum = 0;
    for (int j = 0; j < 32; ++j) sum += hist[t * 32 + j];
    part[t] = sum;
    __syncthreads();
    for (int d = 1; d < 1024; d <<= 1) {
        unsigned v = (t >= d) ? part[t - d] : 0u;
        __syncthreads();
        part[t] += v;
        __syncthreads();
    }
    unsigned run = part[t] - sum;   // exclusive
    for (int j = 0; j < 32; ++j) {
        unsigned h = hist[t * 32 + j];
        base[t * 32 + j] = (int)run;
        cursor[t * 32 + j] = run;
        run += h;
    }
    if (t == 1023) base[32768] = (int)run;
}

__global__ void k_scatter(const int* __restrict__ coords, int N,
                          unsigned* __restrict__ cursor, int* __restrict__ perm) {
    for (int i = blockIdx.x * blockDim.x + threadIdx.x; i < N;
         i += gridDim.x * blockDim.x) {
        int v = (coords[3 * i] << 10) | (coords[3 * i + 1] << 5) | coords[3 * i + 2];
        unsigned pos = atomicAdd(&cursor[v], 1u);
        perm[pos] = i;
    }
}

__global__ void k_stats0(const float* __restrict__ feats, int N, float* __restrict__ p0) {
    __shared__ float s[9], q[9];
    if (threadIdx.x < 9) { s[threadIdx.x] = 0.f; q[threadIdx.x] = 0.f; }
    __syncthreads();
    float ls[9] = {0}, lq[9] = {0};
    for (size_t i = (size_t)blockIdx.x * blockDim.x + threadIdx.x; i < (size_t)N;
         i += (size_t)gridDim.x * blockDim.x) {
        const float* r = feats + i * 9;
#pragma unroll
        for (int c = 0; c < 9; ++c) { float v = r[c]; ls[c] += v; lq[c] += v * v; }
    }
#pragma unroll
    for (int c = 0; c < 9; ++c) { atomicAdd(&s[c], ls[c]); atomicAdd(&q[c], lq[c]); }
    __syncthreads();
    if (threadIdx.x < 9) {
        atomicAdd(&p0[threadIdx.x], s[threadIdx.x]);
        atomicAdd(&p0[9 + threadIdx.x], q[threadIdx.x]);
    }
}

// A = g*rsqrt(var+eps); C = be - m*A (+ A*bias folded when bias given)
__global__ void k_fin(const float* __restrict__ part, int nparts, int C,
                      const float* __restrict__ g, const float* __restrict__ be,
                      const float* __restrict__ bias,
                      float* __restrict__ A, float* __restrict__ Cc, float n) {
    int c = threadIdx.x;
    if (c >= C) return;
    float s = 0.f, q = 0.f;
    for (int r = 0; r < nparts; ++r) { s += part[r * 2 * C + c]; q += part[r * 2 * C + C + c]; }
    float m = s / n;
    float v = q / n - m * m;
    float a = g[c] * rsqrtf(v + BN_EPS);
    float cc = be[c] - m * a;
    A[c] = a;
    Cc[c] = bias ? fmaf(a, bias[c], cc) : cc;
}

__global__ void k_coords(float* __restrict__ outc) {
    int v = blockIdx.x * blockDim.x + threadIdx.x;
    if (v < NVOX) {
        outc[3 * v + 0] = (float)(v >> 10);
        outc[3 * v + 1] = (float)((v >> 5) & 31);
        outc[3 * v + 2] = (float)(v & 31);
    }
}

// =====================================================================
// STREAMING PATH: one layer per pass, stats fused in epilogue,
// pre-BN activations stored to global (bf16, voxel-sorted order).
// =====================================================================

// GEMM pass: h_out[N][NOUT] = act_in @ W (swapped MFMA: A=weights, B=points).
// GATHER=1: input = permuted feats fp32 (K=32 padded, BN0 applied).
// GATHER=0: input = linear bf16 h_in, BN(Ain,Cin)+ReLU applied during staging.
// Epilogue: store pre-BN h_out bf16 + accumulate sum/ssq of (h+bias) partials.
template<int K, int NOUT, int GATHER>
__global__ __launch_bounds__(256, 2) void k_passS(
    const float* __restrict__ feats,
    const unsigned short* __restrict__ hin,
    const unsigned short* __restrict__ wt,
    const float* __restrict__ Ain, const float* __restrict__ Cin,
    const float* __restrict__ bias,
    const int* __restrict__ perm,
    unsigned short* __restrict__ hout,
    float* __restrict__ partb,
    int N) {
    constexpr int PTS = 128;
    constexpr int ROWB = K * 2;
    constexpr int MT = NOUT / 64;
    constexpr int KC = K / 32;
    extern __shared__ char smem[];
    const int tid = threadIdx.x;
    const int t0 = blockIdx.x * PTS;

    if constexpr (GATHER) {
        for (int i = tid; i < PTS * K * 2 / 16; i += 256)
            *(f32x4*)(smem + i * 16) = (f32x4){0.f, 0.f, 0.f, 0.f};
        __syncthreads();
        for (int idx = tid; idx < PTS * 9; idx += 256) {
            const int p = idx / 9, ch = idx - p * 9;
            const int gp = t0 + p;
            if (gp < N) {
                const int src = perm[gp];
                float v = fmaf(feats[(size_t)src * 9 + ch], Ain[ch], Cin[ch]);
                *(unsigned short*)(smem + swz<ROWB>(p, ch * 2)) = f2bf(v);
            }
        }
    } else {
        constexpr int CH = K / 8;
        for (int it = 0; it < PTS * CH / 256; ++it) {
            const int idx = tid + it * 256;
            const int row = idx / CH, c8 = (idx - row * CH) * 8;
            s16x8 pk = (s16x8){0, 0, 0, 0, 0, 0, 0, 0};
            const int gp = t0 + row;
            if (gp < N) {
                const s16x8 v = *(const s16x8*)(hin + (size_t)gp * K + c8);
                const f32x4 a0 = *(const f32x4*)(Ain + c8);
                const f32x4 a1 = *(const f32x4*)(Ain + c8 + 4);
                const f32x4 c0 = *(const f32x4*)(Cin + c8);
                const f32x4 c1 = *(const f32x4*)(Cin + c8 + 4);
#pragma unroll
                for (int j = 0; j < 4; ++j) {
                    pk[j]     = (short)f2bf(fmaxf(fmaf(bf2f((unsigned short)v[j]), a0[j], c0[j]), 0.f));
                    pk[4 + j] = (short)f2bf(fmaxf(fmaf(bf2f((unsigned short)v[4 + j]), a1[j], c1[j]), 0.f));
                }
            }
            *(s16x8*)(smem + swz<ROWB>(row, c8 * 2)) = pk;
        }
    }
    __syncthreads();

    const int w = tid >> 6, lane = tid & 63, g = lane >> 4, lq = lane & 15;
    const int chbase = w * (NOUT / 4);

    f32x4 acc[MT][8];
#pragma unroll
    for (int mt = 0; mt < MT; ++mt)
#pragma unroll
        for (int ct = 0; ct < 8; ++ct) acc[mt][ct] = (f32x4){0.f, 0.f, 0.f, 0.f};

#pragma unroll
    for (int kc = 0; kc < KC; ++kc) {
        s16x8 a[MT];
#pragma unroll
        for (int mt = 0; mt < MT; ++mt)
            a[mt] = *(const s16x8*)(wt + (size_t)(chbase + mt * 16 + lq) * K + kc * 32 + g * 8);
#pragma unroll
        for (int ct = 0; ct < 8; ++ct) {
            const s16x8 b = *(const s16x8*)(smem + swz<ROWB>(ct * 16 + lq, kc * 64 + g * 16));
#pragma unroll
            for (int mt = 0; mt < MT; ++mt)
                acc[mt][ct] = __builtin_amdgcn_mfma_f32_16x16x32_bf16(a[mt], b, acc[mt][ct], 0, 0, 0);
        }
    }

    float* prow = partb + (blockIdx.x & 63) * (2 * NOUT);
#pragma unroll
    for (int mt = 0; mt < MT; ++mt) {
        const int ch = chbase + mt * 16 + g * 4;
        const f32x4 bv = *(const f32x4*)(bias + ch);
        f32x4 ps = (f32x4){0.f, 0.f, 0.f, 0.f}, pq = (f32x4){0.f, 0.f, 0.f, 0.f};
#pragma unroll
        for (int ct = 0; ct < 8; ++ct) {
            const int gp = t0 + ct * 16 + lq;
            const bool valid = gp < N;
            if (valid) {
                s16x4 pk;
#pragma unroll
                for (int r = 0; r < 4; ++r) pk[r] = (short)f2bf(acc[mt][ct][r]);
                *(s16x4*)(hout + (size_t)gp * NOUT + ch) = pk;
            }
#pragma unroll
            for (int r = 0; r < 4; ++r) {
                const float h = valid ? (acc[mt][ct][r] + bv[r]) : 0.f;
                ps[r] += h; pq[r] += h * h;
            }
        }
#pragma unroll
        for (int m = 1; m <= 8; m <<= 1) {
#pragma unroll
            for (int r = 0; r < 4; ++r) {
                ps[r] += __shfl_xor(ps[r], m);
                pq[r] += __shfl_xor(pq[r], m);
            }
        }
        if (lq == 0) {
#pragma unroll
            for (int r = 0; r < 4; ++r) {
                atomicAdd(&prow[ch + r], ps[r]);
                atomicAdd(&prow[NOUT + ch + r], pq[r]);
            }
        }
    }
}

// Final pass: h3 -> BN3+ReLU -> L4 GEMM (W4 persistent in VGPRs) -> segment-max.
// 512 threads, 32 voxels/block, 64-pt tiles, LDS: act3 32KB + h4 32KB.
__global__ __launch_bounds__(512, 4) void k_pass4(
    const unsigned short* __restrict__ h3,
    const unsigned short* __restrict__ wt4,
    const float* __restrict__ A3, const float* __restrict__ C3,
    const float* __restrict__ b4,
    const int* __restrict__ base,
    float* __restrict__ out) {
    extern __shared__ char smem[];
    char* act3 = smem;            // [64][256] bf16 swizzled
    char* h4   = smem + 32768;    // [64][256] bf16 swizzled

    const int tid = threadIdx.x;
    const int w = tid >> 6, lane = tid & 63, g = lane >> 4, lq = lane & 15;
    const int chbase = w * 32;
    const int vb = blockIdx.x * 32;
    const int pstart = base[vb], pend = base[vb + 32];
    const int chgrp = tid & 31, slot = tid >> 5;   // 16 slots
    int vlo[2], vhi[2];
#pragma unroll
    for (int r = 0; r < 2; ++r) {
        vlo[r] = base[vb + r * 16 + slot];
        vhi[r] = base[vb + r * 16 + slot + 1];
    }

    s16x8 wreg[2][8];
#pragma unroll
    for (int mt = 0; mt < 2; ++mt)
#pragma unroll
        for (int kc = 0; kc < 8; ++kc)
            wreg[mt][kc] = *(const s16x8*)(wt4 + (size_t)(chbase + mt * 16 + lq) * 256 + kc * 32 + g * 8);

    float rmax[2][8];
#pragma unroll
    for (int r = 0; r < 2; ++r)
#pragma unroll
        for (int j = 0; j < 8; ++j) rmax[r][j] = -INFINITY;

    for (int t0 = pstart; t0 < pend; t0 += 64) {
        // stage h3 tile with BN3+ReLU: 64 rows x 32 chunks / 512 thr = 4 iters
#pragma unroll
        for (int it = 0; it < 4; ++it) {
            const int idx = tid + it * 512;
            const int row = idx >> 5, c8 = (idx & 31) * 8;
            s16x8 pk = (s16x8){0, 0, 0, 0, 0, 0, 0, 0};
            const int gp = t0 + row;
            if (gp < pend) {
                const s16x8 v = *(const s16x8*)(h3 + (size_t)gp * 256 + c8);
                const f32x4 a0 = *(const f32x4*)(A3 + c8);
                const f32x4 a1 = *(const f32x4*)(A3 + c8 + 4);
                const f32x4 c0 = *(const f32x4*)(C3 + c8);
                const f32x4 c1 = *(const f32x4*)(C3 + c8 + 4);
#pragma unroll
                for (int j = 0; j < 4; ++j) {
                    pk[j]     = (short)f2bf(fmaxf(fmaf(bf2f((unsigned short)v[j]), a0[j], c0[j]), 0.f));
                    pk[4 + j] = (short)f2bf(fmaxf(fmaf(bf2f((unsigned short)v[4 + j]), a1[j], c1[j]), 0.f));
                }
            }
            *(s16x8*)(act3 + swz<512>(row, c8 * 2)) = pk;
        }
        __syncthreads();

        f32x4 acc[2][4];
#pragma unroll
        for (int mt = 0; mt < 2; ++mt)
#pragma unroll
            for (int ct = 0; ct < 4; ++ct) acc[mt][ct] = (f32x4){0.f, 0.f, 0.f, 0.f};
#pragma unroll
        for (int kc = 0; kc < 8; ++kc) {
#pragma unroll
            for (int ct = 0; ct < 4; ++ct) {
                const s16x8 b = *(const s16x8*)(act3 + swz<512>(ct * 16 + lq, kc * 64 + g * 16));
#pragma unroll
                for (int mt = 0; mt < 2; ++mt)
                    acc[mt][ct] = __builtin_amdgcn_mfma_f32_16x16x32_bf16(wreg[mt][kc], b, acc[mt][ct], 0, 0, 0);
            }
        }
#pragma unroll
        for (int mt = 0; mt < 2; ++mt) {
            const int ch = chbase + mt * 16 + g * 4;
            const f32x4 bv = *(const f32x4*)(b4 + ch);
#pragma unroll
            for (int ct = 0; ct < 4; ++ct) {
                s16x4 pk;
#pragma unroll
                for (int r = 0; r < 4; ++r) pk[r] = (short)f2bf(acc[mt][ct][r] + bv[r]);
                *(s16x4*)(h4 + swz<512>(ct * 16 + lq, ch * 2)) = pk;
            }
        }
        __syncthreads();
#pragma unroll
        for (int r = 0; r < 2; ++r) {
            const int lo = max(vlo[r], t0), hi = min(vhi[r], t0 + 64);
            for (int p = lo; p < hi; ++p) {
                const s16x8 hv = *(const s16x8*)(h4 + swz<512>(p - t0, chgrp * 16));
#pragma unroll
                for (int j = 0; j < 8; ++j)
                    rmax[r][j] = fmaxf(rmax[r][j], bf2f((unsigned short)hv[j]));
            }
        }
        __syncthreads();
    }
#pragma unroll
    for (int r = 0; r < 2; ++r) {
        float* orow = out + (size_t)(vb + r * 16 + slot) * 256 + chgrp * 8;
        f32x4 o0, o1;
#pragma unroll
        for (int j = 0; j < 4; ++j) { o0[j] = rmax[r][j]; o1[j] = rmax[r][4 + j]; }
        *(f32x4*)orow = o0;
        *(f32x4*)(orow + 4) = o1;
    }
}

// =====================================================================
// LEGACY PATH (round-2 kernels, used if ws too small for streaming)
// =====================================================================
template<int NOUT, int K, int MODE>
__device__ __forceinline__ void layer(
    const unsigned short* __restrict__ wt,
    const char* __restrict__ lds_in, char* __restrict__ lds_out,
    const float* __restrict__ Af, const float* __restrict__ Cf,
    const float* __restrict__ bias, float* __restrict__ part,
    int p0, int N, int tid) {
    constexpr int ROWB_IN = K * 2;
    constexpr int ROWB_OUT = NOUT * 2;
    constexpr int MT = NOUT / 64;
    constexpr int KC = K / 32;
    const int w = tid >> 6, lane = tid & 63, g = lane >> 4, lq = lane & 15;
    const int chbase = w * (NOUT / 4);

    f32x4 acc[MT][4];
#pragma unroll
    for (int mt = 0; mt < MT; ++mt)
#pragma unroll
        for (int ct = 0; ct < 4; ++ct) acc[mt][ct] = (f32x4){0.f, 0.f, 0.f, 0.f};

#pragma unroll
    for (int kc = 0; kc < KC; ++kc) {
        s16x8 a[MT];
#pragma unroll
        for (int mt = 0; mt < MT; ++mt)
            a[mt] = *(const s16x8*)(wt + (size_t)(chbase + mt * 16 + lq) * K + kc * 32 + g * 8);
#pragma unroll
        for (int ct = 0; ct < 4; ++ct) {
            const int row = ct * 16 + lq;
            s16x8 b = *(const s16x8*)(lds_in + swz<ROWB_IN>(row, kc * 64 + g * 16));
#pragma unroll
            for (int mt = 0; mt < MT; ++mt)
                acc[mt][ct] = __builtin_amdgcn_mfma_f32_16x16x32_bf16(a[mt], b, acc[mt][ct], 0, 0, 0);
        }
    }

    if constexpr (MODE == 0) {
#pragma unroll
        for (int mt = 0; mt < MT; ++mt) {
            const int ch = chbase + mt * 16 + g * 4;
            const f32x4 av = *(const f32x4*)(Af + ch);
            const f32x4 cv = *(const f32x4*)(Cf + ch);
#pragma unroll
            for (int ct = 0; ct < 4; ++ct) {
                const int row = ct * 16 + lq;
                s16x4 pk;
#pragma unroll
                for (int r = 0; r < 4; ++r)
                    pk[r] = (short)f2bf(fmaxf(fmaf(acc[mt][ct][r], av[r], cv[r]), 0.f));
                *(s16x4*)(lds_out + swz<ROWB_OUT>(row, ch * 2)) = pk;
            }
        }
    } else if constexpr (MODE == 1) {
#pragma unroll
        for (int mt = 0; mt < MT; ++mt) {
            const int ch = chbase + mt * 16 + g * 4;
            const f32x4 bv = *(const f32x4*)(bias + ch);
            f32x4 ps = (f32x4){0.f, 0.f, 0.f, 0.f}, pq = (f32x4){0.f, 0.f, 0.f, 0.f};
#pragma unroll
            for (int ct = 0; ct < 4; ++ct) {
                const bool valid = (p0 + ct * 16 + lq) < N;
#pragma unroll
                for (int r = 0; r < 4; ++r) {
                    float h = valid ? (acc[mt][ct][r] + bv[r]) : 0.f;
                    ps[r] += h; pq[r] += h * h;
                }
            }
#pragma unroll
            for (int m = 1; m <= 8; m <<= 1) {
#pragma unroll
                for (int r = 0; r < 4; ++r) {
                    ps[r] += __shfl_xor(ps[r], m);
                    pq[r] += __shfl_xor(pq[r], m);
                }
            }
            if (lq == 0) {
#pragma unroll
                for (int r = 0; r < 4; ++r) {
                    atomicAdd(&part[ch + r], ps[r]);
                    atomicAdd(&part[NOUT + ch + r], pq[r]);
                }
            }
        }
    } else {
#pragma unroll
        for (int mt = 0; mt < MT; ++mt) {
            const int ch = chbase + mt * 16 + g * 4;
            const f32x4 bv = *(const f32x4*)(bias + ch);
#pragma unroll
            for (int ct = 0; ct < 4; ++ct) {
                const int row = ct * 16 + lq;
                s16x4 pk;
#pragma unroll
                for (int r = 0; r < 4; ++r)
                    pk[r] = (short)f2bf(acc[mt][ct][r] + bv[r]);
                *(s16x4*)(lds_out + swz<ROWB_OUT>(row, ch * 2)) = pk;
            }
        }
    }
}

__device__ __forceinline__ void stage_act0(const float* __restrict__ feats,
                                           const float* __restrict__ A0,
                                           const float* __restrict__ C0,
                                           const int* __restrict__ perm,
                                           int t0, int pend, char* act0, int tid) {
    *(f32x4*)(act0 + tid * 16) = (f32x4){0.f, 0.f, 0.f, 0.f};
    __syncthreads();
    for (int idx = tid; idx < PT * 9; idx += TPB) {
        const int p = idx / 9, ch = idx - p * 9;
        const int gp = t0 + p;
        if (gp < pend) {
            const int src = perm ? perm[gp] : gp;
            float v = fmaf(feats[(size_t)src * 9 + ch], A0[ch], C0[ch]);
            *(unsigned short*)(act0 + swz<64>(p, ch * 2)) = f2bf(v);
        }
    }
}

template<int STAGE>
__global__ __launch_bounds__(TPB, 2) void k_stage(
    const float* __restrict__ feats, char* __restrict__ ws,
    const float* __restrict__ b1, const float* __restrict__ b2,
    const float* __restrict__ b3, const float* __restrict__ b4,
    float* __restrict__ out, int N) {
    extern __shared__ char smem[];
    char* act0 = smem + ACT0_OFF;
    char* act1 = smem + ACT1_OFF;
    char* act2 = smem + ACT2_OFF;
    char* act3 = smem + ACT3_OFF;
    char* h4   = smem + H4_OFF;

    const int tid = threadIdx.x;
    const float* A0 = (const float*)(ws + A0_OFF);
    const float* C0 = (const float*)(ws + C0_OFF);
    const float* A1 = (const float*)(ws + A1_OFF);
    const float* C1 = (const float*)(ws + C1_OFF);
    const float* A2 = (const float*)(ws + A2_OFF);
    const float* C2 = (const float*)(ws + C2_OFF);
    const float* A3 = (const float*)(ws + A3_OFF);
    const float* C3 = (const float*)(ws + C3_OFF);
    const unsigned short* Wt1 = (const unsigned short*)(ws + WT1_OFF);
    const unsigned short* Wt2 = (const unsigned short*)(ws + WT2_OFF);
    const unsigned short* Wt3 = (const unsigned short*)(ws + WT3_OFF);
    const unsigned short* Wt4 = (const unsigned short*)(ws + WT4_OFF);

    if constexpr (STAGE < 4) {
        const int t0 = blockIdx.x * PT;
        stage_act0(feats, A0, C0, nullptr, t0, N, act0, tid);
        __syncthreads();
        if constexpr (STAGE == 1) {
            float* prow = (float*)(ws + P1_OFF) + (blockIdx.x & 63) * 128;
            layer<64, 32, 1>(Wt1, act0, nullptr, nullptr, nullptr, b1, prow, t0, N, tid);
            return;
        }
        layer<64, 32, 0>(Wt1, act0, act1, A1, C1, nullptr, nullptr, t0, N, tid);
        __syncthreads();
        if constexpr (STAGE == 2) {
            float* prow = (float*)(ws + P2_OFF) + (blockIdx.x & 63) * 256;
            layer<128, 64, 1>(Wt2, act1, nullptr, nullptr, nullptr, b2, prow, t0, N, tid);
            return;
        }
        layer<128, 64, 0>(Wt2, act1, act2, A2, C2, nullptr, nullptr, t0, N, tid);
        __syncthreads();
        float* prow = (float*)(ws + P3_OFF) + (blockIdx.x & 63) * 512;
        layer<256, 128, 1>(Wt3, act2, nullptr, nullptr, nullptr, b3, prow, t0, N, tid);
    } else {
        const int* base = (const int*)(ws + BASE_OFF);
        const int* perm = (const int*)(ws + PERM_OFF);
        const int vb = blockIdx.x * VB;
        const int pstart = base[vb], pend = base[vb + VB];
        const int chgrp = tid & 31, slot = tid >> 5;
        const int vlo = base[vb + slot], vhi = base[vb + slot + 1];
        float rmax[8];
#pragma unroll
        for (int j = 0; j < 8; ++j) rmax[j] = -INFINITY;

        for (int t0 = pstart; t0 < pend; t0 += PT) {
            stage_act0(feats, A0, C0, perm, t0, pend, act0, tid);
            __syncthreads();
            layer<64, 32, 0>(Wt1, act0, act1, A1, C1, nullptr, nullptr, t0, N, tid);
            __syncthreads();
            layer<128, 64, 0>(Wt2, act1, act2, A2, C2, nullptr, nullptr, t0, N, tid);
            __syncthreads();
            layer<256, 128, 0>(Wt3, act2, act3, A3, C3, nullptr, nullptr, t0, N, tid);
            __syncthreads();
            layer<256, 256, 2>(Wt4, act3, h4, nullptr, nullptr, b4, nullptr, t0, N, tid);
            __syncthreads();
            const int lo = max(vlo, t0), hi = min(vhi, t0 + PT);
            for (int p = lo; p < hi; ++p) {
                const int row = p - t0;
                s16x8 hv = *(const s16x8*)(h4 + swz<512>(row, chgrp * 16));
#pragma unroll
                for (int j = 0; j < 8; ++j)
                    rmax[j] = fmaxf(rmax[j], bf2f((unsigned short)hv[j]));
            }
            __syncthreads();
        }
        float* orow = out + (size_t)(vb + slot) * 256 + chgrp * 8;
        f32x4 o0, o1;
#pragma unroll
        for (int j = 0; j < 4; ++j) { o0[j] = rmax[j]; o1[j] = rmax[4 + j]; }
        *(f32x4*)orow = o0;
        *(f32x4*)(orow + 4) = o1;
    }
}

extern "C" void kernel_launch(void* const* d_in, const int* in_sizes, int n_in,
                              void* d_out, int out_size, void* d_ws, size_t ws_size,
                              hipStream_t stream) {
    const float* feats = (const float*)d_in[0];
    const int* coords = (const int*)d_in[1];
    const float* g0 = (const float*)d_in[3];
    const float* be0 = (const float*)d_in[4];
    const float* W1 = (const float*)d_in[5];
    const float* b1 = (const float*)d_in[6];
    const float* g1 = (const float*)d_in[7];
    const float* be1 = (const float*)d_in[8];
    const float* W2 = (const float*)d_in[9];
    const float* b2 = (const float*)d_in[10];
    const float* g2 = (const float*)d_in[11];
    const float* be2 = (const float*)d_in[12];
    const float* W3 = (const float*)d_in[13];
    const float* b3 = (const float*)d_in[14];
    const float* g3 = (const float*)d_in[15];
    const float* be3 = (const float*)d_in[16];
    const float* W4 = (const float*)d_in[17];
    const float* b4 = (const float*)d_in[18];
    float* out = (float*)d_out;
    char* ws = (char*)d_ws;

    const int N = in_sizes[0] / 9;
    const float fN = (float)N;

    hipMemsetAsync(ws, 0, PAR_END, stream);                  // stats partials
    hipMemsetAsync(ws + HIST_OFF, 0, 131072, stream);        // histogram

    k_prepw<<<128, TPB, 0, stream>>>(W1, W2, W3, W4,
        (unsigned short*)(ws + WT1_OFF), (unsigned short*)(ws + WT2_OFF),
        (unsigned short*)(ws + WT3_OFF), (unsigned short*)(ws + WT4_OFF));
    k_hist<<<1024, TPB, 0, stream>>>(coords, N, (unsigned*)(ws + HIST_OFF));
    k_scan<<<1, 1024, 0, stream>>>((const unsigned*)(ws + HIST_OFF),
                                   (int*)(ws + BASE_OFF), (unsigned*)(ws + CURS_OFF), N);
    k_scatter<<<1024, TPB, 0, stream>>>(coords, N, (unsigned*)(ws + CURS_OFF),
                                        (int*)(ws + PERM_OFF));

    k_stats0<<<256, TPB, 0, stream>>>(feats, N, (float*)(ws + P0_OFF));
    k_fin<<<1, TPB, 0, stream>>>((const float*)(ws + P0_OFF), 1, 9, g0, be0, nullptr,
                                 (float*)(ws + A0_OFF), (float*)(ws + C0_OFF), fN);

    k_coords<<<(NVOX + TPB - 1) / TPB, TPB, 0, stream>>>(out + (size_t)NVOX * 256);

    const size_t need = (size_t)H1_OFF + (size_t)N * 896u;
    if (ws_size >= need) {
        // ---------- streaming path ----------
        unsigned short* H1 = (unsigned short*)(ws + H1_OFF);
        unsigned short* H2 = (unsigned short*)(ws + H1_OFF + (size_t)N * 128u);
        unsigned short* H3 = (unsigned short*)(ws + H1_OFF + (size_t)N * 384u);
        const int nblk = (N + 127) / 128;

        k_passS<32, 64, 1><<<nblk, 256, 8192, stream>>>(
            feats, nullptr, (const unsigned short*)(ws + WT1_OFF),
            (const float*)(ws + A0_OFF), (const float*)(ws + C0_OFF), b1,
            (const int*)(ws + PERM_OFF), H1, (float*)(ws + P1_OFF), N);
        k_fin<<<1, TPB, 0, stream>>>((const float*)(ws + P1_OFF), 64, 64, g1, be1, b1,
                                     (float*)(ws + A1_OFF), (float*)(ws + C1_OFF), fN);

        k_passS<64, 128, 0><<<nblk, 256, 16384, stream>>>(
            nullptr, H1, (const unsigned short*)(ws + WT2_OFF),
            (const float*)(ws + A1_OFF), (const float*)(ws + C1_OFF), b2,
            nullptr, H2, (float*)(ws + P2_OFF), N);
        k_fin<<<1, TPB, 0, stream>>>((const float*)(ws + P2_OFF), 64, 128, g2, be2, b2,
                                     (float*)(ws + A2_OFF), (float*)(ws + C2_OFF), fN);

        k_passS<128, 256, 0><<<nblk, 256, 32768, stream>>>(
            nullptr, H2, (const unsigned short*)(ws + WT3_OFF),
            (const float*)(ws + A2_OFF), (const float*)(ws + C2_OFF), b3,
            nullptr, H3, (float*)(ws + P3_OFF), N);
        k_fin<<<1, TPB, 0, stream>>>((const float*)(ws + P3_OFF), 64, 256, g3, be3, b3,
                                     (float*)(ws + A3_OFF), (float*)(ws + C3_OFF), fN);

        k_pass4<<<NVOX / 32, 512, 65536, stream>>>(
            H3, (const unsigned short*)(ws + WT4_OFF),
            (const float*)(ws + A3_OFF), (const float*)(ws + C3_OFF), b4,
            (const int*)(ws + BASE_OFF), out);
    } else {
        // ---------- legacy path ----------
        const int nblk = (N + PT - 1) / PT;
        k_stage<1><<<nblk, TPB, SMEM_S1, stream>>>(feats, ws, b1, b2, b3, b4, out, N);
        k_fin<<<1, TPB, 0, stream>>>((const float*)(ws + P1_OFF), 64, 64, g1, be1, b1,
                                     (float*)(ws + A1_OFF), (float*)(ws + C1_OFF), fN);
        k_stage<2><<<nblk, TPB, SMEM_S2, stream>>>(feats, ws, b1, b2, b3, b4, out, N);
        k_fin<<<1, TPB, 0, stream>>>((const float*)(ws + P2_OFF), 64, 128, g2, be2, b2,
                                     (float*)(ws + A2_OFF), (float*)(ws + C2_OFF), fN);
        k_stage<3><<<nblk, TPB, SMEM_S3, stream>>>(feats, ws, b1, b2, b3, b4, out, N);
        k_fin<<<1, TPB, 0, stream>>>((const float*)(ws + P3_OFF), 64, 256, g3, be3, b3,
                                     (float*)(ws + A3_OFF), (float*)(ws + C3_OFF), fN);
        k_stage<4><<<NVOX / VB, TPB, SMEM_S4, stream>>>(feats, ws, b1, b2, b3, b4, out, N);
    }
}

// Round 4
// 1013.639 us; speedup vs baseline: 17.6023x; 1.4070x over previous
//
#include <hip/hip_runtime.h>
#include <math.h>

#define TPB 256
#define PT 64            // points per tile (legacy path)
#define NVOX 32768
#define VB 8             // voxels per stage-4 block (legacy path)
#define BN_EPS 1e-5f

typedef short s16x8 __attribute__((ext_vector_type(8)));
typedef short s16x4 __attribute__((ext_vector_type(4)));
typedef float f32x4 __attribute__((ext_vector_type(4)));

// ---------------- ws byte offsets ----------------
#define P0_OFF     0u                      // 18 f32 (sum9|ssq9)
#define P1_OFF     256u                    // 64 banks x (64 sum | 64 ssq)
#define P2_OFF     (P1_OFF + 64u*128u*4u)
#define P3_OFF     (P2_OFF + 64u*256u*4u)
#define PAR_END    (P3_OFF + 64u*512u*4u)        // 229632
#define A0_OFF     229632u
#define C0_OFF     229888u
#define A1_OFF     230144u
#define C1_OFF     230400u
#define A2_OFF     230656u
#define C2_OFF     231680u
#define A3_OFF     232704u
#define C3_OFF     233728u
#define HIST_OFF   234752u                 // 32768 u32
#define BASE_OFF   (HIST_OFF + 131072u)    // 32769 i32 (padded)
#define CURS_OFF   (BASE_OFF + 131328u)    // 32768 u32
#define PERM_OFF   (CURS_OFF + 131072u)    // N u32 (N<=1e6)
#define WT1_OFF    (PERM_OFF + 4000000u)   // 64x32 bf16 (K-padded)
#define WT2_OFF    (WT1_OFF + 4096u)       // 128x64
#define WT3_OFF    (WT2_OFF + 16384u)      // 256x128
#define WT4_OFF    (WT3_OFF + 65536u)      // 256x256
#define X_OFF      4845568u                // X bf16 [Npad][16] (BN0-applied, voxel-sorted)

// ---------------- LDS byte offsets (legacy path) ----------------
#define ACT0_OFF 0
#define ACT1_OFF 4096
#define ACT2_OFF 12288
#define ACT3_OFF 32768
#define H4_OFF   0
#define SMEM_S1  4096
#define SMEM_S2  12288
#define SMEM_S3  28672
#define SMEM_S4  65536

__device__ __forceinline__ unsigned short f2bf(float f) {
    unsigned u = __float_as_uint(f);
    u += 0x7FFFu + ((u >> 16) & 1u);
    return (unsigned short)(u >> 16);
}
__device__ __forceinline__ float bf2f(unsigned short h) {
    return __uint_as_float(((unsigned)h) << 16);
}

template<int ROWB>
__device__ __forceinline__ int swz(int row, int b) {
    constexpr int M = (ROWB >= 128) ? 7 : ((ROWB >= 64) ? 3 : 1);
    return row * ROWB + (b ^ ((row & M) << 4));
}

__device__ __forceinline__ s16x4 bn_relu_pack(f32x4 acc, f32x4 av, f32x4 cv) {
    s16x4 pk;
#pragma unroll
    for (int r = 0; r < 4; ++r) pk[r] = (short)f2bf(fmaxf(fmaf(acc[r], av[r], cv[r]), 0.f));
    return pk;
}

template<int NOUT>
__device__ __forceinline__ void stats_red(f32x4 ps, f32x4 pq, int ch, float* prow) {
#pragma unroll
    for (int m = 1; m <= 8; m <<= 1) {
#pragma unroll
        for (int r = 0; r < 4; ++r) { ps[r] += __shfl_xor(ps[r], m); pq[r] += __shfl_xor(pq[r], m); }
    }
    if ((threadIdx.x & 15) == 0) {
#pragma unroll
        for (int r = 0; r < 4; ++r) {
            atomicAdd(&prow[ch + r], ps[r]);
            atomicAdd(&prow[NOUT + ch + r], pq[r]);
        }
    }
}

// ---------------- small prep kernels ----------------
__global__ void k_prepw(const float* __restrict__ W1, const float* __restrict__ W2,
                        const float* __restrict__ W3, const float* __restrict__ W4,
                        unsigned short* __restrict__ wt1, unsigned short* __restrict__ wt2,
                        unsigned short* __restrict__ wt3, unsigned short* __restrict__ wt4) {
    for (int i = blockIdx.x * blockDim.x + threadIdx.x; i < 108544;
         i += gridDim.x * blockDim.x) {
        if (i < 2048) {
            int n = i >> 5, k = i & 31;
            wt1[i] = (k < 9) ? f2bf(W1[k * 64 + n]) : (unsigned short)0;
        } else if (i < 10240) {
            int j = i - 2048; int n = j >> 6, k = j & 63;
            wt2[j] = f2bf(W2[k * 128 + n]);
        } else if (i < 43008) {
            int j = i - 10240; int n = j >> 7, k = j & 127;
            wt3[j] = f2bf(W3[k * 256 + n]);
        } else {
            int j = i - 43008; int n = j >> 8, k = j & 255;
            wt4[j] = f2bf(W4[k * 256 + n]);
        }
    }
}

__global__ void k_hist(const int* __restrict__ coords, int N, unsigned* __restrict__ hist) {
    for (int i = blockIdx.x * blockDim.x + threadIdx.x; i < N;
         i += gridDim.x * blockDim.x) {
        int v = (coords[3 * i] << 10) | (coords[3 * i + 1] << 5) | coords[3 * i + 2];
        atomicAdd(&hist[v], 1u);
    }
}

__global__ void k_scan(const unsigned* __restrict__ hist, int* __restrict__ base,
                       unsigned* __restrict__ cursor, int N) {
    __shared__ unsigned part[1024];
    const int t = threadIdx.x;
    unsigned sum = 0;
    for (int j = 0; j < 32; ++j) sum += hist[t * 32 + j];
    part[t] = sum;
    __syncthreads();
    for (int d = 1; d < 1024; d <<= 1) {
        unsigned v = (t >= d) ? part[t - d] : 0u;
        __syncthreads();
        part[t] += v;
        __syncthreads();
    }
    unsigned run = part[t] - sum;   // exclusive
    for (int j = 0; j < 32; ++j) {
        unsigned h = hist[t * 32 + j];
        base[t * 32 + j] = (int)run;
        cursor[t * 32 + j] = run;
        run += h;
    }
    if (t == 1023) base[32768] = (int)run;
}

__global__ void k_scatter(const int* __restrict__ coords, int N,
                          unsigned* __restrict__ cursor, int* __restrict__ perm) {
    for (int i = blockIdx.x * blockDim.x + threadIdx.x; i < N;
         i += gridDim.x * blockDim.x) {
        int v = (coords[3 * i] << 10) | (coords[3 * i + 1] << 5) | coords[3 * i + 2];
        unsigned pos = atomicAdd(&cursor[v], 1u);
        perm[pos] = i;
    }
}

__global__ void k_stats0(const float* __restrict__ feats, int N, float* __restrict__ p0) {
    __shared__ float s[9], q[9];
    if (threadIdx.x < 9) { s[threadIdx.x] = 0.f; q[threadIdx.x] = 0.f; }
    __syncthreads();
    float ls[9] = {0}, lq[9] = {0};
    for (size_t i = (size_t)blockIdx.x * blockDim.x + threadIdx.x; i < (size_t)N;
         i += (size_t)gridDim.x * blockDim.x) {
        const float* r = feats + i * 9;
#pragma unroll
        for (int c = 0; c < 9; ++c) { float v = r[c]; ls[c] += v; lq[c] += v * v; }
    }
#pragma unroll
    for (int c = 0; c < 9; ++c) { atomicAdd(&s[c], ls[c]); atomicAdd(&q[c], lq[c]); }
    __syncthreads();
    if (threadIdx.x < 9) {
        atomicAdd(&p0[threadIdx.x], s[threadIdx.x]);
        atomicAdd(&p0[9 + threadIdx.x], q[threadIdx.x]);
    }
}

__global__ void k_fin(const float* __restrict__ part, int nparts, int C,
                      const float* __restrict__ g, const float* __restrict__ be,
                      const float* __restrict__ bias,
                      float* __restrict__ A, float* __restrict__ Cc, float n) {
    int c = threadIdx.x;
    if (c >= C) return;
    float s = 0.f, q = 0.f;
    for (int r = 0; r < nparts; ++r) { s += part[r * 2 * C + c]; q += part[r * 2 * C + C + c]; }
    float m = s / n;
    float v = q / n - m * m;
    float a = g[c] * rsqrtf(v + BN_EPS);
    float cc = be[c] - m * a;
    A[c] = a;
    Cc[c] = bias ? fmaf(a, bias[c], cc) : cc;
}

__global__ void k_coords(float* __restrict__ outc) {
    int v = blockIdx.x * blockDim.x + threadIdx.x;
    if (v < NVOX) {
        outc[3 * v + 0] = (float)(v >> 10);
        outc[3 * v + 1] = (float)((v >> 5) & 31);
        outc[3 * v + 2] = (float)(v & 31);
    }
}

// =====================================================================
// STREAMING PATH
// X = BN0(feats) permuted, bf16 [Npad][16] (32B rows). LDS tiles pad K to 32.
// Swapped GEMM everywhere: A=weights (lane lq = out-ch row, g = K-group),
// B=points from LDS (lq = pt col, g = K-group); C row = g*4+reg, col = lq.
// =====================================================================

// pass1: gather+BN0 -> X dump + L1 stats
__global__ __launch_bounds__(256, 4) void k_pass1(
    const float* __restrict__ feats, const int* __restrict__ perm,
    const unsigned short* __restrict__ wt1,
    const float* __restrict__ A0, const float* __restrict__ C0,
    const float* __restrict__ b1,
    unsigned short* __restrict__ Xg, float* __restrict__ p1,
    int N, int nt) {
    __shared__ char Xl[8192];   // [128][64B] swz
    const int tid = threadIdx.x;
    const int w = tid >> 6, lane = tid & 63, g = lane >> 4, lq = lane & 15;
    const int chb = w * 16;
    const s16x8 a1 = *(const s16x8*)(wt1 + (chb + lq) * 32 + g * 8);
    const int ch = chb + g * 4;
    const f32x4 bv = *(const f32x4*)(b1 + ch);
    float* prow = p1 + (blockIdx.x & 63) * 128;

    for (int t = blockIdx.x; t < nt; t += gridDim.x) {
        const int t0 = t * 128;
        *(f32x4*)(Xl + tid * 32) = (f32x4){0.f, 0.f, 0.f, 0.f};
        *(f32x4*)(Xl + tid * 32 + 16) = (f32x4){0.f, 0.f, 0.f, 0.f};
        __syncthreads();
        for (int idx = tid; idx < 128 * 9; idx += 256) {
            const int p = idx / 9, c = idx - p * 9;
            const int gp = t0 + p;
            if (gp < N) {
                const int src = perm[gp];
                float v = fmaf(feats[(size_t)src * 9 + c], A0[c], C0[c]);
                *(unsigned short*)(Xl + swz<64>(p, c * 2)) = f2bf(v);
            }
        }
        __syncthreads();
        {   // dump X tile (32B global rows; upper 16 LDS bytes are pad)
            const int row = tid >> 1, c = (tid & 1) * 16;
            *(s16x8*)(Xg + (size_t)(t0 + row) * 16 + c / 2) =
                *(const s16x8*)(Xl + swz<64>(row, c));
        }
        // L1: MT1 CT8 KC1
        f32x4 acc[8];
#pragma unroll
        for (int ct = 0; ct < 8; ++ct) acc[ct] = (f32x4){0.f, 0.f, 0.f, 0.f};
#pragma unroll
        for (int ct = 0; ct < 8; ++ct) {
            const s16x8 b = *(const s16x8*)(Xl + swz<64>(ct * 16 + lq, g * 16));
            acc[ct] = __builtin_amdgcn_mfma_f32_16x16x32_bf16(a1, b, acc[ct], 0, 0, 0);
        }
        f32x4 ps = (f32x4){0.f,0.f,0.f,0.f}, pq = (f32x4){0.f,0.f,0.f,0.f};
#pragma unroll
        for (int ct = 0; ct < 8; ++ct) {
            const bool valid = (t0 + ct * 16 + lq) < N;
#pragma unroll
            for (int r = 0; r < 4; ++r) {
                const float h = valid ? (acc[ct][r] + bv[r]) : 0.f;
                ps[r] += h; pq[r] += h * h;
            }
        }
        stats_red<64>(ps, pq, ch, prow);
        __syncthreads();
    }
}

// pass2: X -> L1 -> BN1+ReLU -> L2 stats
__global__ __launch_bounds__(256, 2) void k_pass2(
    const unsigned short* __restrict__ Xg,
    const unsigned short* __restrict__ wt1, const unsigned short* __restrict__ wt2,
    const float* __restrict__ A1, const float* __restrict__ C1,
    const float* __restrict__ b2,
    float* __restrict__ p2, int N, int nt) {
    __shared__ char smem[40960];   // Wt2l 16K | Xl 8K | act1 16K
    char* Wt2l = smem;
    char* Xl   = smem + 16384;
    char* act1 = smem + 24576;
    const int tid = threadIdx.x;
    const int w = tid >> 6, lane = tid & 63, g = lane >> 4, lq = lane & 15;
    const int chb1 = w * 16, chb2 = w * 32;

    for (int i = tid; i < 1024; i += 256) {
        const int row = i >> 3, c = (i & 7) * 16;
        *(s16x8*)(Wt2l + swz<128>(row, c)) = *(const s16x8*)(wt2 + row * 64 + c / 2);
    }
    const s16x8 a1 = *(const s16x8*)(wt1 + (chb1 + lq) * 32 + g * 8);
    const int ch1 = chb1 + g * 4;
    const f32x4 av1 = *(const f32x4*)(A1 + ch1);
    const f32x4 cv1 = *(const f32x4*)(C1 + ch1);
    f32x4 bv2[2];
#pragma unroll
    for (int mt = 0; mt < 2; ++mt) bv2[mt] = *(const f32x4*)(b2 + chb2 + mt * 16 + g * 4);
    float* prow = p2 + (blockIdx.x & 63) * 256;

    for (int t = blockIdx.x; t < nt; t += gridDim.x) {
        const int t0 = t * 128;
        for (int i = tid; i < 512; i += 256) {
            const int row = i >> 2, c = (i & 3) * 16;
            s16x8 v = (s16x8){0,0,0,0,0,0,0,0};
            if (c < 32) v = *(const s16x8*)(Xg + (size_t)(t0 + row) * 16 + c / 2);
            *(s16x8*)(Xl + swz<64>(row, c)) = v;
        }
        __syncthreads();
        // L1
        f32x4 acc1[8];
#pragma unroll
        for (int ct = 0; ct < 8; ++ct) acc1[ct] = (f32x4){0.f,0.f,0.f,0.f};
#pragma unroll
        for (int ct = 0; ct < 8; ++ct) {
            const s16x8 b = *(const s16x8*)(Xl + swz<64>(ct * 16 + lq, g * 16));
            acc1[ct] = __builtin_amdgcn_mfma_f32_16x16x32_bf16(a1, b, acc1[ct], 0, 0, 0);
        }
#pragma unroll
        for (int ct = 0; ct < 8; ++ct)
            *(s16x4*)(act1 + swz<128>(ct * 16 + lq, ch1 * 2)) = bn_relu_pack(acc1[ct], av1, cv1);
        __syncthreads();
        // L2: MT2 CT8 KC2
        f32x4 acc2[2][8];
#pragma unroll
        for (int mt = 0; mt < 2; ++mt)
#pragma unroll
            for (int ct = 0; ct < 8; ++ct) acc2[mt][ct] = (f32x4){0.f,0.f,0.f,0.f};
#pragma unroll
        for (int kc = 0; kc < 2; ++kc) {
            s16x8 a[2];
#pragma unroll
            for (int mt = 0; mt < 2; ++mt)
                a[mt] = *(const s16x8*)(Wt2l + swz<128>(chb2 + mt * 16 + lq, kc * 64 + g * 16));
#pragma unroll
            for (int ct = 0; ct < 8; ++ct) {
                const s16x8 b = *(const s16x8*)(act1 + swz<128>(ct * 16 + lq, kc * 64 + g * 16));
#pragma unroll
                for (int mt = 0; mt < 2; ++mt)
                    acc2[mt][ct] = __builtin_amdgcn_mfma_f32_16x16x32_bf16(a[mt], b, acc2[mt][ct], 0, 0, 0);
            }
        }
#pragma unroll
        for (int mt = 0; mt < 2; ++mt) {
            f32x4 ps = (f32x4){0.f,0.f,0.f,0.f}, pq = (f32x4){0.f,0.f,0.f,0.f};
#pragma unroll
            for (int ct = 0; ct < 8; ++ct) {
                const bool valid = (t0 + ct * 16 + lq) < N;
#pragma unroll
                for (int r = 0; r < 4; ++r) {
                    const float h = valid ? (acc2[mt][ct][r] + bv2[mt][r]) : 0.f;
                    ps[r] += h; pq[r] += h * h;
                }
            }
            stats_red<128>(ps, pq, chb2 + mt * 16 + g * 4, prow);
        }
        __syncthreads();
    }
}

// pass3: X -> L1 -> L2 -> L3 stats.  W3 in VGPRs.
__global__ __launch_bounds__(512, 2) void k_pass3(
    const unsigned short* __restrict__ Xg,
    const unsigned short* __restrict__ wt1, const unsigned short* __restrict__ wt2,
    const unsigned short* __restrict__ wt3,
    const float* __restrict__ A1, const float* __restrict__ C1,
    const float* __restrict__ A2, const float* __restrict__ C2,
    const float* __restrict__ b3,
    float* __restrict__ p3, int N, int nt) {
    extern __shared__ char smem[];
    char* Wt2l = smem;             // 16K
    char* act1 = smem + 16384;     // 16K [128][128B]
    char* act2 = smem + 32768;     // 32K [128][256B]; Xl aliases first 8K
    char* Xl   = smem + 32768;
    const int tid = threadIdx.x;
    const int w = tid >> 6, lane = tid & 63, g = lane >> 4, lq = lane & 15;
    const int wm = w >> 1, wn = w & 1;
    const int chb1 = wm * 16, chb2 = w * 16, chb3 = w * 32;

    for (int i = tid; i < 1024; i += 512) {
        const int row = i >> 3, c = (i & 7) * 16;
        *(s16x8*)(Wt2l + swz<128>(row, c)) = *(const s16x8*)(wt2 + row * 64 + c / 2);
    }
    s16x8 w3[2][4];
#pragma unroll
    for (int mt = 0; mt < 2; ++mt)
#pragma unroll
        for (int kc = 0; kc < 4; ++kc)
            w3[mt][kc] = *(const s16x8*)(wt3 + (size_t)(chb3 + mt * 16 + lq) * 128 + kc * 32 + g * 8);
    const s16x8 a1 = *(const s16x8*)(wt1 + (chb1 + lq) * 32 + g * 8);
    const int ch1 = chb1 + g * 4, ch2 = chb2 + g * 4;
    const f32x4 av1 = *(const f32x4*)(A1 + ch1);
    const f32x4 cv1 = *(const f32x4*)(C1 + ch1);
    const f32x4 av2 = *(const f32x4*)(A2 + ch2);
    const f32x4 cv2 = *(const f32x4*)(C2 + ch2);
    f32x4 bv3[2];
#pragma unroll
    for (int mt = 0; mt < 2; ++mt) bv3[mt] = *(const f32x4*)(b3 + chb3 + mt * 16 + g * 4);
    float* prow = p3 + (blockIdx.x & 63) * 512;

    for (int t = blockIdx.x; t < nt; t += gridDim.x) {
        const int t0 = t * 128;
        {
            const int row = tid >> 2, c = (tid & 3) * 16;
            s16x8 v = (s16x8){0,0,0,0,0,0,0,0};
            if (c < 32) v = *(const s16x8*)(Xg + (size_t)(t0 + row) * 16 + c / 2);
            *(s16x8*)(Xl + swz<64>(row, c)) = v;
        }
        __syncthreads();
        // L1: waves split points (wn), MT1 CT4
        f32x4 acc1[4];
#pragma unroll
        for (int ct = 0; ct < 4; ++ct) acc1[ct] = (f32x4){0.f,0.f,0.f,0.f};
#pragma unroll
        for (int ct = 0; ct < 4; ++ct) {
            const int row = wn * 64 + ct * 16 + lq;
            const s16x8 b = *(const s16x8*)(Xl + swz<64>(row, g * 16));
            acc1[ct] = __builtin_amdgcn_mfma_f32_16x16x32_bf16(a1, b, acc1[ct], 0, 0, 0);
        }
#pragma unroll
        for (int ct = 0; ct < 4; ++ct) {
            const int row = wn * 64 + ct * 16 + lq;
            *(s16x4*)(act1 + swz<128>(row, ch1 * 2)) = bn_relu_pack(acc1[ct], av1, cv1);
        }
        __syncthreads();
        // L2: MT1 CT8 KC2
        f32x4 acc2[8];
#pragma unroll
        for (int ct = 0; ct < 8; ++ct) acc2[ct] = (f32x4){0.f,0.f,0.f,0.f};
#pragma unroll
        for (int kc = 0; kc < 2; ++kc) {
            const s16x8 a = *(const s16x8*)(Wt2l + swz<128>(chb2 + lq, kc * 64 + g * 16));
#pragma unroll
            for (int ct = 0; ct < 8; ++ct) {
                const s16x8 b = *(const s16x8*)(act1 + swz<128>(ct * 16 + lq, kc * 64 + g * 16));
                acc2[ct] = __builtin_amdgcn_mfma_f32_16x16x32_bf16(a, b, acc2[ct], 0, 0, 0);
            }
        }
#pragma unroll
        for (int ct = 0; ct < 8; ++ct)
            *(s16x4*)(act2 + swz<256>(ct * 16 + lq, ch2 * 2)) = bn_relu_pack(acc2[ct], av2, cv2);
        __syncthreads();
        // L3: MT2 CT8 KC4
        f32x4 acc3[2][8];
#pragma unroll
        for (int mt = 0; mt < 2; ++mt)
#pragma unroll
            for (int ct = 0; ct < 8; ++ct) acc3[mt][ct] = (f32x4){0.f,0.f,0.f,0.f};
#pragma unroll
        for (int kc = 0; kc < 4; ++kc) {
#pragma unroll
            for (int ct = 0; ct < 8; ++ct) {
                const s16x8 b = *(const s16x8*)(act2 + swz<256>(ct * 16 + lq, kc * 64 + g * 16));
#pragma unroll
                for (int mt = 0; mt < 2; ++mt)
                    acc3[mt][ct] = __builtin_amdgcn_mfma_f32_16x16x32_bf16(w3[mt][kc], b, acc3[mt][ct], 0, 0, 0);
            }
        }
#pragma unroll
        for (int mt = 0; mt < 2; ++mt) {
            f32x4 ps = (f32x4){0.f,0.f,0.f,0.f}, pq = (f32x4){0.f,0.f,0.f,0.f};
#pragma unroll
            for (int ct = 0; ct < 8; ++ct) {
                const bool valid = (t0 + ct * 16 + lq) < N;
#pragma unroll
                for (int r = 0; r < 4; ++r) {
                    const float h = valid ? (acc3[mt][ct][r] + bv3[mt][r]) : 0.f;
                    ps[r] += h; pq[r] += h * h;
                }
            }
            stats_red<256>(ps, pq, chb3 + mt * 16 + g * 4, prow);
        }
        __syncthreads();
    }
}

// pass4: X -> L1..L4 -> segment max.  W3,W4 in VGPRs; 16 voxels/block.
__global__ __launch_bounds__(512, 2) void k_pass4(
    const unsigned short* __restrict__ Xg,
    const unsigned short* __restrict__ wt1, const unsigned short* __restrict__ wt2,
    const unsigned short* __restrict__ wt3, const unsigned short* __restrict__ wt4,
    const float* __restrict__ A1, const float* __restrict__ C1,
    const float* __restrict__ A2, const float* __restrict__ C2,
    const float* __restrict__ A3, const float* __restrict__ C3,
    const float* __restrict__ b4,
    const int* __restrict__ base, float* __restrict__ out) {
    extern __shared__ char smem[];
    char* Wt2l = smem;             // 16K
    char* act1 = smem + 16384;     // 8K  [64][128B]
    char* H    = smem + 24576;     // 32K: act2 [64][256B] then h4 [64][512B]
    char* act3 = smem + 57344;     // 32K [64][512B]; Xl aliases first 4K
    char* Xl   = smem + 57344;
    const int tid = threadIdx.x;
    const int w = tid >> 6, lane = tid & 63, g = lane >> 4, lq = lane & 15;
    const int wm = w >> 1, wn = w & 1;
    const int chb1 = wm * 16, chb2 = w * 16, chb = w * 32;

    for (int i = tid; i < 1024; i += 512) {
        const int row = i >> 3, c = (i & 7) * 16;
        *(s16x8*)(Wt2l + swz<128>(row, c)) = *(const s16x8*)(wt2 + row * 64 + c / 2);
    }
    s16x8 w3[2][4], w4[2][8];
#pragma unroll
    for (int mt = 0; mt < 2; ++mt) {
#pragma unroll
        for (int kc = 0; kc < 4; ++kc)
            w3[mt][kc] = *(const s16x8*)(wt3 + (size_t)(chb + mt * 16 + lq) * 128 + kc * 32 + g * 8);
#pragma unroll
        for (int kc = 0; kc < 8; ++kc)
            w4[mt][kc] = *(const s16x8*)(wt4 + (size_t)(chb + mt * 16 + lq) * 256 + kc * 32 + g * 8);
    }
    const s16x8 a1 = *(const s16x8*)(wt1 + (chb1 + lq) * 32 + g * 8);
    const int ch1 = chb1 + g * 4, ch2 = chb2 + g * 4;
    const f32x4 av1 = *(const f32x4*)(A1 + ch1);
    const f32x4 cv1 = *(const f32x4*)(C1 + ch1);
    const f32x4 av2 = *(const f32x4*)(A2 + ch2);
    const f32x4 cv2 = *(const f32x4*)(C2 + ch2);
    f32x4 av3[2], cv3[2], bv4[2];
#pragma unroll
    for (int mt = 0; mt < 2; ++mt) {
        av3[mt] = *(const f32x4*)(A3 + chb + mt * 16 + g * 4);
        cv3[mt] = *(const f32x4*)(C3 + chb + mt * 16 + g * 4);
        bv4[mt] = *(const f32x4*)(b4 + chb + mt * 16 + g * 4);
    }

    const int vb = blockIdx.x * 16;
    const int pstart = base[vb], pend = base[vb + 16];
    const int chgrp = tid & 31, slot = tid >> 5;
    const int vlo = base[vb + slot], vhi = base[vb + slot + 1];
    float rmax[8];
#pragma unroll
    for (int j = 0; j < 8; ++j) rmax[j] = -INFINITY;

    for (int t0 = pstart; t0 < pend; t0 += 64) {
        if (tid < 256) {
            const int row = tid >> 2, c = (tid & 3) * 16;
            const int gp = t0 + row;
            s16x8 v = (s16x8){0,0,0,0,0,0,0,0};
            if (c < 32 && gp < pend) v = *(const s16x8*)(Xg + (size_t)gp * 16 + c / 2);
            *(s16x8*)(Xl + swz<64>(row, c)) = v;
        }
        __syncthreads();
        // L1: wn splits 64 pts, CT2
        f32x4 acc1[2];
#pragma unroll
        for (int ct = 0; ct < 2; ++ct) acc1[ct] = (f32x4){0.f,0.f,0.f,0.f};
#pragma unroll
        for (int ct = 0; ct < 2; ++ct) {
            const int row = wn * 32 + ct * 16 + lq;
            const s16x8 b = *(const s16x8*)(Xl + swz<64>(row, g * 16));
            acc1[ct] = __builtin_amdgcn_mfma_f32_16x16x32_bf16(a1, b, acc1[ct], 0, 0, 0);
        }
#pragma unroll
        for (int ct = 0; ct < 2; ++ct) {
            const int row = wn * 32 + ct * 16 + lq;
            *(s16x4*)(act1 + swz<128>(row, ch1 * 2)) = bn_relu_pack(acc1[ct], av1, cv1);
        }
        __syncthreads();
        // L2: MT1 CT4 KC2 -> act2 (in H)
        f32x4 acc2[4];
#pragma unroll
        for (int ct = 0; ct < 4; ++ct) acc2[ct] = (f32x4){0.f,0.f,0.f,0.f};
#pragma unroll
        for (int kc = 0; kc < 2; ++kc) {
            const s16x8 a = *(const s16x8*)(Wt2l + swz<128>(chb2 + lq, kc * 64 + g * 16));
#pragma unroll
            for (int ct = 0; ct < 4; ++ct) {
                const s16x8 b = *(const s16x8*)(act1 + swz<128>(ct * 16 + lq, kc * 64 + g * 16));
                acc2[ct] = __builtin_amdgcn_mfma_f32_16x16x32_bf16(a, b, acc2[ct], 0, 0, 0);
            }
        }
#pragma unroll
        for (int ct = 0; ct < 4; ++ct)
            *(s16x4*)(H + swz<256>(ct * 16 + lq, ch2 * 2)) = bn_relu_pack(acc2[ct], av2, cv2);
        __syncthreads();
        // L3: MT2 CT4 KC4 -> act3
        f32x4 acc3[2][4];
#pragma unroll
        for (int mt = 0; mt < 2; ++mt)
#pragma unroll
            for (int ct = 0; ct < 4; ++ct) acc3[mt][ct] = (f32x4){0.f,0.f,0.f,0.f};
#pragma unroll
        for (int kc = 0; kc < 4; ++kc) {
#pragma unroll
            for (int ct = 0; ct < 4; ++ct) {
                const s16x8 b = *(const s16x8*)(H + swz<256>(ct * 16 + lq, kc * 64 + g * 16));
#pragma unroll
                for (int mt = 0; mt < 2; ++mt)
                    acc3[mt][ct] = __builtin_amdgcn_mfma_f32_16x16x32_bf16(w3[mt][kc], b, acc3[mt][ct], 0, 0, 0);
            }
        }
#pragma unroll
        for (int mt = 0; mt < 2; ++mt)
#pragma unroll
            for (int ct = 0; ct < 4; ++ct)
                *(s16x4*)(act3 + swz<512>(ct * 16 + lq, (chb + mt * 16 + g * 4) * 2)) =
                    bn_relu_pack(acc3[mt][ct], av3[mt], cv3[mt]);
        __syncthreads();
        // L4: MT2 CT4 KC8 -> h4 (in H)
        f32x4 acc4[2][4];
#pragma unroll
        for (int mt = 0; mt < 2; ++mt)
#pragma unroll
            for (int ct = 0; ct < 4; ++ct) acc4[mt][ct] = (f32x4){0.f,0.f,0.f,0.f};
#pragma unroll
        for (int kc = 0; kc < 8; ++kc) {
#pragma unroll
            for (int ct = 0; ct < 4; ++ct) {
                const s16x8 b = *(const s16x8*)(act3 + swz<512>(ct * 16 + lq, kc * 64 + g * 16));
#pragma unroll
                for (int mt = 0; mt < 2; ++mt)
                    acc4[mt][ct] = __builtin_amdgcn_mfma_f32_16x16x32_bf16(w4[mt][kc], b, acc4[mt][ct], 0, 0, 0);
            }
        }
#pragma unroll
        for (int mt = 0; mt < 2; ++mt) {
#pragma unroll
            for (int ct = 0; ct < 4; ++ct) {
                s16x4 pk;
#pragma unroll
                for (int r = 0; r < 4; ++r) pk[r] = (short)f2bf(acc4[mt][ct][r] + bv4[mt][r]);
                *(s16x4*)(H + swz<512>(ct * 16 + lq, (chb + mt * 16 + g * 4) * 2)) = pk;
            }
        }
        __syncthreads();
        // segment max from h4
        {
            const int lo = max(vlo, t0), hi = min(vhi, t0 + 64);
            for (int p = lo; p < hi; ++p) {
                const s16x8 hv = *(const s16x8*)(H + swz<512>(p - t0, chgrp * 16));
#pragma unroll
                for (int j = 0; j < 8; ++j)
                    rmax[j] = fmaxf(rmax[j], bf2f((unsigned short)hv[j]));
            }
        }
        __syncthreads();
    }
    float* orow = out + (size_t)(vb + slot) * 256 + chgrp * 8;
    f32x4 o0, o1;
#pragma unroll
    for (int j = 0; j < 4; ++j) { o0[j] = rmax[j]; o1[j] = rmax[4 + j]; }
    *(f32x4*)orow = o0;
    *(f32x4*)(orow + 4) = o1;
}

// =====================================================================
// LEGACY PATH (round-2 kernels, used if ws too small)
// =====================================================================
template<int NOUT, int K, int MODE>
__device__ __forceinline__ void layer(
    const unsigned short* __restrict__ wt,
    const char* __restrict__ lds_in, char* __restrict__ lds_out,
    const float* __restrict__ Af, const float* __restrict__ Cf,
    const float* __restrict__ bias, float* __restrict__ part,
    int p0, int N, int tid) {
    constexpr int ROWB_IN = K * 2;
    constexpr int ROWB_OUT = NOUT * 2;
    constexpr int MT = NOUT / 64;
    constexpr int KC = K / 32;
    const int w = tid >> 6, lane = tid & 63, g = lane >> 4, lq = lane & 15;
    const int chbase = w * (NOUT / 4);

    f32x4 acc[MT][4];
#pragma unroll
    for (int mt = 0; mt < MT; ++mt)
#pragma unroll
        for (int ct = 0; ct < 4; ++ct) acc[mt][ct] = (f32x4){0.f, 0.f, 0.f, 0.f};

#pragma unroll
    for (int kc = 0; kc < KC; ++kc) {
        s16x8 a[MT];
#pragma unroll
        for (int mt = 0; mt < MT; ++mt)
            a[mt] = *(const s16x8*)(wt + (size_t)(chbase + mt * 16 + lq) * K + kc * 32 + g * 8);
#pragma unroll
        for (int ct = 0; ct < 4; ++ct) {
            const int row = ct * 16 + lq;
            s16x8 b = *(const s16x8*)(lds_in + swz<ROWB_IN>(row, kc * 64 + g * 16));
#pragma unroll
            for (int mt = 0; mt < MT; ++mt)
                acc[mt][ct] = __builtin_amdgcn_mfma_f32_16x16x32_bf16(a[mt], b, acc[mt][ct], 0, 0, 0);
        }
    }

    if constexpr (MODE == 0) {
#pragma unroll
        for (int mt = 0; mt < MT; ++mt) {
            const int ch = chbase + mt * 16 + g * 4;
            const f32x4 av = *(const f32x4*)(Af + ch);
            const f32x4 cv = *(const f32x4*)(Cf + ch);
#pragma unroll
            for (int ct = 0; ct < 4; ++ct) {
                const int row = ct * 16 + lq;
                *(s16x4*)(lds_out + swz<ROWB_OUT>(row, ch * 2)) = bn_relu_pack(acc[mt][ct], av, cv);
            }
        }
    } else if constexpr (MODE == 1) {
#pragma unroll
        for (int mt = 0; mt < MT; ++mt) {
            const int ch = chbase + mt * 16 + g * 4;
            const f32x4 bv = *(const f32x4*)(bias + ch);
            f32x4 ps = (f32x4){0.f, 0.f, 0.f, 0.f}, pq = (f32x4){0.f, 0.f, 0.f, 0.f};
#pragma unroll
            for (int ct = 0; ct < 4; ++ct) {
                const bool valid = (p0 + ct * 16 + lq) < N;
#pragma unroll
                for (int r = 0; r < 4; ++r) {
                    float h = valid ? (acc[mt][ct][r] + bv[r]) : 0.f;
                    ps[r] += h; pq[r] += h * h;
                }
            }
            stats_red<NOUT>(ps, pq, ch, part);
        }
    } else {
#pragma unroll
        for (int mt = 0; mt < MT; ++mt) {
            const int ch = chbase + mt * 16 + g * 4;
            const f32x4 bv = *(const f32x4*)(bias + ch);
#pragma unroll
            for (int ct = 0; ct < 4; ++ct) {
                const int row = ct * 16 + lq;
                s16x4 pk;
#pragma unroll
                for (int r = 0; r < 4; ++r)
                    pk[r] = (short)f2bf(acc[mt][ct][r] + bv[r]);
                *(s16x4*)(lds_out + swz<ROWB_OUT>(row, ch * 2)) = pk;
            }
        }
    }
}

__device__ __forceinline__ void stage_act0(const float* __restrict__ feats,
                                           const float* __restrict__ A0,
                                           const float* __restrict__ C0,
                                           const int* __restrict__ perm,
                                           int t0, int pend, char* act0, int tid) {
    *(f32x4*)(act0 + tid * 16) = (f32x4){0.f, 0.f, 0.f, 0.f};
    __syncthreads();
    for (int idx = tid; idx < PT * 9; idx += TPB) {
        const int p = idx / 9, ch = idx - p * 9;
        const int gp = t0 + p;
        if (gp < pend) {
            const int src = perm ? perm[gp] : gp;
            float v = fmaf(feats[(size_t)src * 9 + ch], A0[ch], C0[ch]);
            *(unsigned short*)(act0 + swz<64>(p, ch * 2)) = f2bf(v);
        }
    }
}

template<int STAGE>
__global__ __launch_bounds__(TPB, 2) void k_stage(
    const float* __restrict__ feats, char* __restrict__ ws,
    const float* __restrict__ b1, const float* __restrict__ b2,
    const float* __restrict__ b3, const float* __restrict__ b4,
    float* __restrict__ out, int N) {
    extern __shared__ char smem[];
    char* act0 = smem + ACT0_OFF;
    char* act1 = smem + ACT1_OFF;
    char* act2 = smem + ACT2_OFF;
    char* act3 = smem + ACT3_OFF;
    char* h4   = smem + H4_OFF;

    const int tid = threadIdx.x;
    const float* A0 = (const float*)(ws + A0_OFF);
    const float* C0 = (const float*)(ws + C0_OFF);
    const float* A1 = (const float*)(ws + A1_OFF);
    const float* C1 = (const float*)(ws + C1_OFF);
    const float* A2 = (const float*)(ws + A2_OFF);
    const float* C2 = (const float*)(ws + C2_OFF);
    const float* A3 = (const float*)(ws + A3_OFF);
    const float* C3 = (const float*)(ws + C3_OFF);
    const unsigned short* Wt1 = (const unsigned short*)(ws + WT1_OFF);
    const unsigned short* Wt2 = (const unsigned short*)(ws + WT2_OFF);
    const unsigned short* Wt3 = (const unsigned short*)(ws + WT3_OFF);
    const unsigned short* Wt4 = (const unsigned short*)(ws + WT4_OFF);

    if constexpr (STAGE < 4) {
        const int t0 = blockIdx.x * PT;
        stage_act0(feats, A0, C0, nullptr, t0, N, act0, tid);
        __syncthreads();
        if constexpr (STAGE == 1) {
            float* prow = (float*)(ws + P1_OFF) + (blockIdx.x & 63) * 128;
            layer<64, 32, 1>(Wt1, act0, nullptr, nullptr, nullptr, b1, prow, t0, N, tid);
            return;
        }
        layer<64, 32, 0>(Wt1, act0, act1, A1, C1, nullptr, nullptr, t0, N, tid);
        __syncthreads();
        if constexpr (STAGE == 2) {
            float* prow = (float*)(ws + P2_OFF) + (blockIdx.x & 63) * 256;
            layer<128, 64, 1>(Wt2, act1, nullptr, nullptr, nullptr, b2, prow, t0, N, tid);
            return;
        }
        layer<128, 64, 0>(Wt2, act1, act2, A2, C2, nullptr, nullptr, t0, N, tid);
        __syncthreads();
        float* prow = (float*)(ws + P3_OFF) + (blockIdx.x & 63) * 512;
        layer<256, 128, 1>(Wt3, act2, nullptr, nullptr, nullptr, b3, prow, t0, N, tid);
    } else {
        const int* base = (const int*)(ws + BASE_OFF);
        const int* perm = (const int*)(ws + PERM_OFF);
        const int vb = blockIdx.x * VB;
        const int pstart = base[vb], pend = base[vb + VB];
        const int chgrp = tid & 31, slot = tid >> 5;
        const int vlo = base[vb + slot], vhi = base[vb + slot + 1];
        float rmax[8];
#pragma unroll
        for (int j = 0; j < 8; ++j) rmax[j] = -INFINITY;

        for (int t0 = pstart; t0 < pend; t0 += PT) {
            stage_act0(feats, A0, C0, perm, t0, pend, act0, tid);
            __syncthreads();
            layer<64, 32, 0>(Wt1, act0, act1, A1, C1, nullptr, nullptr, t0, N, tid);
            __syncthreads();
            layer<128, 64, 0>(Wt2, act1, act2, A2, C2, nullptr, nullptr, t0, N, tid);
            __syncthreads();
            layer<256, 128, 0>(Wt3, act2, act3, A3, C3, nullptr, nullptr, t0, N, tid);
            __syncthreads();
            layer<256, 256, 2>(Wt4, act3, h4, nullptr, nullptr, b4, nullptr, t0, N, tid);
            __syncthreads();
            const int lo = max(vlo, t0), hi = min(vhi, t0 + PT);
            for (int p = lo; p < hi; ++p) {
                const int row = p - t0;
                s16x8 hv = *(const s16x8*)(h4 + swz<512>(row, chgrp * 16));
#pragma unroll
                for (int j = 0; j < 8; ++j)
                    rmax[j] = fmaxf(rmax[j], bf2f((unsigned short)hv[j]));
            }
            __syncthreads();
        }
        float* orow = out + (size_t)(vb + slot) * 256 + chgrp * 8;
        f32x4 o0, o1;
#pragma unroll
        for (int j = 0; j < 4; ++j) { o0[j] = rmax[j]; o1[j] = rmax[4 + j]; }
        *(f32x4*)orow = o0;
        *(f32x4*)(orow + 4) = o1;
    }
}

extern "C" void kernel_launch(void* const* d_in, const int* in_sizes, int n_in,
                              void* d_out, int out_size, void* d_ws, size_t ws_size,
                              hipStream_t stream) {
    const float* feats = (const float*)d_in[0];
    const int* coords = (const int*)d_in[1];
    const float* g0 = (const float*)d_in[3];
    const float* be0 = (const float*)d_in[4];
    const float* W1 = (const float*)d_in[5];
    const float* b1 = (const float*)d_in[6];
    const float* g1 = (const float*)d_in[7];
    const float* be1 = (const float*)d_in[8];
    const float* W2 = (const float*)d_in[9];
    const float* b2 = (const float*)d_in[10];
    const float* g2 = (const float*)d_in[11];
    const float* be2 = (const float*)d_in[12];
    const float* W3 = (const float*)d_in[13];
    const float* b3 = (const float*)d_in[14];
    const float* g3 = (const float*)d_in[15];
    const float* be3 = (const float*)d_in[16];
    const float* W4 = (const float*)d_in[17];
    const float* b4 = (const float*)d_in[18];
    float* out = (float*)d_out;
    char* ws = (char*)d_ws;

    const int N = in_sizes[0] / 9;
    const float fN = (float)N;
    const int nt = (N + 127) / 128;

    hipMemsetAsync(ws, 0, PAR_END, stream);
    hipMemsetAsync(ws + HIST_OFF, 0, 131072, stream);

    k_prepw<<<128, TPB, 0, stream>>>(W1, W2, W3, W4,
        (unsigned short*)(ws + WT1_OFF), (unsigned short*)(ws + WT2_OFF),
        (unsigned short*)(ws + WT3_OFF), (unsigned short*)(ws + WT4_OFF));
    k_hist<<<1024, TPB, 0, stream>>>(coords, N, (unsigned*)(ws + HIST_OFF));
    k_scan<<<1, 1024, 0, stream>>>((const unsigned*)(ws + HIST_OFF),
                                   (int*)(ws + BASE_OFF), (unsigned*)(ws + CURS_OFF), N);
    k_scatter<<<1024, TPB, 0, stream>>>(coords, N, (unsigned*)(ws + CURS_OFF),
                                        (int*)(ws + PERM_OFF));

    k_stats0<<<256, TPB, 0, stream>>>(feats, N, (float*)(ws + P0_OFF));
    k_fin<<<1, TPB, 0, stream>>>((const float*)(ws + P0_OFF), 1, 9, g0, be0, nullptr,
                                 (float*)(ws + A0_OFF), (float*)(ws + C0_OFF), fN);
    k_coords<<<(NVOX + TPB - 1) / TPB, TPB, 0, stream>>>(out + (size_t)NVOX * 256);

    const size_t need = (size_t)X_OFF + (size_t)nt * 4096u;
    if (ws_size >= need && N <= 1000000) {
        unsigned short* Xg = (unsigned short*)(ws + X_OFF);
        const unsigned short* wt1 = (const unsigned short*)(ws + WT1_OFF);
        const unsigned short* wt2 = (const unsigned short*)(ws + WT2_OFF);
        const unsigned short* wt3 = (const unsigned short*)(ws + WT3_OFF);
        const unsigned short* wt4 = (const unsigned short*)(ws + WT4_OFF);
        const float* A0 = (const float*)(ws + A0_OFF);
        const float* C0 = (const float*)(ws + C0_OFF);
        float* A1 = (float*)(ws + A1_OFF); float* C1 = (float*)(ws + C1_OFF);
        float* A2 = (float*)(ws + A2_OFF); float* C2 = (float*)(ws + C2_OFF);
        float* A3 = (float*)(ws + A3_OFF); float* C3 = (float*)(ws + C3_OFF);

        hipFuncSetAttribute((const void*)k_pass3,
            hipFuncAttributeMaxDynamicSharedMemorySize, 65536);
        hipFuncSetAttribute((const void*)k_pass4,
            hipFuncAttributeMaxDynamicSharedMemorySize, 90112);

        k_pass1<<<1024, 256, 0, stream>>>(feats, (const int*)(ws + PERM_OFF), wt1,
            A0, C0, b1, Xg, (float*)(ws + P1_OFF), N, nt);
        k_fin<<<1, TPB, 0, stream>>>((const float*)(ws + P1_OFF), 64, 64, g1, be1, b1,
                                     A1, C1, fN);
        k_pass2<<<1024, 256, 0, stream>>>(Xg, wt1, wt2, A1, C1, b2,
                                          (float*)(ws + P2_OFF), N, nt);
        k_fin<<<1, TPB, 0, stream>>>((const float*)(ws + P2_OFF), 64, 128, g2, be2, b2,
                                     A2, C2, fN);
        k_pass3<<<1024, 512, 65536, stream>>>(Xg, wt1, wt2, wt3, A1, C1, A2, C2, b3,
                                              (float*)(ws + P3_OFF), N, nt);
        k_fin<<<1, TPB, 0, stream>>>((const float*)(ws + P3_OFF), 64, 256, g3, be3, b3,
                                     A3, C3, fN);
        k_pass4<<<NVOX / 16, 512, 90112, stream>>>(Xg, wt1, wt2, wt3, wt4,
            A1, C1, A2, C2, A3, C3, b4, (const int*)(ws + BASE_OFF), out);
    } else {
        const int nblk = (N + PT - 1) / PT;
        k_stage<1><<<nblk, TPB, SMEM_S1, stream>>>(feats, ws, b1, b2, b3, b4, out, N);
        k_fin<<<1, TPB, 0, stream>>>((const float*)(ws + P1_OFF), 64, 64, g1, be1, b1,
                                     (float*)(ws + A1_OFF), (float*)(ws + C1_OFF), fN);
        k_stage<2><<<nblk, TPB, SMEM_S2, stream>>>(feats, ws, b1, b2, b3, b4, out, N);
        k_fin<<<1, TPB, 0, stream>>>((const float*)(ws + P2_OFF), 64, 128, g2, be2, b2,
                                     (float*)(ws + A2_OFF), (float*)(ws + C2_OFF), fN);
        k_stage<3><<<nblk, TPB, SMEM_S3, stream>>>(feats, ws, b1, b2, b3, b4, out, N);
        k_fin<<<1, TPB, 0, stream>>>((const float*)(ws + P3_OFF), 64, 256, g3, be3, b3,
                                     (float*)(ws + A3_OFF), (float*)(ws + C3_OFF), fN);
        k_stage<4><<<NVOX / VB, TPB, SMEM_S4, stream>>>(feats, ws, b1, b2, b3, b4, out, N);
    }
}

// Round 5
// 1009.663 us; speedup vs baseline: 17.6716x; 1.0039x over previous
//
#include <hip/hip_runtime.h>
#include <math.h>

#define TPB 256
#define NVOX 32768
#define BN_EPS 1e-5f

typedef short s16x8 __attribute__((ext_vector_type(8)));
typedef short s16x4 __attribute__((ext_vector_type(4)));
typedef float f32x4 __attribute__((ext_vector_type(4)));

// ---------------- ws byte offsets ----------------
#define P0_OFF     0u
#define P1_OFF     256u
#define P2_OFF     (P1_OFF + 64u*128u*4u)
#define P3_OFF     (P2_OFF + 64u*256u*4u)
#define PAR_END    (P3_OFF + 64u*512u*4u)        // 229632
#define A0_OFF     229632u
#define C0_OFF     229888u
#define A1_OFF     230144u
#define C1_OFF     230400u
#define A2_OFF     230656u
#define C2_OFF     231680u
#define A3_OFF     232704u
#define C3_OFF     233728u
#define HIST_OFF   234752u
#define BASE_OFF   (HIST_OFF + 131072u)
#define CURS_OFF   (BASE_OFF + 131328u)
#define PERM_OFF   (CURS_OFF + 131072u)
#define WT1_OFF    (PERM_OFF + 4000000u)   // 64x32 bf16 (K padded w/ zeros)
#define WT2_OFF    (WT1_OFF + 4096u)       // 128x64
#define WT3_OFF    (WT2_OFF + 16384u)      // 256x128
#define WT4_OFF    (WT3_OFF + 65536u)      // 256x256
#define X_OFF      4845568u                // X bf16 [Npad][16], voxel-sorted

__device__ __forceinline__ unsigned short f2bf(float f) {
    unsigned u = __float_as_uint(f);
    u += 0x7FFFu + ((u >> 16) & 1u);
    return (unsigned short)(u >> 16);
}
__device__ __forceinline__ float bf2f(unsigned short h) {
    return __uint_as_float(((unsigned)h) << 16);
}

template<int ROWB>
__device__ __forceinline__ int swz(int row, int b) {
    constexpr int M = (ROWB >= 128) ? 7 : ((ROWB >= 64) ? 3 : 1);
    return row * ROWB + (b ^ ((row & M) << 4));
}

__device__ __forceinline__ s16x4 bn_relu_pack(f32x4 acc, f32x4 av, f32x4 cv) {
    s16x4 pk;
#pragma unroll
    for (int r = 0; r < 4; ++r) pk[r] = (short)f2bf(fmaxf(fmaf(acc[r], av[r], cv[r]), 0.f));
    return pk;
}

template<int NOUT>
__device__ __forceinline__ void stats_red(f32x4 ps, f32x4 pq, int ch, float* prow) {
#pragma unroll
    for (int m = 1; m <= 8; m <<= 1) {
#pragma unroll
        for (int r = 0; r < 4; ++r) { ps[r] += __shfl_xor(ps[r], m); pq[r] += __shfl_xor(pq[r], m); }
    }
    if ((threadIdx.x & 15) == 0) {
#pragma unroll
        for (int r = 0; r < 4; ++r) {
            atomicAdd(&prow[ch + r], ps[r]);
            atomicAdd(&prow[NOUT + ch + r], pq[r]);
        }
    }
}

// ---------------- prep kernels ----------------
__global__ void k_prepw(const float* __restrict__ W1, const float* __restrict__ W2,
                        const float* __restrict__ W3, const float* __restrict__ W4,
                        unsigned short* __restrict__ wt1, unsigned short* __restrict__ wt2,
                        unsigned short* __restrict__ wt3, unsigned short* __restrict__ wt4) {
    for (int i = blockIdx.x * blockDim.x + threadIdx.x; i < 108544;
         i += gridDim.x * blockDim.x) {
        if (i < 2048) {
            int n = i >> 5, k = i & 31;
            wt1[i] = (k < 9) ? f2bf(W1[k * 64 + n]) : (unsigned short)0;
        } else if (i < 10240) {
            int j = i - 2048; int n = j >> 6, k = j & 63;
            wt2[j] = f2bf(W2[k * 128 + n]);
        } else if (i < 43008) {
            int j = i - 10240; int n = j >> 7, k = j & 127;
            wt3[j] = f2bf(W3[k * 256 + n]);
        } else {
            int j = i - 43008; int n = j >> 8, k = j & 255;
            wt4[j] = f2bf(W4[k * 256 + n]);
        }
    }
}

// fused: voxel histogram + feats channel stats
__global__ void k_hist_stats(const int* __restrict__ coords, const float* __restrict__ feats,
                             int N, unsigned* __restrict__ hist, float* __restrict__ p0) {
    __shared__ float s[9], q[9];
    if (threadIdx.x < 9) { s[threadIdx.x] = 0.f; q[threadIdx.x] = 0.f; }
    __syncthreads();
    float ls[9] = {0}, lq[9] = {0};
    for (int i = blockIdx.x * blockDim.x + threadIdx.x; i < N;
         i += gridDim.x * blockDim.x) {
        int v = (coords[3 * i] << 10) | (coords[3 * i + 1] << 5) | coords[3 * i + 2];
        atomicAdd(&hist[v], 1u);
        const float* r = feats + (size_t)i * 9;
#pragma unroll
        for (int c = 0; c < 9; ++c) { float x = r[c]; ls[c] += x; lq[c] += x * x; }
    }
#pragma unroll
    for (int c = 0; c < 9; ++c) { atomicAdd(&s[c], ls[c]); atomicAdd(&q[c], lq[c]); }
    __syncthreads();
    if (threadIdx.x < 9) {
        atomicAdd(&p0[threadIdx.x], s[threadIdx.x]);
        atomicAdd(&p0[9 + threadIdx.x], q[threadIdx.x]);
    }
}

__global__ void k_scan(const unsigned* __restrict__ hist, int* __restrict__ base,
                       unsigned* __restrict__ cursor, int N) {
    __shared__ unsigned part[1024];
    const int t = threadIdx.x;
    unsigned sum = 0;
    for (int j = 0; j < 32; ++j) sum += hist[t * 32 + j];
    part[t] = sum;
    __syncthreads();
    for (int d = 1; d < 1024; d <<= 1) {
        unsigned v = (t >= d) ? part[t - d] : 0u;
        __syncthreads();
        part[t] += v;
        __syncthreads();
    }
    unsigned run = part[t] - sum;
    for (int j = 0; j < 32; ++j) {
        unsigned h = hist[t * 32 + j];
        base[t * 32 + j] = (int)run;
        cursor[t * 32 + j] = run;
        run += h;
    }
    if (t == 1023) base[32768] = (int)run;
}

__global__ void k_scatter(const int* __restrict__ coords, int N,
                          unsigned* __restrict__ cursor, int* __restrict__ perm) {
    for (int i = blockIdx.x * blockDim.x + threadIdx.x; i < N;
         i += gridDim.x * blockDim.x) {
        int v = (coords[3 * i] << 10) | (coords[3 * i + 1] << 5) | coords[3 * i + 2];
        unsigned pos = atomicAdd(&cursor[v], 1u);
        perm[pos] = i;
    }
}

__global__ void k_fin(const float* __restrict__ part, int nparts, int C,
                      const float* __restrict__ g, const float* __restrict__ be,
                      const float* __restrict__ bias,
                      float* __restrict__ A, float* __restrict__ Cc, float n) {
    int c = threadIdx.x;
    if (c >= C) return;
    float s = 0.f, q = 0.f;
    for (int r = 0; r < nparts; ++r) { s += part[r * 2 * C + c]; q += part[r * 2 * C + C + c]; }
    float m = s / n;
    float v = q / n - m * m;
    float a = g[c] * rsqrtf(v + BN_EPS);
    float cc = be[c] - m * a;
    A[c] = a;
    Cc[c] = bias ? fmaf(a, bias[c], cc) : cc;
}

__global__ void k_coords(float* __restrict__ outc) {
    int v = blockIdx.x * blockDim.x + threadIdx.x;
    if (v < NVOX) {
        outc[3 * v + 0] = (float)(v >> 10);
        outc[3 * v + 1] = (float)((v >> 5) & 31);
        outc[3 * v + 2] = (float)(v & 31);
    }
}

// =====================================================================
// pass1: gather+BN0 -> X dump + L1 stats (LDS staging; gather is scalar)
// =====================================================================
__global__ __launch_bounds__(256, 4) void k_pass1(
    const float* __restrict__ feats, const int* __restrict__ perm,
    const unsigned short* __restrict__ wt1,
    const float* __restrict__ A0, const float* __restrict__ C0,
    const float* __restrict__ b1,
    unsigned short* __restrict__ Xg, float* __restrict__ p1,
    int N, int nt) {
    __shared__ char Xl[8192];   // [128][64B] swz<64>
    const int tid = threadIdx.x;
    const int w = tid >> 6, lane = tid & 63, g = lane >> 4, lq = lane & 15;
    const int chb = w * 16;
    const s16x8 a1 = *(const s16x8*)(wt1 + (chb + lq) * 32 + g * 8);
    const int ch = chb + g * 4;
    const f32x4 bv = *(const f32x4*)(b1 + ch);
    float* prow = p1 + (blockIdx.x & 63) * 128;

    for (int t = blockIdx.x; t < nt; t += gridDim.x) {
        const int t0 = t * 128;
        *(f32x4*)(Xl + tid * 32) = (f32x4){0.f, 0.f, 0.f, 0.f};
        *(f32x4*)(Xl + tid * 32 + 16) = (f32x4){0.f, 0.f, 0.f, 0.f};
        __syncthreads();
        for (int idx = tid; idx < 128 * 9; idx += 256) {
            const int p = idx / 9, c = idx - p * 9;
            const int gp = t0 + p;
            if (gp < N) {
                const int src = perm[gp];
                float v = fmaf(feats[(size_t)src * 9 + c], A0[c], C0[c]);
                *(unsigned short*)(Xl + swz<64>(p, c * 2)) = f2bf(v);
            }
        }
        __syncthreads();
        {   // dump linear X (un-swizzle)
            const int row = tid >> 1, c = (tid & 1) * 16;
            *(s16x8*)(Xg + (size_t)(t0 + row) * 16 + c / 2) =
                *(const s16x8*)(Xl + swz<64>(row, c));
        }
        f32x4 acc[8];
#pragma unroll
        for (int ct = 0; ct < 8; ++ct) acc[ct] = (f32x4){0.f, 0.f, 0.f, 0.f};
#pragma unroll
        for (int ct = 0; ct < 8; ++ct) {
            const s16x8 b = *(const s16x8*)(Xl + swz<64>(ct * 16 + lq, g * 16));
            acc[ct] = __builtin_amdgcn_mfma_f32_16x16x32_bf16(a1, b, acc[ct], 0, 0, 0);
        }
        f32x4 ps = (f32x4){0.f,0.f,0.f,0.f}, pq = (f32x4){0.f,0.f,0.f,0.f};
#pragma unroll
        for (int ct = 0; ct < 8; ++ct) {
            const bool valid = (t0 + ct * 16 + lq) < N;
#pragma unroll
            for (int r = 0; r < 4; ++r) {
                const float h = valid ? (acc[ct][r] + bv[r]) : 0.f;
                ps[r] += h; pq[r] += h * h;
            }
        }
        stats_red<64>(ps, pq, ch, prow);
        __syncthreads();
    }
}

// =====================================================================
// pass2: X --(L1,direct-global B)--> act1 --(L2, W2 in regs)--> stats
// =====================================================================
__global__ __launch_bounds__(256) void k_pass2(
    const unsigned short* __restrict__ Xg,
    const unsigned short* __restrict__ wt1, const unsigned short* __restrict__ wt2,
    const float* __restrict__ A1, const float* __restrict__ C1,
    const float* __restrict__ b2,
    float* __restrict__ p2, int N, int nt) {
    __shared__ char act1[16384];   // [128][128B] swz<128>
    const int tid = threadIdx.x;
    const int w = tid >> 6, lane = tid & 63, g = lane >> 4, lq = lane & 15;
    const int chb1 = w * 16, chb2 = w * 32;

    const s16x8 a1 = *(const s16x8*)(wt1 + (chb1 + lq) * 32 + g * 8);
    s16x8 w2f[2][2];
#pragma unroll
    for (int mt = 0; mt < 2; ++mt)
#pragma unroll
        for (int kc = 0; kc < 2; ++kc)
            w2f[mt][kc] = *(const s16x8*)(wt2 + (size_t)(chb2 + mt * 16 + lq) * 64 + kc * 32 + g * 8);
    const int ch1 = chb1 + g * 4;
    const f32x4 av1 = *(const f32x4*)(A1 + ch1);
    const f32x4 cv1 = *(const f32x4*)(C1 + ch1);
    f32x4 bv2[2];
#pragma unroll
    for (int mt = 0; mt < 2; ++mt) bv2[mt] = *(const f32x4*)(b2 + chb2 + mt * 16 + g * 4);
    float* prow = p2 + (blockIdx.x & 63) * 256;

    for (int t = blockIdx.x; t < nt; t += gridDim.x) {
        const int t0 = t * 128;
        f32x4 acc1[8];
#pragma unroll
        for (int ct = 0; ct < 8; ++ct) acc1[ct] = (f32x4){0.f,0.f,0.f,0.f};
#pragma unroll
        for (int ct = 0; ct < 8; ++ct) {
            const s16x8 b = *(const s16x8*)(Xg + (size_t)(t0 + ct * 16 + lq) * 16 + g * 8);
            acc1[ct] = __builtin_amdgcn_mfma_f32_16x16x32_bf16(a1, b, acc1[ct], 0, 0, 0);
        }
#pragma unroll
        for (int ct = 0; ct < 8; ++ct)
            *(s16x4*)(act1 + swz<128>(ct * 16 + lq, ch1 * 2)) = bn_relu_pack(acc1[ct], av1, cv1);
        __syncthreads();

        f32x4 acc2[2][8];
#pragma unroll
        for (int mt = 0; mt < 2; ++mt)
#pragma unroll
            for (int ct = 0; ct < 8; ++ct) acc2[mt][ct] = (f32x4){0.f,0.f,0.f,0.f};
#pragma unroll
        for (int kc = 0; kc < 2; ++kc) {
#pragma unroll
            for (int ct = 0; ct < 8; ++ct) {
                const s16x8 b = *(const s16x8*)(act1 + swz<128>(ct * 16 + lq, kc * 64 + g * 16));
#pragma unroll
                for (int mt = 0; mt < 2; ++mt)
                    acc2[mt][ct] = __builtin_amdgcn_mfma_f32_16x16x32_bf16(w2f[mt][kc], b, acc2[mt][ct], 0, 0, 0);
            }
        }
#pragma unroll
        for (int mt = 0; mt < 2; ++mt) {
            f32x4 ps = (f32x4){0.f,0.f,0.f,0.f}, pq = (f32x4){0.f,0.f,0.f,0.f};
#pragma unroll
            for (int ct = 0; ct < 8; ++ct) {
                const bool valid = (t0 + ct * 16 + lq) < N;
#pragma unroll
                for (int r = 0; r < 4; ++r) {
                    const float h = valid ? (acc2[mt][ct][r] + bv2[mt][r]) : 0.f;
                    ps[r] += h; pq[r] += h * h;
                }
            }
            stats_red<128>(ps, pq, chb2 + mt * 16 + g * 4, prow);
        }
        __syncthreads();
    }
}

// =====================================================================
// pass3: X -> L1 -> L2 -> L3 stats (+ optional h3 dump). W2,W3 in regs.
// =====================================================================
template<int DUMP>
__global__ __launch_bounds__(512) void k_pass3(
    const unsigned short* __restrict__ Xg,
    const unsigned short* __restrict__ wt1, const unsigned short* __restrict__ wt2,
    const unsigned short* __restrict__ wt3,
    const float* __restrict__ A1, const float* __restrict__ C1,
    const float* __restrict__ A2, const float* __restrict__ C2,
    const float* __restrict__ b3,
    float* __restrict__ p3, unsigned short* __restrict__ h3g,
    int N, int nt) {
    __shared__ char act1[16384];   // [128][128B]
    __shared__ char act2[32768];   // [128][256B]
    const int tid = threadIdx.x;
    const int w = tid >> 6, lane = tid & 63, g = lane >> 4, lq = lane & 15;
    const int wm = w >> 1, wn = w & 1;
    const int chb1 = wm * 16, chb2 = w * 16, chb3 = w * 32;

    const s16x8 a1 = *(const s16x8*)(wt1 + (chb1 + lq) * 32 + g * 8);
    s16x8 w2f[2], w3f[2][4];
#pragma unroll
    for (int kc = 0; kc < 2; ++kc)
        w2f[kc] = *(const s16x8*)(wt2 + (size_t)(chb2 + lq) * 64 + kc * 32 + g * 8);
#pragma unroll
    for (int mt = 0; mt < 2; ++mt)
#pragma unroll
        for (int kc = 0; kc < 4; ++kc)
            w3f[mt][kc] = *(const s16x8*)(wt3 + (size_t)(chb3 + mt * 16 + lq) * 128 + kc * 32 + g * 8);
    const int ch1 = chb1 + g * 4, ch2 = chb2 + g * 4;
    const f32x4 av1 = *(const f32x4*)(A1 + ch1);
    const f32x4 cv1 = *(const f32x4*)(C1 + ch1);
    const f32x4 av2 = *(const f32x4*)(A2 + ch2);
    const f32x4 cv2 = *(const f32x4*)(C2 + ch2);
    f32x4 bv3[2];
#pragma unroll
    for (int mt = 0; mt < 2; ++mt) bv3[mt] = *(const f32x4*)(b3 + chb3 + mt * 16 + g * 4);
    float* prow = p3 + (blockIdx.x & 63) * 512;

    for (int t = blockIdx.x; t < nt; t += gridDim.x) {
        const int t0 = t * 128;
        // L1 (B direct from global X)
        f32x4 acc1[4];
#pragma unroll
        for (int ct = 0; ct < 4; ++ct) acc1[ct] = (f32x4){0.f,0.f,0.f,0.f};
#pragma unroll
        for (int ct = 0; ct < 4; ++ct) {
            const int row = wn * 64 + ct * 16 + lq;
            const s16x8 b = *(const s16x8*)(Xg + (size_t)(t0 + row) * 16 + g * 8);
            acc1[ct] = __builtin_amdgcn_mfma_f32_16x16x32_bf16(a1, b, acc1[ct], 0, 0, 0);
        }
#pragma unroll
        for (int ct = 0; ct < 4; ++ct) {
            const int row = wn * 64 + ct * 16 + lq;
            *(s16x4*)(act1 + swz<128>(row, ch1 * 2)) = bn_relu_pack(acc1[ct], av1, cv1);
        }
        __syncthreads();
        // L2
        f32x4 acc2[8];
#pragma unroll
        for (int ct = 0; ct < 8; ++ct) acc2[ct] = (f32x4){0.f,0.f,0.f,0.f};
#pragma unroll
        for (int kc = 0; kc < 2; ++kc) {
#pragma unroll
            for (int ct = 0; ct < 8; ++ct) {
                const s16x8 b = *(const s16x8*)(act1 + swz<128>(ct * 16 + lq, kc * 64 + g * 16));
                acc2[ct] = __builtin_amdgcn_mfma_f32_16x16x32_bf16(w2f[kc], b, acc2[ct], 0, 0, 0);
            }
        }
#pragma unroll
        for (int ct = 0; ct < 8; ++ct)
            *(s16x4*)(act2 + swz<256>(ct * 16 + lq, ch2 * 2)) = bn_relu_pack(acc2[ct], av2, cv2);
        __syncthreads();
        // L3
        f32x4 acc3[2][8];
#pragma unroll
        for (int mt = 0; mt < 2; ++mt)
#pragma unroll
            for (int ct = 0; ct < 8; ++ct) acc3[mt][ct] = (f32x4){0.f,0.f,0.f,0.f};
#pragma unroll
        for (int kc = 0; kc < 4; ++kc) {
#pragma unroll
            for (int ct = 0; ct < 8; ++ct) {
                const s16x8 b = *(const s16x8*)(act2 + swz<256>(ct * 16 + lq, kc * 64 + g * 16));
#pragma unroll
                for (int mt = 0; mt < 2; ++mt)
                    acc3[mt][ct] = __builtin_amdgcn_mfma_f32_16x16x32_bf16(w3f[mt][kc], b, acc3[mt][ct], 0, 0, 0);
            }
        }
        if constexpr (DUMP) {
#pragma unroll
            for (int mt = 0; mt < 2; ++mt) {
                const int ch = chb3 + mt * 16 + g * 4;
#pragma unroll
                for (int ct = 0; ct < 8; ++ct) {
                    const int pt = t0 + ct * 16 + lq;
                    if (pt < N) {
                        s16x4 pk;
#pragma unroll
                        for (int r = 0; r < 4; ++r) pk[r] = (short)f2bf(acc3[mt][ct][r]);
                        *(s16x4*)(h3g + (size_t)pt * 256 + ch) = pk;
                    }
                }
            }
        }
#pragma unroll
        for (int mt = 0; mt < 2; ++mt) {
            f32x4 ps = (f32x4){0.f,0.f,0.f,0.f}, pq = (f32x4){0.f,0.f,0.f,0.f};
#pragma unroll
            for (int ct = 0; ct < 8; ++ct) {
                const bool valid = (t0 + ct * 16 + lq) < N;
#pragma unroll
                for (int r = 0; r < 4; ++r) {
                    const float h = valid ? (acc3[mt][ct][r] + bv3[mt][r]) : 0.f;
                    ps[r] += h; pq[r] += h * h;
                }
            }
            stats_red<256>(ps, pq, chb3 + mt * 16 + g * 4, prow);
        }
        __syncthreads();
    }
}

// =====================================================================
// pass4 T1 (fallback): X -> L1..L4 -> segment max.  W2,W3,W4 in regs.
// =====================================================================
__global__ __launch_bounds__(512) void k_pass4(
    const unsigned short* __restrict__ Xg,
    const unsigned short* __restrict__ wt1, const unsigned short* __restrict__ wt2,
    const unsigned short* __restrict__ wt3, const unsigned short* __restrict__ wt4,
    const float* __restrict__ A1, const float* __restrict__ C1,
    const float* __restrict__ A2, const float* __restrict__ C2,
    const float* __restrict__ A3, const float* __restrict__ C3,
    const float* __restrict__ b4,
    const int* __restrict__ base, float* __restrict__ out) {
    extern __shared__ char smem[];
    char* act1 = smem;             // 8K  [64][128B]
    char* H    = smem + 8192;      // 32K: act2 [64][256B] then h4 [64][512B]
    char* act3 = smem + 40960;     // 32K [64][512B]
    const int tid = threadIdx.x;
    const int w = tid >> 6, lane = tid & 63, g = lane >> 4, lq = lane & 15;
    const int wm = w >> 1, wn = w & 1;
    const int chb1 = wm * 16, chb2 = w * 16, chb = w * 32;

    const s16x8 a1 = *(const s16x8*)(wt1 + (chb1 + lq) * 32 + g * 8);
    s16x8 w2f[2], w3[2][4], w4[2][8];
#pragma unroll
    for (int kc = 0; kc < 2; ++kc)
        w2f[kc] = *(const s16x8*)(wt2 + (size_t)(chb2 + lq) * 64 + kc * 32 + g * 8);
#pragma unroll
    for (int mt = 0; mt < 2; ++mt) {
#pragma unroll
        for (int kc = 0; kc < 4; ++kc)
            w3[mt][kc] = *(const s16x8*)(wt3 + (size_t)(chb + mt * 16 + lq) * 128 + kc * 32 + g * 8);
#pragma unroll
        for (int kc = 0; kc < 8; ++kc)
            w4[mt][kc] = *(const s16x8*)(wt4 + (size_t)(chb + mt * 16 + lq) * 256 + kc * 32 + g * 8);
    }
    const int ch1 = chb1 + g * 4, ch2 = chb2 + g * 4;
    const f32x4 av1 = *(const f32x4*)(A1 + ch1);
    const f32x4 cv1 = *(const f32x4*)(C1 + ch1);
    const f32x4 av2 = *(const f32x4*)(A2 + ch2);
    const f32x4 cv2 = *(const f32x4*)(C2 + ch2);
    f32x4 av3[2], cv3[2], bv4[2];
#pragma unroll
    for (int mt = 0; mt < 2; ++mt) {
        av3[mt] = *(const f32x4*)(A3 + chb + mt * 16 + g * 4);
        cv3[mt] = *(const f32x4*)(C3 + chb + mt * 16 + g * 4);
        bv4[mt] = *(const f32x4*)(b4 + chb + mt * 16 + g * 4);
    }

    const int vb = blockIdx.x * 16;
    const int pstart = base[vb], pend = base[vb + 16];
    const int chgrp = tid & 31, slot = tid >> 5;
    const int vlo = base[vb + slot], vhi = base[vb + slot + 1];
    float rmax[8];
#pragma unroll
    for (int j = 0; j < 8; ++j) rmax[j] = -INFINITY;

    for (int t0 = pstart; t0 < pend; t0 += 64) {
        // L1 (B direct from X)
        f32x4 acc1[2];
#pragma unroll
        for (int ct = 0; ct < 2; ++ct) acc1[ct] = (f32x4){0.f,0.f,0.f,0.f};
#pragma unroll
        for (int ct = 0; ct < 2; ++ct) {
            const int row = wn * 32 + ct * 16 + lq;
            const s16x8 b = *(const s16x8*)(Xg + (size_t)(t0 + row) * 16 + g * 8);
            acc1[ct] = __builtin_amdgcn_mfma_f32_16x16x32_bf16(a1, b, acc1[ct], 0, 0, 0);
        }
#pragma unroll
        for (int ct = 0; ct < 2; ++ct) {
            const int row = wn * 32 + ct * 16 + lq;
            *(s16x4*)(act1 + swz<128>(row, ch1 * 2)) = bn_relu_pack(acc1[ct], av1, cv1);
        }
        __syncthreads();
        // L2
        f32x4 acc2[4];
#pragma unroll
        for (int ct = 0; ct < 4; ++ct) acc2[ct] = (f32x4){0.f,0.f,0.f,0.f};
#pragma unroll
        for (int kc = 0; kc < 2; ++kc) {
#pragma unroll
            for (int ct = 0; ct < 4; ++ct) {
                const s16x8 b = *(const s16x8*)(act1 + swz<128>(ct * 16 + lq, kc * 64 + g * 16));
                acc2[ct] = __builtin_amdgcn_mfma_f32_16x16x32_bf16(w2f[kc], b, acc2[ct], 0, 0, 0);
            }
        }
#pragma unroll
        for (int ct = 0; ct < 4; ++ct)
            *(s16x4*)(H + swz<256>(ct * 16 + lq, ch2 * 2)) = bn_relu_pack(acc2[ct], av2, cv2);
        __syncthreads();
        // L3
        f32x4 acc3[2][4];
#pragma unroll
        for (int mt = 0; mt < 2; ++mt)
#pragma unroll
            for (int ct = 0; ct < 4; ++ct) acc3[mt][ct] = (f32x4){0.f,0.f,0.f,0.f};
#pragma unroll
        for (int kc = 0; kc < 4; ++kc) {
#pragma unroll
            for (int ct = 0; ct < 4; ++ct) {
                const s16x8 b = *(const s16x8*)(H + swz<256>(ct * 16 + lq, kc * 64 + g * 16));
#pragma unroll
                for (int mt = 0; mt < 2; ++mt)
                    acc3[mt][ct] = __builtin_amdgcn_mfma_f32_16x16x32_bf16(w3[mt][kc], b, acc3[mt][ct], 0, 0, 0);
            }
        }
#pragma unroll
        for (int mt = 0; mt < 2; ++mt)
#pragma unroll
            for (int ct = 0; ct < 4; ++ct)
                *(s16x4*)(act3 + swz<512>(ct * 16 + lq, (chb + mt * 16 + g * 4) * 2)) =
                    bn_relu_pack(acc3[mt][ct], av3[mt], cv3[mt]);
        __syncthreads();
        // L4
        f32x4 acc4[2][4];
#pragma unroll
        for (int mt = 0; mt < 2; ++mt)
#pragma unroll
            for (int ct = 0; ct < 4; ++ct) acc4[mt][ct] = (f32x4){0.f,0.f,0.f,0.f};
#pragma unroll
        for (int kc = 0; kc < 8; ++kc) {
#pragma unroll
            for (int ct = 0; ct < 4; ++ct) {
                const s16x8 b = *(const s16x8*)(act3 + swz<512>(ct * 16 + lq, kc * 64 + g * 16));
#pragma unroll
                for (int mt = 0; mt < 2; ++mt)
                    acc4[mt][ct] = __builtin_amdgcn_mfma_f32_16x16x32_bf16(w4[mt][kc], b, acc4[mt][ct], 0, 0, 0);
            }
        }
#pragma unroll
        for (int mt = 0; mt < 2; ++mt) {
#pragma unroll
            for (int ct = 0; ct < 4; ++ct) {
                s16x4 pk;
#pragma unroll
                for (int r = 0; r < 4; ++r) pk[r] = (short)f2bf(acc4[mt][ct][r] + bv4[mt][r]);
                *(s16x4*)(H + swz<512>(ct * 16 + lq, (chb + mt * 16 + g * 4) * 2)) = pk;
            }
        }
        __syncthreads();
        {
            const int lo = max(vlo, t0), hi = min(vhi, t0 + 64);
            for (int p = lo; p < hi; ++p) {
                const s16x8 hv = *(const s16x8*)(H + swz<512>(p - t0, chgrp * 16));
#pragma unroll
                for (int j = 0; j < 8; ++j)
                    rmax[j] = fmaxf(rmax[j], bf2f((unsigned short)hv[j]));
            }
        }
        __syncthreads();
    }
    float* orow = out + (size_t)(vb + slot) * 256 + chgrp * 8;
    f32x4 o0, o1;
#pragma unroll
    for (int j = 0; j < 4; ++j) { o0[j] = rmax[j]; o1[j] = rmax[4 + j]; }
    *(f32x4*)orow = o0;
    *(f32x4*)(orow + 4) = o1;
}

// =====================================================================
// pass4 T2 (lite): h3 -> BN3+ReLU -> L4 (W4 in regs) -> segment max
// =====================================================================
__global__ __launch_bounds__(512) void k_pass4l(
    const unsigned short* __restrict__ h3g,
    const unsigned short* __restrict__ wt4,
    const float* __restrict__ A3, const float* __restrict__ C3,
    const float* __restrict__ b4,
    const int* __restrict__ base, float* __restrict__ out, int N) {
    extern __shared__ char smem[];
    char* act3 = smem;            // 32K [64][512B]
    char* h4   = smem + 32768;    // 32K [64][512B]
    const int tid = threadIdx.x;
    const int w = tid >> 6, lane = tid & 63, g = lane >> 4, lq = lane & 15;
    const int chb = w * 32;

    s16x8 w4f[2][8];
#pragma unroll
    for (int mt = 0; mt < 2; ++mt)
#pragma unroll
        for (int kc = 0; kc < 8; ++kc)
            w4f[mt][kc] = *(const s16x8*)(wt4 + (size_t)(chb + mt * 16 + lq) * 256 + kc * 32 + g * 8);
    f32x4 bv4[2];
#pragma unroll
    for (int mt = 0; mt < 2; ++mt) bv4[mt] = *(const f32x4*)(b4 + chb + mt * 16 + g * 4);

    // staging assignment: thread owns col-chunk j (16B = 8 ch), rows rowg+16*it
    const int j = tid & 31, rowg = tid >> 5;
    const int c8 = j * 8;
    const f32x4 av3a = *(const f32x4*)(A3 + c8);
    const f32x4 av3b = *(const f32x4*)(A3 + c8 + 4);
    const f32x4 cv3a = *(const f32x4*)(C3 + c8);
    const f32x4 cv3b = *(const f32x4*)(C3 + c8 + 4);

    const int vb = blockIdx.x * 16;
    const int pstart = base[vb], pend = base[vb + 16];
    const int chgrp = tid & 31, slot = tid >> 5;
    const int vlo = base[vb + slot], vhi = base[vb + slot + 1];
    float rmax[8];
#pragma unroll
    for (int jj = 0; jj < 8; ++jj) rmax[jj] = -INFINITY;

    for (int t0 = pstart; t0 < pend; t0 += 64) {
        // stage h3 tile with BN3+ReLU (coalesced 16B loads)
#pragma unroll
        for (int it = 0; it < 4; ++it) {
            const int row = rowg + it * 16;
            const int gp = min(t0 + row, N - 1);
            const s16x8 v = *(const s16x8*)(h3g + (size_t)gp * 256 + c8);
            s16x8 pk;
#pragma unroll
            for (int r = 0; r < 4; ++r) {
                pk[r]     = (short)f2bf(fmaxf(fmaf(bf2f((unsigned short)v[r]), av3a[r], cv3a[r]), 0.f));
                pk[4 + r] = (short)f2bf(fmaxf(fmaf(bf2f((unsigned short)v[4 + r]), av3b[r], cv3b[r]), 0.f));
            }
            *(s16x8*)(act3 + swz<512>(row, c8 * 2)) = pk;
        }
        __syncthreads();
        // L4
        f32x4 acc4[2][4];
#pragma unroll
        for (int mt = 0; mt < 2; ++mt)
#pragma unroll
            for (int ct = 0; ct < 4; ++ct) acc4[mt][ct] = (f32x4){0.f,0.f,0.f,0.f};
#pragma unroll
        for (int kc = 0; kc < 8; ++kc) {
#pragma unroll
            for (int ct = 0; ct < 4; ++ct) {
                const s16x8 b = *(const s16x8*)(act3 + swz<512>(ct * 16 + lq, kc * 64 + g * 16));
#pragma unroll
                for (int mt = 0; mt < 2; ++mt)
                    acc4[mt][ct] = __builtin_amdgcn_mfma_f32_16x16x32_bf16(w4f[mt][kc], b, acc4[mt][ct], 0, 0, 0);
            }
        }
#pragma unroll
        for (int mt = 0; mt < 2; ++mt) {
#pragma unroll
            for (int ct = 0; ct < 4; ++ct) {
                s16x4 pk;
#pragma unroll
                for (int r = 0; r < 4; ++r) pk[r] = (short)f2bf(acc4[mt][ct][r] + bv4[mt][r]);
                *(s16x4*)(h4 + swz<512>(ct * 16 + lq, (chb + mt * 16 + g * 4) * 2)) = pk;
            }
        }
        __syncthreads();
        {
            const int lo = max(vlo, t0), hi = min(vhi, t0 + 64);
            for (int p = lo; p < hi; ++p) {
                const s16x8 hv = *(const s16x8*)(h4 + swz<512>(p - t0, chgrp * 16));
#pragma unroll
                for (int jj = 0; jj < 8; ++jj)
                    rmax[jj] = fmaxf(rmax[jj], bf2f((unsigned short)hv[jj]));
            }
        }
        __syncthreads();
    }
    float* orow = out + (size_t)(vb + slot) * 256 + chgrp * 8;
    f32x4 o0, o1;
#pragma unroll
    for (int jj = 0; jj < 4; ++jj) { o0[jj] = rmax[jj]; o1[jj] = rmax[4 + jj]; }
    *(f32x4*)orow = o0;
    *(f32x4*)(orow + 4) = o1;
}

extern "C" void kernel_launch(void* const* d_in, const int* in_sizes, int n_in,
                              void* d_out, int out_size, void* d_ws, size_t ws_size,
                              hipStream_t stream) {
    const float* feats = (const float*)d_in[0];
    const int* coords = (const int*)d_in[1];
    const float* g0 = (const float*)d_in[3];
    const float* be0 = (const float*)d_in[4];
    const float* W1 = (const float*)d_in[5];
    const float* b1 = (const float*)d_in[6];
    const float* g1 = (const float*)d_in[7];
    const float* be1 = (const float*)d_in[8];
    const float* W2 = (const float*)d_in[9];
    const float* b2 = (const float*)d_in[10];
    const float* g2 = (const float*)d_in[11];
    const float* be2 = (const float*)d_in[12];
    const float* W3 = (const float*)d_in[13];
    const float* b3 = (const float*)d_in[14];
    const float* g3 = (const float*)d_in[15];
    const float* be3 = (const float*)d_in[16];
    const float* W4 = (const float*)d_in[17];
    const float* b4 = (const float*)d_in[18];
    float* out = (float*)d_out;
    char* ws = (char*)d_ws;

    const int N = in_sizes[0] / 9;
    const float fN = (float)N;
    const int nt = (N + 127) / 128;

    const size_t xg_bytes = (size_t)nt * 4096u + 8192u;   // + overread pad
    const size_t h3_off = X_OFF + ((xg_bytes + 255u) & ~(size_t)255u);
    const size_t need_t2 = h3_off + (size_t)nt * 65536u + 65536u;
    const bool t2 = (ws_size >= need_t2);

    hipMemsetAsync(ws, 0, PAR_END, stream);
    hipMemsetAsync(ws + HIST_OFF, 0, 131072, stream);

    unsigned short* Xg = (unsigned short*)(ws + X_OFF);
    unsigned short* H3 = (unsigned short*)(ws + h3_off);
    const unsigned short* wt1 = (const unsigned short*)(ws + WT1_OFF);
    const unsigned short* wt2 = (const unsigned short*)(ws + WT2_OFF);
    const unsigned short* wt3 = (const unsigned short*)(ws + WT3_OFF);
    const unsigned short* wt4 = (const unsigned short*)(ws + WT4_OFF);
    float* A0 = (float*)(ws + A0_OFF); float* C0 = (float*)(ws + C0_OFF);
    float* A1 = (float*)(ws + A1_OFF); float* C1 = (float*)(ws + C1_OFF);
    float* A2 = (float*)(ws + A2_OFF); float* C2 = (float*)(ws + C2_OFF);
    float* A3 = (float*)(ws + A3_OFF); float* C3 = (float*)(ws + C3_OFF);

    hipFuncSetAttribute((const void*)k_pass4,
        hipFuncAttributeMaxDynamicSharedMemorySize, 73728);
    hipFuncSetAttribute((const void*)k_pass4l,
        hipFuncAttributeMaxDynamicSharedMemorySize, 65536);

    k_prepw<<<128, TPB, 0, stream>>>(W1, W2, W3, W4,
        (unsigned short*)(ws + WT1_OFF), (unsigned short*)(ws + WT2_OFF),
        (unsigned short*)(ws + WT3_OFF), (unsigned short*)(ws + WT4_OFF));
    k_hist_stats<<<1024, TPB, 0, stream>>>(coords, feats, N,
        (unsigned*)(ws + HIST_OFF), (float*)(ws + P0_OFF));
    k_scan<<<1, 1024, 0, stream>>>((const unsigned*)(ws + HIST_OFF),
                                   (int*)(ws + BASE_OFF), (unsigned*)(ws + CURS_OFF), N);
    k_scatter<<<1024, TPB, 0, stream>>>(coords, N, (unsigned*)(ws + CURS_OFF),
                                        (int*)(ws + PERM_OFF));
    k_fin<<<1, TPB, 0, stream>>>((const float*)(ws + P0_OFF), 1, 9, g0, be0, nullptr,
                                 A0, C0, fN);
    k_coords<<<(NVOX + TPB - 1) / TPB, TPB, 0, stream>>>(out + (size_t)NVOX * 256);

    k_pass1<<<1024, 256, 0, stream>>>(feats, (const int*)(ws + PERM_OFF), wt1,
        A0, C0, b1, Xg, (float*)(ws + P1_OFF), N, nt);
    k_fin<<<1, TPB, 0, stream>>>((const float*)(ws + P1_OFF), 64, 64, g1, be1, b1,
                                 A1, C1, fN);

    k_pass2<<<2048, 256, 0, stream>>>(Xg, wt1, wt2, A1, C1, b2,
                                      (float*)(ws + P2_OFF), N, nt);
    k_fin<<<1, TPB, 0, stream>>>((const float*)(ws + P2_OFF), 64, 128, g2, be2, b2,
                                 A2, C2, fN);

    if (t2) {
        k_pass3<1><<<1024, 512, 0, stream>>>(Xg, wt1, wt2, wt3, A1, C1, A2, C2, b3,
                                             (float*)(ws + P3_OFF), H3, N, nt);
        k_fin<<<1, TPB, 0, stream>>>((const float*)(ws + P3_OFF), 64, 256, g3, be3, b3,
                                     A3, C3, fN);
        k_pass4l<<<NVOX / 16, 512, 65536, stream>>>(H3, wt4, A3, C3, b4,
            (const int*)(ws + BASE_OFF), out, N);
    } else {
        k_pass3<0><<<1024, 512, 0, stream>>>(Xg, wt1, wt2, wt3, A1, C1, A2, C2, b3,
                                             (float*)(ws + P3_OFF), H3, N, nt);
        k_fin<<<1, TPB, 0, stream>>>((const float*)(ws + P3_OFF), 64, 256, g3, be3, b3,
                                     A3, C3, fN);
        k_pass4<<<NVOX / 16, 512, 73728, stream>>>(Xg, wt1, wt2, wt3, wt4,
            A1, C1, A2, C2, A3, C3, b4, (const int*)(ws + BASE_OFF), out);
    }
}

// Round 6
// 1008.121 us; speedup vs baseline: 17.6987x; 1.0015x over previous
//
#include <hip/hip_runtime.h>
#include <math.h>

#define TPB 256
#define NVOX 32768
#define BN_EPS 1e-5f

typedef short s16x8 __attribute__((ext_vector_type(8)));
typedef short s16x4 __attribute__((ext_vector_type(4)));
typedef float f32x4 __attribute__((ext_vector_type(4)));

// ---------------- ws byte offsets ----------------
#define P0_OFF     0u
#define P1_OFF     256u
#define P2_OFF     (P1_OFF + 64u*128u*4u)
#define P3_OFF     (P2_OFF + 64u*256u*4u)
#define PAR_END    (P3_OFF + 64u*512u*4u)        // 229632
#define A0_OFF     229632u
#define C0_OFF     229888u
#define A1_OFF     230144u
#define C1_OFF     230400u
#define A2_OFF     230656u
#define C2_OFF     231680u
#define A3_OFF     232704u
#define C3_OFF     233728u
#define HIST_OFF   234752u
#define BASE_OFF   (HIST_OFF + 131072u)
#define CURS_OFF   (BASE_OFF + 131328u)
#define WT1_OFF    (CURS_OFF + 131072u)
#define WT2_OFF    (WT1_OFF + 4096u)
#define WT3_OFF    (WT2_OFF + 16384u)
#define WT4_OFF    (WT3_OFF + 65536u)
#define X_OFF      4845568u                // X bf16 [Npad][16], voxel-sorted

__device__ __forceinline__ unsigned short f2bf(float f) {
    unsigned u = __float_as_uint(f);
    u += 0x7FFFu + ((u >> 16) & 1u);
    return (unsigned short)(u >> 16);
}
__device__ __forceinline__ float bf2f(unsigned short h) {
    return __uint_as_float(((unsigned)h) << 16);
}

template<int ROWB>
__device__ __forceinline__ int swz(int row, int b) {
    constexpr int M = (ROWB >= 128) ? 7 : ((ROWB >= 64) ? 3 : 1);
    return row * ROWB + (b ^ ((row & M) << 4));
}

__device__ __forceinline__ s16x4 bn_relu_pack(f32x4 acc, f32x4 av, f32x4 cv) {
    s16x4 pk;
#pragma unroll
    for (int r = 0; r < 4; ++r) pk[r] = (short)f2bf(fmaxf(fmaf(acc[r], av[r], cv[r]), 0.f));
    return pk;
}

template<int NOUT>
__device__ __forceinline__ void stats_red(f32x4 ps, f32x4 pq, int ch, float* prow) {
#pragma unroll
    for (int m = 1; m <= 8; m <<= 1) {
#pragma unroll
        for (int r = 0; r < 4; ++r) { ps[r] += __shfl_xor(ps[r], m); pq[r] += __shfl_xor(pq[r], m); }
    }
    if ((threadIdx.x & 15) == 0) {
#pragma unroll
        for (int r = 0; r < 4; ++r) {
            atomicAdd(&prow[ch + r], ps[r]);
            atomicAdd(&prow[NOUT + ch + r], pq[r]);
        }
    }
}

// ---------------- prep kernels ----------------
__global__ void k_prepw(const float* __restrict__ W1, const float* __restrict__ W2,
                        const float* __restrict__ W3, const float* __restrict__ W4,
                        unsigned short* __restrict__ wt1, unsigned short* __restrict__ wt2,
                        unsigned short* __restrict__ wt3, unsigned short* __restrict__ wt4) {
    for (int i = blockIdx.x * blockDim.x + threadIdx.x; i < 108544;
         i += gridDim.x * blockDim.x) {
        if (i < 2048) {
            int n = i >> 5, k = i & 31;
            wt1[i] = (k < 9) ? f2bf(W1[k * 64 + n]) : (unsigned short)0;
        } else if (i < 10240) {
            int j = i - 2048; int n = j >> 6, k = j & 63;
            wt2[j] = f2bf(W2[k * 128 + n]);
        } else if (i < 43008) {
            int j = i - 10240; int n = j >> 7, k = j & 127;
            wt3[j] = f2bf(W3[k * 256 + n]);
        } else {
            int j = i - 43008; int n = j >> 8, k = j & 255;
            wt4[j] = f2bf(W4[k * 256 + n]);
        }
    }
}

__global__ void k_hist_stats(const int* __restrict__ coords, const float* __restrict__ feats,
                             int N, unsigned* __restrict__ hist, float* __restrict__ p0) {
    __shared__ float s[9], q[9];
    if (threadIdx.x < 9) { s[threadIdx.x] = 0.f; q[threadIdx.x] = 0.f; }
    __syncthreads();
    float ls[9] = {0}, lq[9] = {0};
    for (int i = blockIdx.x * blockDim.x + threadIdx.x; i < N;
         i += gridDim.x * blockDim.x) {
        int v = (coords[3 * i] << 10) | (coords[3 * i + 1] << 5) | coords[3 * i + 2];
        atomicAdd(&hist[v], 1u);
        const float* r = feats + (size_t)i * 9;
#pragma unroll
        for (int c = 0; c < 9; ++c) { float x = r[c]; ls[c] += x; lq[c] += x * x; }
    }
#pragma unroll
    for (int c = 0; c < 9; ++c) { atomicAdd(&s[c], ls[c]); atomicAdd(&q[c], lq[c]); }
    __syncthreads();
    if (threadIdx.x < 9) {
        atomicAdd(&p0[threadIdx.x], s[threadIdx.x]);
        atomicAdd(&p0[9 + threadIdx.x], q[threadIdx.x]);
    }
}

__global__ void k_scan(const unsigned* __restrict__ hist, int* __restrict__ base,
                       unsigned* __restrict__ cursor, int N) {
    __shared__ unsigned part[1024];
    const int t = threadIdx.x;
    unsigned sum = 0;
    for (int j = 0; j < 32; ++j) sum += hist[t * 32 + j];
    part[t] = sum;
    __syncthreads();
    for (int d = 1; d < 1024; d <<= 1) {
        unsigned v = (t >= d) ? part[t - d] : 0u;
        __syncthreads();
        part[t] += v;
        __syncthreads();
    }
    unsigned run = part[t] - sum;
    for (int j = 0; j < 32; ++j) {
        unsigned h = hist[t * 32 + j];
        base[t * 32 + j] = (int)run;
        cursor[t * 32 + j] = run;
        run += h;
    }
    if (t == 1023) base[32768] = (int)run;
}

// fused scatter: gather feats, apply BN0, write X in voxel-sorted order
__global__ void k_scatter2(const int* __restrict__ coords, const float* __restrict__ feats,
                           int N, unsigned* __restrict__ cursor,
                           const float* __restrict__ A0, const float* __restrict__ C0,
                           unsigned short* __restrict__ Xg) {
    float a0[9], c0[9];
#pragma unroll
    for (int c = 0; c < 9; ++c) { a0[c] = A0[c]; c0[c] = C0[c]; }
    for (int i = blockIdx.x * blockDim.x + threadIdx.x; i < N;
         i += gridDim.x * blockDim.x) {
        int v = (coords[3 * i] << 10) | (coords[3 * i + 1] << 5) | coords[3 * i + 2];
        unsigned pos = atomicAdd(&cursor[v], 1u);
        const float* r = feats + (size_t)i * 9;
        s16x8 lo, hi;
#pragma unroll
        for (int c = 0; c < 8; ++c) lo[c] = (short)f2bf(fmaf(r[c], a0[c], c0[c]));
        hi = (s16x8){0, 0, 0, 0, 0, 0, 0, 0};
        hi[0] = (short)f2bf(fmaf(r[8], a0[8], c0[8]));
        *(s16x8*)(Xg + (size_t)pos * 16) = lo;
        *(s16x8*)(Xg + (size_t)pos * 16 + 8) = hi;
    }
}

__global__ void k_fin(const float* __restrict__ part, int nparts, int C,
                      const float* __restrict__ g, const float* __restrict__ be,
                      const float* __restrict__ bias,
                      float* __restrict__ A, float* __restrict__ Cc, float n) {
    int c = threadIdx.x;
    if (c >= C) return;
    float s = 0.f, q = 0.f;
    for (int r = 0; r < nparts; ++r) { s += part[r * 2 * C + c]; q += part[r * 2 * C + C + c]; }
    float m = s / n;
    float v = q / n - m * m;
    float a = g[c] * rsqrtf(v + BN_EPS);
    float cc = be[c] - m * a;
    A[c] = a;
    Cc[c] = bias ? fmaf(a, bias[c], cc) : cc;
}

__global__ void k_coords(float* __restrict__ outc) {
    int v = blockIdx.x * blockDim.x + threadIdx.x;
    if (v < NVOX) {
        outc[3 * v + 0] = (float)(v >> 10);
        outc[3 * v + 1] = (float)((v >> 5) & 31);
        outc[3 * v + 2] = (float)(v & 31);
    }
}

// =====================================================================
// pass1s: stats of h1 from linear X (no LDS)
// =====================================================================
__global__ __launch_bounds__(256) void k_pass1s(
    const unsigned short* __restrict__ Xg, const unsigned short* __restrict__ wt1,
    const float* __restrict__ b1, float* __restrict__ p1, int N, int nt) {
    const int tid = threadIdx.x;
    const int w = tid >> 6, lane = tid & 63, g = lane >> 4, lq = lane & 15;
    const int chb = w * 16;
    const s16x8 a1 = *(const s16x8*)(wt1 + (chb + lq) * 32 + g * 8);
    const int ch = chb + g * 4;
    const f32x4 bv = *(const f32x4*)(b1 + ch);
    f32x4 ps = (f32x4){0.f,0.f,0.f,0.f}, pq = (f32x4){0.f,0.f,0.f,0.f};
    for (int t = blockIdx.x; t < nt; t += gridDim.x) {
        const int t0 = t * 128;
#pragma unroll
        for (int ct = 0; ct < 8; ++ct) {
            const int p = t0 + ct * 16 + lq;
            const s16x8 b = *(const s16x8*)(Xg + (size_t)p * 16 + g * 8);
            f32x4 a = (f32x4){0.f,0.f,0.f,0.f};
            a = __builtin_amdgcn_mfma_f32_16x16x32_bf16(a1, b, a, 0, 0, 0);
            const bool valid = p < N;
#pragma unroll
            for (int r = 0; r < 4; ++r) {
                const float h = valid ? (a[r] + bv[r]) : 0.f;
                ps[r] += h; pq[r] += h * h;
            }
        }
    }
    stats_red<64>(ps, pq, ch, p1 + (blockIdx.x & 63) * 128);
}

// =====================================================================
// pass2: X -> L1 -> L2 stats.  1 barrier/tile (act1 double-buffered).
// =====================================================================
__global__ __launch_bounds__(256) void k_pass2(
    const unsigned short* __restrict__ Xg,
    const unsigned short* __restrict__ wt1, const unsigned short* __restrict__ wt2,
    const float* __restrict__ A1, const float* __restrict__ C1,
    const float* __restrict__ b2,
    float* __restrict__ p2, int N, int nt) {
    __shared__ char act1[2][16384];   // [128][128B] swz<128>
    const int tid = threadIdx.x;
    const int w = tid >> 6, lane = tid & 63, g = lane >> 4, lq = lane & 15;
    const int chb1 = w * 16, chb2 = w * 32;
    const s16x8 a1 = *(const s16x8*)(wt1 + (chb1 + lq) * 32 + g * 8);
    s16x8 w2f[2][2];
#pragma unroll
    for (int mt = 0; mt < 2; ++mt)
#pragma unroll
        for (int kc = 0; kc < 2; ++kc)
            w2f[mt][kc] = *(const s16x8*)(wt2 + (size_t)(chb2 + mt * 16 + lq) * 64 + kc * 32 + g * 8);
    const int ch1 = chb1 + g * 4;
    const f32x4 av1 = *(const f32x4*)(A1 + ch1);
    const f32x4 cv1 = *(const f32x4*)(C1 + ch1);
    f32x4 bv2[2];
#pragma unroll
    for (int mt = 0; mt < 2; ++mt) bv2[mt] = *(const f32x4*)(b2 + chb2 + mt * 16 + g * 4);
    f32x4 ps[2], pq[2];
#pragma unroll
    for (int mt = 0; mt < 2; ++mt) { ps[mt] = (f32x4){0.f,0.f,0.f,0.f}; pq[mt] = (f32x4){0.f,0.f,0.f,0.f}; }

    int t = blockIdx.x;
    if (t < nt) {
        // prologue L1 -> buf0
#pragma unroll
        for (int ct = 0; ct < 8; ++ct) {
            const int row = ct * 16 + lq;
            const s16x8 b = *(const s16x8*)(Xg + (size_t)(t * 128 + row) * 16 + g * 8);
            f32x4 a = (f32x4){0.f,0.f,0.f,0.f};
            a = __builtin_amdgcn_mfma_f32_16x16x32_bf16(a1, b, a, 0, 0, 0);
            *(s16x4*)(act1[0] + swz<128>(row, ch1 * 2)) = bn_relu_pack(a, av1, cv1);
        }
        __syncthreads();
        int cur = 0;
        while (true) {
            const int tn = t + gridDim.x;
            const bool more = tn < nt;
            const int t0 = t * 128;
            // L2 + stats from act1[cur]
            f32x4 acc2[2][8];
#pragma unroll
            for (int mt = 0; mt < 2; ++mt)
#pragma unroll
                for (int ct = 0; ct < 8; ++ct) acc2[mt][ct] = (f32x4){0.f,0.f,0.f,0.f};
#pragma unroll
            for (int kc = 0; kc < 2; ++kc)
#pragma unroll
                for (int ct = 0; ct < 8; ++ct) {
                    const s16x8 b = *(const s16x8*)(act1[cur] + swz<128>(ct * 16 + lq, kc * 64 + g * 16));
#pragma unroll
                    for (int mt = 0; mt < 2; ++mt)
                        acc2[mt][ct] = __builtin_amdgcn_mfma_f32_16x16x32_bf16(w2f[mt][kc], b, acc2[mt][ct], 0, 0, 0);
                }
#pragma unroll
            for (int mt = 0; mt < 2; ++mt)
#pragma unroll
                for (int ct = 0; ct < 8; ++ct) {
                    const bool valid = (t0 + ct * 16 + lq) < N;
#pragma unroll
                    for (int r = 0; r < 4; ++r) {
                        const float h = valid ? (acc2[mt][ct][r] + bv2[mt][r]) : 0.f;
                        ps[mt][r] += h; pq[mt][r] += h * h;
                    }
                }
            // prefetch next tile's L1 into other buffer
            if (more) {
#pragma unroll
                for (int ct = 0; ct < 8; ++ct) {
                    const int row = ct * 16 + lq;
                    const s16x8 b = *(const s16x8*)(Xg + (size_t)(tn * 128 + row) * 16 + g * 8);
                    f32x4 a = (f32x4){0.f,0.f,0.f,0.f};
                    a = __builtin_amdgcn_mfma_f32_16x16x32_bf16(a1, b, a, 0, 0, 0);
                    *(s16x4*)(act1[cur ^ 1] + swz<128>(row, ch1 * 2)) = bn_relu_pack(a, av1, cv1);
                }
            }
            __syncthreads();
            if (!more) break;
            t = tn; cur ^= 1;
        }
    }
    float* prow = p2 + (blockIdx.x & 63) * 256;
#pragma unroll
    for (int mt = 0; mt < 2; ++mt)
        stats_red<128>(ps[mt], pq[mt], chb2 + mt * 16 + g * 4, prow);
}

// =====================================================================
// pass3: X -> L1 -> L2 -> L3 stats.  Tile 64, 2-phase pipeline.
// =====================================================================
__global__ __launch_bounds__(512) void k_pass3(
    const unsigned short* __restrict__ Xg,
    const unsigned short* __restrict__ wt1, const unsigned short* __restrict__ wt2,
    const unsigned short* __restrict__ wt3,
    const float* __restrict__ A1, const float* __restrict__ C1,
    const float* __restrict__ A2, const float* __restrict__ C2,
    const float* __restrict__ b3,
    float* __restrict__ p3, int N, int nt) {
    __shared__ char act1[8192];    // [64][128B]
    __shared__ char act2[16384];   // [64][256B]
    const int tid = threadIdx.x;
    const int w = tid >> 6, lane = tid & 63, g = lane >> 4, lq = lane & 15;
    const int wm = w >> 1, wn = w & 1;
    const int chb1 = wm * 16, chb2 = w * 16, chb3 = w * 32;
    const s16x8 a1 = *(const s16x8*)(wt1 + (chb1 + lq) * 32 + g * 8);
    s16x8 w2f[2], w3f[2][4];
#pragma unroll
    for (int kc = 0; kc < 2; ++kc)
        w2f[kc] = *(const s16x8*)(wt2 + (size_t)(chb2 + lq) * 64 + kc * 32 + g * 8);
#pragma unroll
    for (int mt = 0; mt < 2; ++mt)
#pragma unroll
        for (int kc = 0; kc < 4; ++kc)
            w3f[mt][kc] = *(const s16x8*)(wt3 + (size_t)(chb3 + mt * 16 + lq) * 128 + kc * 32 + g * 8);
    const int ch1 = chb1 + g * 4, ch2 = chb2 + g * 4;
    const f32x4 av1 = *(const f32x4*)(A1 + ch1);
    const f32x4 cv1 = *(const f32x4*)(C1 + ch1);
    const f32x4 av2 = *(const f32x4*)(A2 + ch2);
    const f32x4 cv2 = *(const f32x4*)(C2 + ch2);
    f32x4 bv3[2];
#pragma unroll
    for (int mt = 0; mt < 2; ++mt) bv3[mt] = *(const f32x4*)(b3 + chb3 + mt * 16 + g * 4);
    f32x4 ps[2], pq[2];
#pragma unroll
    for (int mt = 0; mt < 2; ++mt) { ps[mt] = (f32x4){0.f,0.f,0.f,0.f}; pq[mt] = (f32x4){0.f,0.f,0.f,0.f}; }

    int t = blockIdx.x;
    if (t < nt) {
        // prologue: L1(t) -> act1 ; L2 -> act2
#pragma unroll
        for (int ct = 0; ct < 2; ++ct) {
            const int row = wn * 32 + ct * 16 + lq;
            const s16x8 b = *(const s16x8*)(Xg + (size_t)(t * 64 + row) * 16 + g * 8);
            f32x4 a = (f32x4){0.f,0.f,0.f,0.f};
            a = __builtin_amdgcn_mfma_f32_16x16x32_bf16(a1, b, a, 0, 0, 0);
            *(s16x4*)(act1 + swz<128>(row, ch1 * 2)) = bn_relu_pack(a, av1, cv1);
        }
        __syncthreads();
        {
            f32x4 acc[4];
#pragma unroll
            for (int ct = 0; ct < 4; ++ct) acc[ct] = (f32x4){0.f,0.f,0.f,0.f};
#pragma unroll
            for (int kc = 0; kc < 2; ++kc)
#pragma unroll
                for (int ct = 0; ct < 4; ++ct) {
                    const s16x8 b = *(const s16x8*)(act1 + swz<128>(ct * 16 + lq, kc * 64 + g * 16));
                    acc[ct] = __builtin_amdgcn_mfma_f32_16x16x32_bf16(w2f[kc], b, acc[ct], 0, 0, 0);
                }
#pragma unroll
            for (int ct = 0; ct < 4; ++ct)
                *(s16x4*)(act2 + swz<256>(ct * 16 + lq, ch2 * 2)) = bn_relu_pack(acc[ct], av2, cv2);
        }
        __syncthreads();
        while (true) {
            const int tn = t + gridDim.x;
            const bool more = tn < nt;
            // phase A: prefetch L1(tn) + L3(t)+stats
            s16x8 xb[2];
            if (more) {
#pragma unroll
                for (int ct = 0; ct < 2; ++ct) {
                    const int row = wn * 32 + ct * 16 + lq;
                    xb[ct] = *(const s16x8*)(Xg + (size_t)(tn * 64 + row) * 16 + g * 8);
                }
            }
            {
                f32x4 acc[2][4];
#pragma unroll
                for (int mt = 0; mt < 2; ++mt)
#pragma unroll
                    for (int ct = 0; ct < 4; ++ct) acc[mt][ct] = (f32x4){0.f,0.f,0.f,0.f};
#pragma unroll
                for (int kc = 0; kc < 4; ++kc)
#pragma unroll
                    for (int ct = 0; ct < 4; ++ct) {
                        const s16x8 b = *(const s16x8*)(act2 + swz<256>(ct * 16 + lq, kc * 64 + g * 16));
#pragma unroll
                        for (int mt = 0; mt < 2; ++mt)
                            acc[mt][ct] = __builtin_amdgcn_mfma_f32_16x16x32_bf16(w3f[mt][kc], b, acc[mt][ct], 0, 0, 0);
                    }
                const int t0 = t * 64;
#pragma unroll
                for (int mt = 0; mt < 2; ++mt)
#pragma unroll
                    for (int ct = 0; ct < 4; ++ct) {
                        const bool valid = (t0 + ct * 16 + lq) < N;
#pragma unroll
                        for (int r = 0; r < 4; ++r) {
                            const float h = valid ? (acc[mt][ct][r] + bv3[mt][r]) : 0.f;
                            ps[mt][r] += h; pq[mt][r] += h * h;
                        }
                    }
            }
            if (more) {
#pragma unroll
                for (int ct = 0; ct < 2; ++ct) {
                    const int row = wn * 32 + ct * 16 + lq;
                    f32x4 a = (f32x4){0.f,0.f,0.f,0.f};
                    a = __builtin_amdgcn_mfma_f32_16x16x32_bf16(a1, xb[ct], a, 0, 0, 0);
                    *(s16x4*)(act1 + swz<128>(row, ch1 * 2)) = bn_relu_pack(a, av1, cv1);
                }
            }
            __syncthreads();
            // phase B: L2(tn)
            if (more) {
                f32x4 acc[4];
#pragma unroll
                for (int ct = 0; ct < 4; ++ct) acc[ct] = (f32x4){0.f,0.f,0.f,0.f};
#pragma unroll
                for (int kc = 0; kc < 2; ++kc)
#pragma unroll
                    for (int ct = 0; ct < 4; ++ct) {
                        const s16x8 b = *(const s16x8*)(act1 + swz<128>(ct * 16 + lq, kc * 64 + g * 16));
                        acc[ct] = __builtin_amdgcn_mfma_f32_16x16x32_bf16(w2f[kc], b, acc[ct], 0, 0, 0);
                    }
#pragma unroll
                for (int ct = 0; ct < 4; ++ct)
                    *(s16x4*)(act2 + swz<256>(ct * 16 + lq, ch2 * 2)) = bn_relu_pack(acc[ct], av2, cv2);
            }
            __syncthreads();
            if (!more) break;
            t = tn;
        }
    }
    float* prow = p3 + (blockIdx.x & 63) * 512;
#pragma unroll
    for (int mt = 0; mt < 2; ++mt)
        stats_red<256>(ps[mt], pq[mt], chb3 + mt * 16 + g * 4, prow);
}

// =====================================================================
// pass4: X -> L1..L4 -> segment max.  2-phase pipeline, in-reg segmax.
// =====================================================================
__global__ __launch_bounds__(512) void k_pass4(
    const unsigned short* __restrict__ Xg,
    const unsigned short* __restrict__ wt1, const unsigned short* __restrict__ wt2,
    const unsigned short* __restrict__ wt3, const unsigned short* __restrict__ wt4,
    const float* __restrict__ A1, const float* __restrict__ C1,
    const float* __restrict__ A2, const float* __restrict__ C2,
    const float* __restrict__ A3, const float* __restrict__ C3,
    const float* __restrict__ b4,
    const int* __restrict__ base, float* __restrict__ out) {
    extern __shared__ char smem[];
    char* act1 = smem;                      // 8K  [64][128B]
    char* act2 = smem + 8192;               // 16K [64][256B]
    char* act3 = smem + 24576;              // 32K [64][512B]
    float* vmax = (float*)(smem + 57344);   // 16K [16][256]

    const int tid = threadIdx.x;
    const int w = tid >> 6, lane = tid & 63, g = lane >> 4, lq = lane & 15;
    const int wm = w >> 1, wn = w & 1;
    const int chb1 = wm * 16, chb2 = w * 16, chb = w * 32;
    const int vb = blockIdx.x * 16;

    int bsv[17];
#pragma unroll
    for (int s = 0; s <= 16; ++s) bsv[s] = base[vb + s];
    const int pstart = bsv[0], pend = bsv[16];

    const s16x8 a1 = *(const s16x8*)(wt1 + (chb1 + lq) * 32 + g * 8);
    s16x8 w2f[2], w3f[2][4], w4f[2][8];
#pragma unroll
    for (int kc = 0; kc < 2; ++kc)
        w2f[kc] = *(const s16x8*)(wt2 + (size_t)(chb2 + lq) * 64 + kc * 32 + g * 8);
#pragma unroll
    for (int mt = 0; mt < 2; ++mt) {
#pragma unroll
        for (int kc = 0; kc < 4; ++kc)
            w3f[mt][kc] = *(const s16x8*)(wt3 + (size_t)(chb + mt * 16 + lq) * 128 + kc * 32 + g * 8);
#pragma unroll
        for (int kc = 0; kc < 8; ++kc)
            w4f[mt][kc] = *(const s16x8*)(wt4 + (size_t)(chb + mt * 16 + lq) * 256 + kc * 32 + g * 8);
    }
    const int ch1 = chb1 + g * 4, ch2 = chb2 + g * 4;
    const f32x4 av1 = *(const f32x4*)(A1 + ch1);
    const f32x4 cv1 = *(const f32x4*)(C1 + ch1);
    const f32x4 av2 = *(const f32x4*)(A2 + ch2);
    const f32x4 cv2 = *(const f32x4*)(C2 + ch2);
    f32x4 av3[2], cv3[2], bv4[2];
#pragma unroll
    for (int mt = 0; mt < 2; ++mt) {
        av3[mt] = *(const f32x4*)(A3 + chb + mt * 16 + g * 4);
        cv3[mt] = *(const f32x4*)(C3 + chb + mt * 16 + g * 4);
        bv4[mt] = *(const f32x4*)(b4 + chb + mt * 16 + g * 4);
    }

    for (int i = tid; i < 16 * 256; i += 512) vmax[i] = -INFINITY;
    __syncthreads();

    if (pstart < pend) {
        // prologue: L1(pstart) -> act1 ; L2 -> act2
#pragma unroll
        for (int ct = 0; ct < 2; ++ct) {
            const int row = wn * 32 + ct * 16 + lq;
            const s16x8 b = *(const s16x8*)(Xg + (size_t)(pstart + row) * 16 + g * 8);
            f32x4 a = (f32x4){0.f,0.f,0.f,0.f};
            a = __builtin_amdgcn_mfma_f32_16x16x32_bf16(a1, b, a, 0, 0, 0);
            *(s16x4*)(act1 + swz<128>(row, ch1 * 2)) = bn_relu_pack(a, av1, cv1);
        }
        __syncthreads();
        {
            f32x4 acc[4];
#pragma unroll
            for (int ct = 0; ct < 4; ++ct) acc[ct] = (f32x4){0.f,0.f,0.f,0.f};
#pragma unroll
            for (int kc = 0; kc < 2; ++kc)
#pragma unroll
                for (int ct = 0; ct < 4; ++ct) {
                    const s16x8 b = *(const s16x8*)(act1 + swz<128>(ct * 16 + lq, kc * 64 + g * 16));
                    acc[ct] = __builtin_amdgcn_mfma_f32_16x16x32_bf16(w2f[kc], b, acc[ct], 0, 0, 0);
                }
#pragma unroll
            for (int ct = 0; ct < 4; ++ct)
                *(s16x4*)(act2 + swz<256>(ct * 16 + lq, ch2 * 2)) = bn_relu_pack(acc[ct], av2, cv2);
        }
        __syncthreads();

        for (int t0 = pstart; t0 < pend; t0 += 64) {
            const int nxt = t0 + 64;
            const bool more = nxt < pend;
            // ===== phase A: prefetch L1(nxt) + L3(t0) =====
            s16x8 xb[2];
            if (more) {
#pragma unroll
                for (int ct = 0; ct < 2; ++ct) {
                    const int row = wn * 32 + ct * 16 + lq;
                    xb[ct] = *(const s16x8*)(Xg + (size_t)(nxt + row) * 16 + g * 8);
                }
            }
            {
                f32x4 acc[2][4];
#pragma unroll
                for (int mt = 0; mt < 2; ++mt)
#pragma unroll
                    for (int ct = 0; ct < 4; ++ct) acc[mt][ct] = (f32x4){0.f,0.f,0.f,0.f};
#pragma unroll
                for (int kc = 0; kc < 4; ++kc)
#pragma unroll
                    for (int ct = 0; ct < 4; ++ct) {
                        const s16x8 b = *(const s16x8*)(act2 + swz<256>(ct * 16 + lq, kc * 64 + g * 16));
#pragma unroll
                        for (int mt = 0; mt < 2; ++mt)
                            acc[mt][ct] = __builtin_amdgcn_mfma_f32_16x16x32_bf16(w3f[mt][kc], b, acc[mt][ct], 0, 0, 0);
                    }
#pragma unroll
                for (int mt = 0; mt < 2; ++mt)
#pragma unroll
                    for (int ct = 0; ct < 4; ++ct)
                        *(s16x4*)(act3 + swz<512>(ct * 16 + lq, (chb + mt * 16 + g * 4) * 2)) =
                            bn_relu_pack(acc[mt][ct], av3[mt], cv3[mt]);
            }
            if (more) {
#pragma unroll
                for (int ct = 0; ct < 2; ++ct) {
                    const int row = wn * 32 + ct * 16 + lq;
                    f32x4 a = (f32x4){0.f,0.f,0.f,0.f};
                    a = __builtin_amdgcn_mfma_f32_16x16x32_bf16(a1, xb[ct], a, 0, 0, 0);
                    *(s16x4*)(act1 + swz<128>(row, ch1 * 2)) = bn_relu_pack(a, av1, cv1);
                }
            }
            __syncthreads();
            // ===== phase B: L2(nxt) + L4(t0) + segmented max =====
            if (more) {
                f32x4 acc[4];
#pragma unroll
                for (int ct = 0; ct < 4; ++ct) acc[ct] = (f32x4){0.f,0.f,0.f,0.f};
#pragma unroll
                for (int kc = 0; kc < 2; ++kc)
#pragma unroll
                    for (int ct = 0; ct < 4; ++ct) {
                        const s16x8 b = *(const s16x8*)(act1 + swz<128>(ct * 16 + lq, kc * 64 + g * 16));
                        acc[ct] = __builtin_amdgcn_mfma_f32_16x16x32_bf16(w2f[kc], b, acc[ct], 0, 0, 0);
                    }
#pragma unroll
                for (int ct = 0; ct < 4; ++ct)
                    *(s16x4*)(act2 + swz<256>(ct * 16 + lq, ch2 * 2)) = bn_relu_pack(acc[ct], av2, cv2);
            }
            {
                f32x4 acc[2][4];
#pragma unroll
                for (int mt = 0; mt < 2; ++mt)
#pragma unroll
                    for (int ct = 0; ct < 4; ++ct) acc[mt][ct] = (f32x4){0.f,0.f,0.f,0.f};
#pragma unroll
                for (int kc = 0; kc < 8; ++kc)
#pragma unroll
                    for (int ct = 0; ct < 4; ++ct) {
                        const s16x8 b = *(const s16x8*)(act3 + swz<512>(ct * 16 + lq, kc * 64 + g * 16));
#pragma unroll
                        for (int mt = 0; mt < 2; ++mt)
                            acc[mt][ct] = __builtin_amdgcn_mfma_f32_16x16x32_bf16(w4f[mt][kc], b, acc[mt][ct], 0, 0, 0);
                    }
                // segmented max over lq within each 16-pt column block
#pragma unroll
                for (int ct = 0; ct < 4; ++ct) {
                    const int p = t0 + ct * 16 + lq;
                    int vid = 0;
#pragma unroll
                    for (int s = 1; s <= 16; ++s) vid += (p >= bsv[s]) ? 1 : 0;
                    float v[8];
#pragma unroll
                    for (int mt = 0; mt < 2; ++mt)
#pragma unroll
                        for (int r = 0; r < 4; ++r) v[mt * 4 + r] = acc[mt][ct][r] + bv4[mt][r];
#pragma unroll
                    for (int d = 1; d < 16; d <<= 1) {
                        const int nvid = __shfl_down(vid, d, 16);
#pragma unroll
                        for (int j = 0; j < 8; ++j) {
                            const float nv = __shfl_down(v[j], d, 16);
                            v[j] = (nvid == vid) ? fmaxf(v[j], nv) : v[j];
                        }
                    }
                    const int pv = __shfl_up(vid, 1, 16);
                    if (vid < 16 && (lq == 0 || pv != vid)) {
#pragma unroll
                        for (int mt = 0; mt < 2; ++mt)
#pragma unroll
                            for (int r = 0; r < 4; ++r) {
                                float* a = &vmax[vid * 256 + chb + mt * 16 + g * 4 + r];
                                *a = fmaxf(*a, v[mt * 4 + r]);
                            }
                    }
                }
            }
            __syncthreads();
        }
    }
    // write pooled output
    {
        const int vx = tid >> 5, c8 = (tid & 31) * 8;
        const float* vr = &vmax[vx * 256 + c8];
        float* orow = out + (size_t)(vb + vx) * 256 + c8;
        *(f32x4*)orow = *(const f32x4*)vr;
        *(f32x4*)(orow + 4) = *(const f32x4*)(vr + 4);
    }
}

extern "C" void kernel_launch(void* const* d_in, const int* in_sizes, int n_in,
                              void* d_out, int out_size, void* d_ws, size_t ws_size,
                              hipStream_t stream) {
    const float* feats = (const float*)d_in[0];
    const int* coords = (const int*)d_in[1];
    const float* g0 = (const float*)d_in[3];
    const float* be0 = (const float*)d_in[4];
    const float* W1 = (const float*)d_in[5];
    const float* b1 = (const float*)d_in[6];
    const float* g1 = (const float*)d_in[7];
    const float* be1 = (const float*)d_in[8];
    const float* W2 = (const float*)d_in[9];
    const float* b2 = (const float*)d_in[10];
    const float* g2 = (const float*)d_in[11];
    const float* be2 = (const float*)d_in[12];
    const float* W3 = (const float*)d_in[13];
    const float* b3 = (const float*)d_in[14];
    const float* g3 = (const float*)d_in[15];
    const float* be3 = (const float*)d_in[16];
    const float* W4 = (const float*)d_in[17];
    const float* b4 = (const float*)d_in[18];
    float* out = (float*)d_out;
    char* ws = (char*)d_ws;

    const int N = in_sizes[0] / 9;
    const float fN = (float)N;
    const int nt128 = (N + 127) / 128;
    const int nt64 = (N + 63) / 64;

    unsigned short* Xg = (unsigned short*)(ws + X_OFF);
    const unsigned short* wt1 = (const unsigned short*)(ws + WT1_OFF);
    const unsigned short* wt2 = (const unsigned short*)(ws + WT2_OFF);
    const unsigned short* wt3 = (const unsigned short*)(ws + WT3_OFF);
    const unsigned short* wt4 = (const unsigned short*)(ws + WT4_OFF);
    float* A0 = (float*)(ws + A0_OFF); float* C0 = (float*)(ws + C0_OFF);
    float* A1 = (float*)(ws + A1_OFF); float* C1 = (float*)(ws + C1_OFF);
    float* A2 = (float*)(ws + A2_OFF); float* C2 = (float*)(ws + C2_OFF);
    float* A3 = (float*)(ws + A3_OFF); float* C3 = (float*)(ws + C3_OFF);

    hipMemsetAsync(ws, 0, PAR_END, stream);
    hipMemsetAsync(ws + HIST_OFF, 0, 131072, stream);
    // zero X padding rows (pass kernels may read past N)
    {
        const size_t rows = (size_t)nt128 * 128;
        hipMemsetAsync(ws + X_OFF + (size_t)N * 32u, 0,
                       (rows - (size_t)N) * 32u + 8192u, stream);
    }

    hipFuncSetAttribute((const void*)k_pass4,
        hipFuncAttributeMaxDynamicSharedMemorySize, 73728);

    k_prepw<<<128, TPB, 0, stream>>>(W1, W2, W3, W4,
        (unsigned short*)(ws + WT1_OFF), (unsigned short*)(ws + WT2_OFF),
        (unsigned short*)(ws + WT3_OFF), (unsigned short*)(ws + WT4_OFF));
    k_hist_stats<<<1024, TPB, 0, stream>>>(coords, feats, N,
        (unsigned*)(ws + HIST_OFF), (float*)(ws + P0_OFF));
    k_fin<<<1, TPB, 0, stream>>>((const float*)(ws + P0_OFF), 1, 9, g0, be0, nullptr,
                                 A0, C0, fN);
    k_scan<<<1, 1024, 0, stream>>>((const unsigned*)(ws + HIST_OFF),
                                   (int*)(ws + BASE_OFF), (unsigned*)(ws + CURS_OFF), N);
    k_scatter2<<<1024, TPB, 0, stream>>>(coords, feats, N, (unsigned*)(ws + CURS_OFF),
                                         A0, C0, Xg);

    k_pass1s<<<2048, 256, 0, stream>>>(Xg, wt1, b1, (float*)(ws + P1_OFF), N, nt128);
    k_fin<<<1, TPB, 0, stream>>>((const float*)(ws + P1_OFF), 64, 64, g1, be1, b1,
                                 A1, C1, fN);

    k_pass2<<<2048, 256, 0, stream>>>(Xg, wt1, wt2, A1, C1, b2,
                                      (float*)(ws + P2_OFF), N, nt128);
    k_fin<<<1, TPB, 0, stream>>>((const float*)(ws + P2_OFF), 64, 128, g2, be2, b2,
                                 A2, C2, fN);

    k_pass3<<<2048, 512, 0, stream>>>(Xg, wt1, wt2, wt3, A1, C1, A2, C2, b3,
                                      (float*)(ws + P3_OFF), N, nt64);
    k_fin<<<1, TPB, 0, stream>>>((const float*)(ws + P3_OFF), 64, 256, g3, be3, b3,
                                 A3, C3, fN);

    k_coords<<<(NVOX + TPB - 1) / TPB, TPB, 0, stream>>>(out + (size_t)NVOX * 256);
    k_pass4<<<NVOX / 16, 512, 73728, stream>>>(Xg, wt1, wt2, wt3, wt4,
        A1, C1, A2, C2, A3, C3, b4, (const int*)(ws + BASE_OFF), out);
}

// Round 7
// 961.234 us; speedup vs baseline: 18.5620x; 1.0488x over previous
//
#include <hip/hip_runtime.h>
#include <math.h>

#define TPB 256
#define NVOX 32768
#define BN_EPS 1e-5f

typedef short s16x8 __attribute__((ext_vector_type(8)));
typedef short s16x4 __attribute__((ext_vector_type(4)));
typedef float f32x4 __attribute__((ext_vector_type(4)));

// ---------------- ws byte offsets ----------------
#define P0_OFF     0u                         // 54 f32 reduced S|G
#define P1_OFF     256u                       // 64 banks x 54 f32 (S9|G45)
#define P2_OFF     (P1_OFF + 64u*128u*4u)     // 64 banks x 256
#define P3_OFF     (P2_OFF + 64u*256u*4u)     // 64 banks x 512
#define PAR_END    (P3_OFF + 64u*512u*4u)
#define A0_OFF     229632u
#define C0_OFF     229888u
#define A1_OFF     230144u
#define C1_OFF     230400u
#define A2_OFF     230656u
#define C2_OFF     231680u
#define A3_OFF     232704u
#define C3_OFF     233728u
#define HIST_OFF   234752u
#define BASE_OFF   (HIST_OFF + 131072u)
#define CURS_OFF   (BASE_OFF + 131328u)
#define WT1_OFF    (CURS_OFF + 131072u)
#define WT2_OFF    (WT1_OFF + 4096u)
#define WT3_OFF    (WT2_OFF + 16384u)
#define WT4_OFF    (WT3_OFF + 65536u)
#define X_OFF      4845568u                   // X bf16 [Npad][16], voxel-sorted

__device__ __forceinline__ unsigned short f2bf(float f) {   // RTNE
    unsigned u = __float_as_uint(f);
    u += 0x7FFFu + ((u >> 16) & 1u);
    return (unsigned short)(u >> 16);
}
__device__ __forceinline__ unsigned short f2bft(float f) {  // truncate (hot path)
    return (unsigned short)(__float_as_uint(f) >> 16);
}
__device__ __forceinline__ float bf2f(unsigned short h) {
    return __uint_as_float(((unsigned)h) << 16);
}

template<int ROWB>
__device__ __forceinline__ int swz(int row, int b) {
    constexpr int M = (ROWB >= 128) ? 7 : ((ROWB >= 64) ? 3 : 1);
    return row * ROWB + (b ^ ((row & M) << 4));
}

__device__ __forceinline__ s16x4 bn_relu_pack(f32x4 acc, f32x4 av, f32x4 cv) {
    s16x4 pk;
#pragma unroll
    for (int r = 0; r < 4; ++r) pk[r] = (short)f2bft(fmaxf(fmaf(acc[r], av[r], cv[r]), 0.f));
    return pk;
}

template<int NOUT>
__device__ __forceinline__ void stats_red(f32x4 ps, f32x4 pq, int ch, float* prow) {
#pragma unroll
    for (int m = 1; m <= 8; m <<= 1) {
#pragma unroll
        for (int r = 0; r < 4; ++r) { ps[r] += __shfl_xor(ps[r], m); pq[r] += __shfl_xor(pq[r], m); }
    }
    if ((threadIdx.x & 15) == 0) {
#pragma unroll
        for (int r = 0; r < 4; ++r) {
            atomicAdd(&prow[ch + r], ps[r]);
            atomicAdd(&prow[NOUT + ch + r], pq[r]);
        }
    }
}

// ---------------- prep kernels ----------------
__global__ void k_prepw(const float* __restrict__ W1, const float* __restrict__ W2,
                        const float* __restrict__ W3, const float* __restrict__ W4,
                        unsigned short* __restrict__ wt1, unsigned short* __restrict__ wt2,
                        unsigned short* __restrict__ wt3, unsigned short* __restrict__ wt4) {
    for (int i = blockIdx.x * blockDim.x + threadIdx.x; i < 108544;
         i += gridDim.x * blockDim.x) {
        if (i < 2048) {
            int n = i >> 5, k = i & 31;
            wt1[i] = (k < 9) ? f2bf(W1[k * 64 + n]) : (unsigned short)0;
        } else if (i < 10240) {
            int j = i - 2048; int n = j >> 6, k = j & 63;
            wt2[j] = f2bf(W2[k * 128 + n]);
        } else if (i < 43008) {
            int j = i - 10240; int n = j >> 7, k = j & 127;
            wt3[j] = f2bf(W3[k * 256 + n]);
        } else {
            int j = i - 43008; int n = j >> 8, k = j & 255;
            wt4[j] = f2bf(W4[k * 256 + n]);
        }
    }
}

// voxel histogram + raw-x moments S (9) and G = upper-tri of Σ x x^T (45)
__global__ void k_hist_stats(const int* __restrict__ coords, const float* __restrict__ feats,
                             int N, unsigned* __restrict__ hist, float* __restrict__ banks) {
    float S[9] = {0}, G[45] = {0};
    for (int i = blockIdx.x * blockDim.x + threadIdx.x; i < N;
         i += gridDim.x * blockDim.x) {
        int v = (coords[3 * i] << 10) | (coords[3 * i + 1] << 5) | coords[3 * i + 2];
        atomicAdd(&hist[v], 1u);
        const float* r = feats + (size_t)i * 9;
        float x[9];
#pragma unroll
        for (int c = 0; c < 9; ++c) { x[c] = r[c]; S[c] += x[c]; }
        int idx = 0;
#pragma unroll
        for (int c = 0; c < 9; ++c)
#pragma unroll
            for (int c2 = 0; c2 <= c; ++c2) { G[idx] = fmaf(x[c], x[c2], G[idx]); ++idx; }
    }
#pragma unroll
    for (int m = 1; m <= 32; m <<= 1) {
#pragma unroll
        for (int c = 0; c < 9; ++c) S[c] += __shfl_xor(S[c], m);
#pragma unroll
        for (int j = 0; j < 45; ++j) G[j] += __shfl_xor(G[j], m);
    }
    if ((threadIdx.x & 63) == 0) {
        float* b = banks + (size_t)(blockIdx.x & 63) * 54;
#pragma unroll
        for (int c = 0; c < 9; ++c) atomicAdd(&b[c], S[c]);
#pragma unroll
        for (int j = 0; j < 45; ++j) atomicAdd(&b[9 + j], G[j]);
    }
}

// reduce banks -> SG[54]; BN0 params from diag
__global__ void k_fin0(const float* __restrict__ banks, float* __restrict__ SG,
                       const float* __restrict__ g0, const float* __restrict__ be0,
                       float* __restrict__ A0, float* __restrict__ C0, float n) {
    __shared__ float sg[54];
    const int t = threadIdx.x;
    if (t < 54) {
        float s = 0.f;
        for (int b = 0; b < 64; ++b) s += banks[b * 54 + t];
        sg[t] = s; SG[t] = s;
    }
    __syncthreads();
    if (t < 9) {
        float m = sg[t] / n;
        float v = sg[9 + t * (t + 1) / 2 + t] / n - m * m;
        float a = g0[t] * rsqrtf(v + BN_EPS);
        A0[t] = a; C0[t] = be0[t] - m * a;
    }
}

// analytic L1 stats: z = a0*x + c0, h = W1^T z + b1
__global__ void k_fin1(const float* __restrict__ SG,
                       const float* __restrict__ A0, const float* __restrict__ C0,
                       const float* __restrict__ W1, const float* __restrict__ b1,
                       const float* __restrict__ g1, const float* __restrict__ be1,
                       float* __restrict__ A1, float* __restrict__ C1, float n) {
    __shared__ float Sz[9], Gz[81];
    const int t = threadIdx.x;
    if (t < 9) Sz[t] = A0[t] * SG[t] + n * C0[t];
    if (t < 81) {
        const int c = t / 9, c2 = t - 9 * (t / 9);
        const int i = c > c2 ? c : c2, j = c > c2 ? c2 : c;
        const float G = SG[9 + i * (i + 1) / 2 + j];
        Gz[t] = A0[c] * A0[c2] * G + A0[c] * SG[c] * C0[c2]
              + C0[c] * A0[c2] * SG[c2] + n * C0[c] * C0[c2];
    }
    __syncthreads();
    if (t < 64) {
        float wn[9];
#pragma unroll
        for (int c = 0; c < 9; ++c) wn[c] = W1[c * 64 + t];
        float su = 0.f, qq = 0.f;
#pragma unroll
        for (int c = 0; c < 9; ++c) {
            su = fmaf(wn[c], Sz[c], su);
#pragma unroll
            for (int c2 = 0; c2 < 9; ++c2) qq = fmaf(wn[c] * wn[c2], Gz[c * 9 + c2], qq);
        }
        const float bb = b1[t];
        const float mean = (su + n * bb) / n;
        const float q = qq + 2.f * bb * su + n * bb * bb;
        const float var = q / n - mean * mean;
        const float a = g1[t] * rsqrtf(var + BN_EPS);
        A1[t] = a;
        C1[t] = fmaf(a, bb, be1[t] - mean * a);
    }
}

__global__ void k_scan(const unsigned* __restrict__ hist, int* __restrict__ base,
                       unsigned* __restrict__ cursor, int N) {
    __shared__ unsigned part[1024];
    const int t = threadIdx.x;
    unsigned sum = 0;
    for (int j = 0; j < 32; ++j) sum += hist[t * 32 + j];
    part[t] = sum;
    __syncthreads();
    for (int d = 1; d < 1024; d <<= 1) {
        unsigned v = (t >= d) ? part[t - d] : 0u;
        __syncthreads();
        part[t] += v;
        __syncthreads();
    }
    unsigned run = part[t] - sum;
    for (int j = 0; j < 32; ++j) {
        unsigned h = hist[t * 32 + j];
        base[t * 32 + j] = (int)run;
        cursor[t * 32 + j] = run;
        run += h;
    }
    if (t == 1023) base[32768] = (int)run;
}

__global__ void k_scatter2(const int* __restrict__ coords, const float* __restrict__ feats,
                           int N, unsigned* __restrict__ cursor,
                           const float* __restrict__ A0, const float* __restrict__ C0,
                           unsigned short* __restrict__ Xg) {
    float a0[9], c0[9];
#pragma unroll
    for (int c = 0; c < 9; ++c) { a0[c] = A0[c]; c0[c] = C0[c]; }
    for (int i = blockIdx.x * blockDim.x + threadIdx.x; i < N;
         i += gridDim.x * blockDim.x) {
        int v = (coords[3 * i] << 10) | (coords[3 * i + 1] << 5) | coords[3 * i + 2];
        unsigned pos = atomicAdd(&cursor[v], 1u);
        const float* r = feats + (size_t)i * 9;
        s16x8 lo, hi;
#pragma unroll
        for (int c = 0; c < 8; ++c) lo[c] = (short)f2bf(fmaf(r[c], a0[c], c0[c]));
        hi = (s16x8){0, 0, 0, 0, 0, 0, 0, 0};
        hi[0] = (short)f2bf(fmaf(r[8], a0[8], c0[8]));
        *(s16x8*)(Xg + (size_t)pos * 16) = lo;
        *(s16x8*)(Xg + (size_t)pos * 16 + 8) = hi;
    }
}

__global__ void k_fin(const float* __restrict__ part, int nparts, int C,
                      const float* __restrict__ g, const float* __restrict__ be,
                      const float* __restrict__ bias,
                      float* __restrict__ A, float* __restrict__ Cc, float n) {
    int c = threadIdx.x;
    if (c >= C) return;
    float s = 0.f, q = 0.f;
    for (int r = 0; r < nparts; ++r) { s += part[r * 2 * C + c]; q += part[r * 2 * C + C + c]; }
    float m = s / n;
    float v = q / n - m * m;
    float a = g[c] * rsqrtf(v + BN_EPS);
    float cc = be[c] - m * a;
    A[c] = a;
    Cc[c] = bias ? fmaf(a, bias[c], cc) : cc;
}

__global__ void k_coords(float* __restrict__ outc) {
    int v = blockIdx.x * blockDim.x + threadIdx.x;
    if (v < NVOX) {
        outc[3 * v + 0] = (float)(v >> 10);
        outc[3 * v + 1] = (float)((v >> 5) & 31);
        outc[3 * v + 2] = (float)(v & 31);
    }
}

// =====================================================================
// pass2: X -> L1 -> L2 stats.  1 barrier/tile (act1 double-buffered).
// =====================================================================
__global__ __launch_bounds__(256) void k_pass2(
    const unsigned short* __restrict__ Xg,
    const unsigned short* __restrict__ wt1, const unsigned short* __restrict__ wt2,
    const float* __restrict__ A1, const float* __restrict__ C1,
    const float* __restrict__ b2,
    float* __restrict__ p2, int N, int nt) {
    __shared__ char act1[2][16384];
    const int tid = threadIdx.x;
    const int w = tid >> 6, lane = tid & 63, g = lane >> 4, lq = lane & 15;
    const int chb1 = w * 16, chb2 = w * 32;
    const s16x8 a1 = *(const s16x8*)(wt1 + (chb1 + lq) * 32 + g * 8);
    s16x8 w2f[2][2];
#pragma unroll
    for (int mt = 0; mt < 2; ++mt)
#pragma unroll
        for (int kc = 0; kc < 2; ++kc)
            w2f[mt][kc] = *(const s16x8*)(wt2 + (size_t)(chb2 + mt * 16 + lq) * 64 + kc * 32 + g * 8);
    const int ch1 = chb1 + g * 4;
    const f32x4 av1 = *(const f32x4*)(A1 + ch1);
    const f32x4 cv1 = *(const f32x4*)(C1 + ch1);
    f32x4 bv2[2];
#pragma unroll
    for (int mt = 0; mt < 2; ++mt) bv2[mt] = *(const f32x4*)(b2 + chb2 + mt * 16 + g * 4);
    f32x4 ps[2], pq[2];
#pragma unroll
    for (int mt = 0; mt < 2; ++mt) { ps[mt] = (f32x4){0.f,0.f,0.f,0.f}; pq[mt] = (f32x4){0.f,0.f,0.f,0.f}; }

    int t = blockIdx.x;
    if (t < nt) {
#pragma unroll
        for (int ct = 0; ct < 8; ++ct) {
            const int row = ct * 16 + lq;
            const s16x8 b = *(const s16x8*)(Xg + (size_t)(t * 128 + row) * 16 + g * 8);
            f32x4 a = (f32x4){0.f,0.f,0.f,0.f};
            a = __builtin_amdgcn_mfma_f32_16x16x32_bf16(a1, b, a, 0, 0, 0);
            *(s16x4*)(act1[0] + swz<128>(row, ch1 * 2)) = bn_relu_pack(a, av1, cv1);
        }
        __syncthreads();
        int cur = 0;
        while (true) {
            const int tn = t + gridDim.x;
            const bool more = tn < nt;
            const int t0 = t * 128;
            f32x4 acc2[2][8];
#pragma unroll
            for (int mt = 0; mt < 2; ++mt)
#pragma unroll
                for (int ct = 0; ct < 8; ++ct) acc2[mt][ct] = (f32x4){0.f,0.f,0.f,0.f};
#pragma unroll
            for (int kc = 0; kc < 2; ++kc)
#pragma unroll
                for (int ct = 0; ct < 8; ++ct) {
                    const s16x8 b = *(const s16x8*)(act1[cur] + swz<128>(ct * 16 + lq, kc * 64 + g * 16));
#pragma unroll
                    for (int mt = 0; mt < 2; ++mt)
                        acc2[mt][ct] = __builtin_amdgcn_mfma_f32_16x16x32_bf16(w2f[mt][kc], b, acc2[mt][ct], 0, 0, 0);
                }
#pragma unroll
            for (int mt = 0; mt < 2; ++mt)
#pragma unroll
                for (int ct = 0; ct < 8; ++ct) {
                    const bool valid = (t0 + ct * 16 + lq) < N;
#pragma unroll
                    for (int r = 0; r < 4; ++r) {
                        const float h = valid ? (acc2[mt][ct][r] + bv2[mt][r]) : 0.f;
                        ps[mt][r] += h; pq[mt][r] += h * h;
                    }
                }
            if (more) {
#pragma unroll
                for (int ct = 0; ct < 8; ++ct) {
                    const int row = ct * 16 + lq;
                    const s16x8 b = *(const s16x8*)(Xg + (size_t)(tn * 128 + row) * 16 + g * 8);
                    f32x4 a = (f32x4){0.f,0.f,0.f,0.f};
                    a = __builtin_amdgcn_mfma_f32_16x16x32_bf16(a1, b, a, 0, 0, 0);
                    *(s16x4*)(act1[cur ^ 1] + swz<128>(row, ch1 * 2)) = bn_relu_pack(a, av1, cv1);
                }
            }
            __syncthreads();
            if (!more) break;
            t = tn; cur ^= 1;
        }
    }
    float* prow = p2 + (blockIdx.x & 63) * 256;
#pragma unroll
    for (int mt = 0; mt < 2; ++mt)
        stats_red<128>(ps[mt], pq[mt], chb2 + mt * 16 + g * 4, prow);
}

// =====================================================================
// pass3: X -> L1 -> L2 -> L3 stats.  Tile 64, 2-phase pipeline.
// =====================================================================
__global__ __launch_bounds__(512) void k_pass3(
    const unsigned short* __restrict__ Xg,
    const unsigned short* __restrict__ wt1, const unsigned short* __restrict__ wt2,
    const unsigned short* __restrict__ wt3,
    const float* __restrict__ A1, const float* __restrict__ C1,
    const float* __restrict__ A2, const float* __restrict__ C2,
    const float* __restrict__ b3,
    float* __restrict__ p3, int N, int nt) {
    __shared__ char act1[8192];
    __shared__ char act2[16384];
    const int tid = threadIdx.x;
    const int w = tid >> 6, lane = tid & 63, g = lane >> 4, lq = lane & 15;
    const int wm = w >> 1, wn = w & 1;
    const int chb1 = wm * 16, chb2 = w * 16, chb3 = w * 32;
    const s16x8 a1 = *(const s16x8*)(wt1 + (chb1 + lq) * 32 + g * 8);
    s16x8 w2f[2], w3f[2][4];
#pragma unroll
    for (int kc = 0; kc < 2; ++kc)
        w2f[kc] = *(const s16x8*)(wt2 + (size_t)(chb2 + lq) * 64 + kc * 32 + g * 8);
#pragma unroll
    for (int mt = 0; mt < 2; ++mt)
#pragma unroll
        for (int kc = 0; kc < 4; ++kc)
            w3f[mt][kc] = *(const s16x8*)(wt3 + (size_t)(chb3 + mt * 16 + lq) * 128 + kc * 32 + g * 8);
    const int ch1 = chb1 + g * 4, ch2 = chb2 + g * 4;
    const f32x4 av1 = *(const f32x4*)(A1 + ch1);
    const f32x4 cv1 = *(const f32x4*)(C1 + ch1);
    const f32x4 av2 = *(const f32x4*)(A2 + ch2);
    const f32x4 cv2 = *(const f32x4*)(C2 + ch2);
    f32x4 bv3[2];
#pragma unroll
    for (int mt = 0; mt < 2; ++mt) bv3[mt] = *(const f32x4*)(b3 + chb3 + mt * 16 + g * 4);
    f32x4 ps[2], pq[2];
#pragma unroll
    for (int mt = 0; mt < 2; ++mt) { ps[mt] = (f32x4){0.f,0.f,0.f,0.f}; pq[mt] = (f32x4){0.f,0.f,0.f,0.f}; }

    int t = blockIdx.x;
    if (t < nt) {
#pragma unroll
        for (int ct = 0; ct < 2; ++ct) {
            const int row = wn * 32 + ct * 16 + lq;
            const s16x8 b = *(const s16x8*)(Xg + (size_t)(t * 64 + row) * 16 + g * 8);
            f32x4 a = (f32x4){0.f,0.f,0.f,0.f};
            a = __builtin_amdgcn_mfma_f32_16x16x32_bf16(a1, b, a, 0, 0, 0);
            *(s16x4*)(act1 + swz<128>(row, ch1 * 2)) = bn_relu_pack(a, av1, cv1);
        }
        __syncthreads();
        {
            f32x4 acc[4];
#pragma unroll
            for (int ct = 0; ct < 4; ++ct) acc[ct] = (f32x4){0.f,0.f,0.f,0.f};
#pragma unroll
            for (int kc = 0; kc < 2; ++kc)
#pragma unroll
                for (int ct = 0; ct < 4; ++ct) {
                    const s16x8 b = *(const s16x8*)(act1 + swz<128>(ct * 16 + lq, kc * 64 + g * 16));
                    acc[ct] = __builtin_amdgcn_mfma_f32_16x16x32_bf16(w2f[kc], b, acc[ct], 0, 0, 0);
                }
#pragma unroll
            for (int ct = 0; ct < 4; ++ct)
                *(s16x4*)(act2 + swz<256>(ct * 16 + lq, ch2 * 2)) = bn_relu_pack(acc[ct], av2, cv2);
        }
        __syncthreads();
        while (true) {
            const int tn = t + gridDim.x;
            const bool more = tn < nt;
            s16x8 xb[2];
            if (more) {
#pragma unroll
                for (int ct = 0; ct < 2; ++ct) {
                    const int row = wn * 32 + ct * 16 + lq;
                    xb[ct] = *(const s16x8*)(Xg + (size_t)(tn * 64 + row) * 16 + g * 8);
                }
            }
            {
                f32x4 acc[2][4];
#pragma unroll
                for (int mt = 0; mt < 2; ++mt)
#pragma unroll
                    for (int ct = 0; ct < 4; ++ct) acc[mt][ct] = (f32x4){0.f,0.f,0.f,0.f};
#pragma unroll
                for (int kc = 0; kc < 4; ++kc)
#pragma unroll
                    for (int ct = 0; ct < 4; ++ct) {
                        const s16x8 b = *(const s16x8*)(act2 + swz<256>(ct * 16 + lq, kc * 64 + g * 16));
#pragma unroll
                        for (int mt = 0; mt < 2; ++mt)
                            acc[mt][ct] = __builtin_amdgcn_mfma_f32_16x16x32_bf16(w3f[mt][kc], b, acc[mt][ct], 0, 0, 0);
                    }
                const int t0 = t * 64;
#pragma unroll
                for (int mt = 0; mt < 2; ++mt)
#pragma unroll
                    for (int ct = 0; ct < 4; ++ct) {
                        const bool valid = (t0 + ct * 16 + lq) < N;
#pragma unroll
                        for (int r = 0; r < 4; ++r) {
                            const float h = valid ? (acc[mt][ct][r] + bv3[mt][r]) : 0.f;
                            ps[mt][r] += h; pq[mt][r] += h * h;
                        }
                    }
            }
            if (more) {
#pragma unroll
                for (int ct = 0; ct < 2; ++ct) {
                    const int row = wn * 32 + ct * 16 + lq;
                    f32x4 a = (f32x4){0.f,0.f,0.f,0.f};
                    a = __builtin_amdgcn_mfma_f32_16x16x32_bf16(a1, xb[ct], a, 0, 0, 0);
                    *(s16x4*)(act1 + swz<128>(row, ch1 * 2)) = bn_relu_pack(a, av1, cv1);
                }
            }
            __syncthreads();
            if (more) {
                f32x4 acc[4];
#pragma unroll
                for (int ct = 0; ct < 4; ++ct) acc[ct] = (f32x4){0.f,0.f,0.f,0.f};
#pragma unroll
                for (int kc = 0; kc < 2; ++kc)
#pragma unroll
                    for (int ct = 0; ct < 4; ++ct) {
                        const s16x8 b = *(const s16x8*)(act1 + swz<128>(ct * 16 + lq, kc * 64 + g * 16));
                        acc[ct] = __builtin_amdgcn_mfma_f32_16x16x32_bf16(w2f[kc], b, acc[ct], 0, 0, 0);
                    }
#pragma unroll
                for (int ct = 0; ct < 4; ++ct)
                    *(s16x4*)(act2 + swz<256>(ct * 16 + lq, ch2 * 2)) = bn_relu_pack(acc[ct], av2, cv2);
            }
            __syncthreads();
            if (!more) break;
            t = tn;
        }
    }
    float* prow = p3 + (blockIdx.x & 63) * 512;
#pragma unroll
    for (int mt = 0; mt < 2; ++mt)
        stats_red<256>(ps[mt], pq[mt], chb3 + mt * 16 + g * 4, prow);
}

// =====================================================================
// pass4: X -> L1..L4 -> segment max.  2 barriers/tile, h4 double-buffered,
// cheap serial per-voxel max epilogue overlapped into phase B.
// =====================================================================
__global__ __launch_bounds__(512) void k_pass4(
    const unsigned short* __restrict__ Xg,
    const unsigned short* __restrict__ wt1, const unsigned short* __restrict__ wt2,
    const unsigned short* __restrict__ wt3, const unsigned short* __restrict__ wt4,
    const float* __restrict__ A1, const float* __restrict__ C1,
    const float* __restrict__ A2, const float* __restrict__ C2,
    const float* __restrict__ A3, const float* __restrict__ C3,
    const float* __restrict__ b4,
    const int* __restrict__ base, float* __restrict__ out) {
    extern __shared__ char smem[];
    char* act1 = smem;                  // 8K  [64][128B]
    char* act2 = smem + 8192;           // 16K [64][256B]
    char* act3 = smem + 24576;          // 32K [64][512B]
    char* h40  = smem + 57344;          // 32K [64][512B]
    char* h41  = smem + 90112;          // 32K

    const int tid = threadIdx.x;
    const int w = tid >> 6, lane = tid & 63, g = lane >> 4, lq = lane & 15;
    const int wm = w >> 1, wn = w & 1;
    const int chb1 = wm * 16, chb2 = w * 16, chb = w * 32;
    const int vb = blockIdx.x * 16;
    const int pstart = base[vb], pend = base[vb + 16];
    const int chgrp = tid & 31, slot = tid >> 5;
    const int vlo = base[vb + slot], vhi = base[vb + slot + 1];

    const s16x8 a1 = *(const s16x8*)(wt1 + (chb1 + lq) * 32 + g * 8);
    s16x8 w2f[2], w3f[2][4], w4f[2][8];
#pragma unroll
    for (int kc = 0; kc < 2; ++kc)
        w2f[kc] = *(const s16x8*)(wt2 + (size_t)(chb2 + lq) * 64 + kc * 32 + g * 8);
#pragma unroll
    for (int mt = 0; mt < 2; ++mt) {
#pragma unroll
        for (int kc = 0; kc < 4; ++kc)
            w3f[mt][kc] = *(const s16x8*)(wt3 + (size_t)(chb + mt * 16 + lq) * 128 + kc * 32 + g * 8);
#pragma unroll
        for (int kc = 0; kc < 8; ++kc)
            w4f[mt][kc] = *(const s16x8*)(wt4 + (size_t)(chb + mt * 16 + lq) * 256 + kc * 32 + g * 8);
    }
    const int ch1 = chb1 + g * 4, ch2 = chb2 + g * 4;
    const f32x4 av1 = *(const f32x4*)(A1 + ch1);
    const f32x4 cv1 = *(const f32x4*)(C1 + ch1);
    const f32x4 av2 = *(const f32x4*)(A2 + ch2);
    const f32x4 cv2 = *(const f32x4*)(C2 + ch2);
    f32x4 av3[2], cv3[2], bv4[2];
#pragma unroll
    for (int mt = 0; mt < 2; ++mt) {
        av3[mt] = *(const f32x4*)(A3 + chb + mt * 16 + g * 4);
        cv3[mt] = *(const f32x4*)(C3 + chb + mt * 16 + g * 4);
        bv4[mt] = *(const f32x4*)(b4 + chb + mt * 16 + g * 4);
    }

    float rmax[8];
#pragma unroll
    for (int j = 0; j < 8; ++j) rmax[j] = -INFINITY;

    if (pstart < pend) {
        // prologue: L1(pstart) -> act1 ; L2 -> act2
#pragma unroll
        for (int ct = 0; ct < 2; ++ct) {
            const int row = wn * 32 + ct * 16 + lq;
            const s16x8 b = *(const s16x8*)(Xg + (size_t)(pstart + row) * 16 + g * 8);
            f32x4 a = (f32x4){0.f,0.f,0.f,0.f};
            a = __builtin_amdgcn_mfma_f32_16x16x32_bf16(a1, b, a, 0, 0, 0);
            *(s16x4*)(act1 + swz<128>(row, ch1 * 2)) = bn_relu_pack(a, av1, cv1);
        }
        __syncthreads();
        {
            f32x4 acc[4];
#pragma unroll
            for (int ct = 0; ct < 4; ++ct) acc[ct] = (f32x4){0.f,0.f,0.f,0.f};
#pragma unroll
            for (int kc = 0; kc < 2; ++kc)
#pragma unroll
                for (int ct = 0; ct < 4; ++ct) {
                    const s16x8 b = *(const s16x8*)(act1 + swz<128>(ct * 16 + lq, kc * 64 + g * 16));
                    acc[ct] = __builtin_amdgcn_mfma_f32_16x16x32_bf16(w2f[kc], b, acc[ct], 0, 0, 0);
                }
#pragma unroll
            for (int ct = 0; ct < 4; ++ct)
                *(s16x4*)(act2 + swz<256>(ct * 16 + lq, ch2 * 2)) = bn_relu_pack(acc[ct], av2, cv2);
        }
        __syncthreads();

        int cur = 0;
        int lt = pstart;
        for (int t0 = pstart; t0 < pend; t0 += 64) {
            const int nxt = t0 + 64;
            const bool more = nxt < pend;
            char* hcur = cur ? h41 : h40;
            char* hprev = cur ? h40 : h41;
            // ===== phase A: L3(t0) + prefetch L1(nxt) =====
            s16x8 xb0, xb1;
            if (more) {
                xb0 = *(const s16x8*)(Xg + (size_t)(nxt + wn * 32 + lq) * 16 + g * 8);
                xb1 = *(const s16x8*)(Xg + (size_t)(nxt + wn * 32 + 16 + lq) * 16 + g * 8);
            }
#pragma unroll
            for (int mt = 0; mt < 2; ++mt) {
                f32x4 acc[4];
#pragma unroll
                for (int ct = 0; ct < 4; ++ct) acc[ct] = (f32x4){0.f,0.f,0.f,0.f};
#pragma unroll
                for (int kc = 0; kc < 4; ++kc)
#pragma unroll
                    for (int ct = 0; ct < 4; ++ct) {
                        const s16x8 b = *(const s16x8*)(act2 + swz<256>(ct * 16 + lq, kc * 64 + g * 16));
                        acc[ct] = __builtin_amdgcn_mfma_f32_16x16x32_bf16(w3f[mt][kc], b, acc[ct], 0, 0, 0);
                    }
#pragma unroll
                for (int ct = 0; ct < 4; ++ct)
                    *(s16x4*)(act3 + swz<512>(ct * 16 + lq, (chb + mt * 16 + g * 4) * 2)) =
                        bn_relu_pack(acc[ct], av3[mt], cv3[mt]);
            }
            if (more) {
                f32x4 a = (f32x4){0.f,0.f,0.f,0.f};
                a = __builtin_amdgcn_mfma_f32_16x16x32_bf16(a1, xb0, a, 0, 0, 0);
                *(s16x4*)(act1 + swz<128>(wn * 32 + lq, ch1 * 2)) = bn_relu_pack(a, av1, cv1);
                f32x4 a2r = (f32x4){0.f,0.f,0.f,0.f};
                a2r = __builtin_amdgcn_mfma_f32_16x16x32_bf16(a1, xb1, a2r, 0, 0, 0);
                *(s16x4*)(act1 + swz<128>(wn * 32 + 16 + lq, ch1 * 2)) = bn_relu_pack(a2r, av1, cv1);
            }
            __syncthreads();
            // ===== phase B: L2(nxt) + L4(t0) -> h4[cur] + max(h4[prev], t0-64) =====
            if (more) {
                f32x4 acc[4];
#pragma unroll
                for (int ct = 0; ct < 4; ++ct) acc[ct] = (f32x4){0.f,0.f,0.f,0.f};
#pragma unroll
                for (int kc = 0; kc < 2; ++kc)
#pragma unroll
                    for (int ct = 0; ct < 4; ++ct) {
                        const s16x8 b = *(const s16x8*)(act1 + swz<128>(ct * 16 + lq, kc * 64 + g * 16));
                        acc[ct] = __builtin_amdgcn_mfma_f32_16x16x32_bf16(w2f[kc], b, acc[ct], 0, 0, 0);
                    }
#pragma unroll
                for (int ct = 0; ct < 4; ++ct)
                    *(s16x4*)(act2 + swz<256>(ct * 16 + lq, ch2 * 2)) = bn_relu_pack(acc[ct], av2, cv2);
            }
#pragma unroll
            for (int mt = 0; mt < 2; ++mt) {
                f32x4 acc[4];
#pragma unroll
                for (int ct = 0; ct < 4; ++ct) acc[ct] = (f32x4){0.f,0.f,0.f,0.f};
#pragma unroll
                for (int kc = 0; kc < 8; ++kc)
#pragma unroll
                    for (int ct = 0; ct < 4; ++ct) {
                        const s16x8 b = *(const s16x8*)(act3 + swz<512>(ct * 16 + lq, kc * 64 + g * 16));
                        acc[ct] = __builtin_amdgcn_mfma_f32_16x16x32_bf16(w4f[mt][kc], b, acc[ct], 0, 0, 0);
                    }
#pragma unroll
                for (int ct = 0; ct < 4; ++ct) {
                    s16x4 pk;
#pragma unroll
                    for (int r = 0; r < 4; ++r) pk[r] = (short)f2bf(acc[ct][r] + bv4[mt][r]);
                    *(s16x4*)(hcur + swz<512>(ct * 16 + lq, (chb + mt * 16 + g * 4) * 2)) = pk;
                }
            }
            if (t0 > pstart) {
                const int tm = t0 - 64;
                const int lo = max(vlo, tm), hi = min(vhi, tm + 64);
                for (int p = lo; p < hi; ++p) {
                    const s16x8 hv = *(const s16x8*)(hprev + swz<512>(p - tm, chgrp * 16));
#pragma unroll
                    for (int j = 0; j < 8; ++j)
                        rmax[j] = fmaxf(rmax[j], bf2f((unsigned short)hv[j]));
                }
            }
            __syncthreads();
            lt = t0;
            cur ^= 1;
        }
        // drain: max of last tile (in buffer cur^1 after final flip)
        {
            char* hlast = (cur ^ 1) ? h41 : h40;
            const int lo = max(vlo, lt), hi = min(vhi, lt + 64);
            for (int p = lo; p < hi; ++p) {
                const s16x8 hv = *(const s16x8*)(hlast + swz<512>(p - lt, chgrp * 16));
#pragma unroll
                for (int j = 0; j < 8; ++j)
                    rmax[j] = fmaxf(rmax[j], bf2f((unsigned short)hv[j]));
            }
        }
    }
    float* orow = out + (size_t)(vb + slot) * 256 + chgrp * 8;
    f32x4 o0, o1;
#pragma unroll
    for (int j = 0; j < 4; ++j) { o0[j] = rmax[j]; o1[j] = rmax[4 + j]; }
    *(f32x4*)orow = o0;
    *(f32x4*)(orow + 4) = o1;
}

extern "C" void kernel_launch(void* const* d_in, const int* in_sizes, int n_in,
                              void* d_out, int out_size, void* d_ws, size_t ws_size,
                              hipStream_t stream) {
    const float* feats = (const float*)d_in[0];
    const int* coords = (const int*)d_in[1];
    const float* g0 = (const float*)d_in[3];
    const float* be0 = (const float*)d_in[4];
    const float* W1 = (const float*)d_in[5];
    const float* b1 = (const float*)d_in[6];
    const float* g1 = (const float*)d_in[7];
    const float* be1 = (const float*)d_in[8];
    const float* W2 = (const float*)d_in[9];
    const float* b2 = (const float*)d_in[10];
    const float* g2 = (const float*)d_in[11];
    const float* be2 = (const float*)d_in[12];
    const float* W3 = (const float*)d_in[13];
    const float* b3 = (const float*)d_in[14];
    const float* g3 = (const float*)d_in[15];
    const float* be3 = (const float*)d_in[16];
    const float* W4 = (const float*)d_in[17];
    const float* b4 = (const float*)d_in[18];
    float* out = (float*)d_out;
    char* ws = (char*)d_ws;

    const int N = in_sizes[0] / 9;
    const float fN = (float)N;
    const int nt128 = (N + 127) / 128;
    const int nt64 = (N + 63) / 64;

    unsigned short* Xg = (unsigned short*)(ws + X_OFF);
    const unsigned short* wt1 = (const unsigned short*)(ws + WT1_OFF);
    const unsigned short* wt2 = (const unsigned short*)(ws + WT2_OFF);
    const unsigned short* wt3 = (const unsigned short*)(ws + WT3_OFF);
    const unsigned short* wt4 = (const unsigned short*)(ws + WT4_OFF);
    float* A0 = (float*)(ws + A0_OFF); float* C0 = (float*)(ws + C0_OFF);
    float* A1 = (float*)(ws + A1_OFF); float* C1 = (float*)(ws + C1_OFF);
    float* A2 = (float*)(ws + A2_OFF); float* C2 = (float*)(ws + C2_OFF);
    float* A3 = (float*)(ws + A3_OFF); float* C3 = (float*)(ws + C3_OFF);

    hipMemsetAsync(ws, 0, PAR_END, stream);
    hipMemsetAsync(ws + HIST_OFF, 0, 131072, stream);
    {   // zero X padding rows (pass kernels may read past N)
        const size_t rows = (size_t)nt128 * 128;
        hipMemsetAsync(ws + X_OFF + (size_t)N * 32u, 0,
                       (rows - (size_t)N) * 32u + 8192u, stream);
    }

    hipFuncSetAttribute((const void*)k_pass4,
        hipFuncAttributeMaxDynamicSharedMemorySize, 122880);

    k_prepw<<<128, TPB, 0, stream>>>(W1, W2, W3, W4,
        (unsigned short*)(ws + WT1_OFF), (unsigned short*)(ws + WT2_OFF),
        (unsigned short*)(ws + WT3_OFF), (unsigned short*)(ws + WT4_OFF));
    k_hist_stats<<<1024, TPB, 0, stream>>>(coords, feats, N,
        (unsigned*)(ws + HIST_OFF), (float*)(ws + P1_OFF));
    k_fin0<<<1, 64, 0, stream>>>((const float*)(ws + P1_OFF), (float*)(ws + P0_OFF),
                                 g0, be0, A0, C0, fN);
    k_fin1<<<1, 128, 0, stream>>>((const float*)(ws + P0_OFF), A0, C0,
                                  W1, b1, g1, be1, A1, C1, fN);
    k_scan<<<1, 1024, 0, stream>>>((const unsigned*)(ws + HIST_OFF),
                                   (int*)(ws + BASE_OFF), (unsigned*)(ws + CURS_OFF), N);
    k_scatter2<<<1024, TPB, 0, stream>>>(coords, feats, N, (unsigned*)(ws + CURS_OFF),
                                         A0, C0, Xg);
    k_coords<<<(NVOX + TPB - 1) / TPB, TPB, 0, stream>>>(out + (size_t)NVOX * 256);

    k_pass2<<<2048, 256, 0, stream>>>(Xg, wt1, wt2, A1, C1, b2,
                                      (float*)(ws + P2_OFF), N, nt128);
    k_fin<<<1, TPB, 0, stream>>>((const float*)(ws + P2_OFF), 64, 128, g2, be2, b2,
                                 A2, C2, fN);

    k_pass3<<<2048, 512, 0, stream>>>(Xg, wt1, wt2, wt3, A1, C1, A2, C2, b3,
                                      (float*)(ws + P3_OFF), N, nt64);
    k_fin<<<1, TPB, 0, stream>>>((const float*)(ws + P3_OFF), 64, 256, g3, be3, b3,
                                 A3, C3, fN);

    k_pass4<<<NVOX / 16, 512, 122880, stream>>>(Xg, wt1, wt2, wt3, wt4,
        A1, C1, A2, C2, A3, C3, b4, (const int*)(ws + BASE_OFF), out);
}